// Round 5
// baseline (697.396 us; speedup 1.0000x reference)
//
#include <hip/hip_runtime.h>
#include <stdint.h>

// B=2,S=2048,D=1024,H=16,R=64,N=32,RK=128,DH=64. Tokens T=4096.

typedef __bf16 bf16x8 __attribute__((ext_vector_type(8)));
typedef float f32x4 __attribute__((ext_vector_type(4)));

__device__ __forceinline__ unsigned short f2b(float f) {
  union { float f; unsigned u; } v; v.f = f;
  unsigned u = v.u;
  unsigned r = (u + 0x7FFFu + ((u >> 16) & 1u)) >> 16;  // RNE
  return (unsigned short)r;
}
__device__ __forceinline__ float b2f(unsigned short h) {
  union { unsigned u; float f; } v; v.u = ((unsigned)h) << 16;
  return v.f;
}
__device__ __forceinline__ unsigned pk2(float lo, float hi) {
  return (unsigned)f2b(lo) | ((unsigned)f2b(hi) << 16);
}

// ---------------------------------------------------------------------------
// Generic bf16 GEMM: C[M,N] = A[M,K] @ Bt[N,K]^T.  128x128 tile, BK=64,
// 256 threads (4 waves, 2x2 of 64x64), 16x16x32 MFMA, global_load_lds x16.
// mode 0: fp32 out; 1: bf16 out; 2: fp32 out + res; 3: bf16 transposed out[N,M]
// ---------------------------------------------------------------------------
__global__ __launch_bounds__(256) void gemm_bt(
    const unsigned short* __restrict__ A, const unsigned short* __restrict__ Bt,
    const float* __restrict__ res, void* __restrict__ out,
    int M, int N, int K, int mode) {
  __shared__ unsigned short lsA[128 * 64];
  __shared__ unsigned short lsB[128 * 64];
  const int tid = threadIdx.x;
  const int w = tid >> 6, lane = tid & 63;
  const int quad = lane >> 4, l16 = lane & 15;
  const int wr = w >> 1, wc = w & 1;
  const int row0 = blockIdx.y * 128;
  const int col0 = blockIdx.x * 128;

  const int srow = w * 32 + (lane >> 3);
  const int scg = (lane & 7) * 8;
  const unsigned short* ap = A + (size_t)(row0 + srow) * K + scg;
  const unsigned short* bp = Bt + (size_t)(col0 + srow) * K + scg;

  const f32x4 fz = {0.f, 0.f, 0.f, 0.f};
  f32x4 acc[4][4];
#pragma unroll
  for (int i = 0; i < 4; ++i)
#pragma unroll
    for (int j = 0; j < 4; ++j) acc[i][j] = fz;

  for (int k0 = 0; k0 < K; k0 += 64) {
#pragma unroll
    for (int i = 0; i < 4; ++i) {
      __builtin_amdgcn_global_load_lds(
          (const __attribute__((address_space(1))) unsigned int*)(ap + (size_t)i * 8 * K + k0),
          (__attribute__((address_space(3))) unsigned int*)&lsA[(w * 32 + i * 8) * 64],
          16, 0, 0);
      __builtin_amdgcn_global_load_lds(
          (const __attribute__((address_space(1))) unsigned int*)(bp + (size_t)i * 8 * K + k0),
          (__attribute__((address_space(3))) unsigned int*)&lsB[(w * 32 + i * 8) * 64],
          16, 0, 0);
    }
    __syncthreads();
#pragma unroll
    for (int kk = 0; kk < 2; ++kk) {
      bf16x8 af[4], bfr[4];
#pragma unroll
      for (int mt = 0; mt < 4; ++mt)
        af[mt] = *(const bf16x8*)&lsA[(wr * 64 + mt * 16 + l16) * 64 + kk * 32 + quad * 8];
#pragma unroll
      for (int nt = 0; nt < 4; ++nt)
        bfr[nt] = *(const bf16x8*)&lsB[(wc * 64 + nt * 16 + l16) * 64 + kk * 32 + quad * 8];
#pragma unroll
      for (int mt = 0; mt < 4; ++mt)
#pragma unroll
        for (int nt = 0; nt < 4; ++nt)
          acc[mt][nt] = __builtin_amdgcn_mfma_f32_16x16x32_bf16(af[mt], bfr[nt], acc[mt][nt], 0, 0, 0);
    }
    __syncthreads();
  }

  const int rb = row0 + wr * 64;
  const int cb = col0 + wc * 64;
#pragma unroll
  for (int mt = 0; mt < 4; ++mt) {
#pragma unroll
    for (int nt = 0; nt < 4; ++nt) {
      const int r = rb + mt * 16 + quad * 4;
      const int c = cb + nt * 16 + l16;
#pragma unroll
      for (int i = 0; i < 4; ++i) {
        const float v = acc[mt][nt][i];
        const size_t idx = (size_t)(r + i) * N + c;
        if (mode == 0) ((float*)out)[idx] = v;
        else if (mode == 1) ((unsigned short*)out)[idx] = f2b(v);
        else if (mode == 2) ((float*)out)[idx] = v + res[idx];
        else ((unsigned short*)out)[(size_t)c * M + (r + i)] = f2b(v);
      }
    }
  }
}

// ---------------------------------------------------------------------------
// Fused Q/K + V restore GEMM (one dispatch, 768 blocks).
// by<64: QKbuf[row,col] (M=8192, A=t_qk);  by>=64: VT[col, row] (M=4096, A=t_v)
// ---------------------------------------------------------------------------
__global__ __launch_bounds__(256) void gemm_qkv(
    const unsigned short* __restrict__ t_qk, const unsigned short* __restrict__ t_v,
    const unsigned short* __restrict__ r_qkT, const unsigned short* __restrict__ r_vT,
    unsigned short* __restrict__ QKbuf, unsigned short* __restrict__ VT) {
  __shared__ unsigned short lsA[128 * 64];
  __shared__ unsigned short lsB[128 * 64];
  const int K = 2048;
  const bool isV = blockIdx.y >= 64;
  const unsigned short* A  = isV ? t_v : t_qk;
  const unsigned short* Bt = isV ? r_vT : r_qkT;
  const int row0 = (isV ? ((int)blockIdx.y - 64) : (int)blockIdx.y) * 128;
  const int col0 = blockIdx.x * 128;
  const int tid = threadIdx.x;
  const int w = tid >> 6, lane = tid & 63;
  const int quad = lane >> 4, l16 = lane & 15;
  const int wr = w >> 1, wc = w & 1;

  const int srow = w * 32 + (lane >> 3);
  const int scg = (lane & 7) * 8;
  const unsigned short* ap = A + (size_t)(row0 + srow) * K + scg;
  const unsigned short* bp = Bt + (size_t)(col0 + srow) * K + scg;

  const f32x4 fz = {0.f, 0.f, 0.f, 0.f};
  f32x4 acc[4][4];
#pragma unroll
  for (int i = 0; i < 4; ++i)
#pragma unroll
    for (int j = 0; j < 4; ++j) acc[i][j] = fz;

  for (int k0 = 0; k0 < K; k0 += 64) {
#pragma unroll
    for (int i = 0; i < 4; ++i) {
      __builtin_amdgcn_global_load_lds(
          (const __attribute__((address_space(1))) unsigned int*)(ap + (size_t)i * 8 * K + k0),
          (__attribute__((address_space(3))) unsigned int*)&lsA[(w * 32 + i * 8) * 64],
          16, 0, 0);
      __builtin_amdgcn_global_load_lds(
          (const __attribute__((address_space(1))) unsigned int*)(bp + (size_t)i * 8 * K + k0),
          (__attribute__((address_space(3))) unsigned int*)&lsB[(w * 32 + i * 8) * 64],
          16, 0, 0);
    }
    __syncthreads();
#pragma unroll
    for (int kk = 0; kk < 2; ++kk) {
      bf16x8 af[4], bfr[4];
#pragma unroll
      for (int mt = 0; mt < 4; ++mt)
        af[mt] = *(const bf16x8*)&lsA[(wr * 64 + mt * 16 + l16) * 64 + kk * 32 + quad * 8];
#pragma unroll
      for (int nt = 0; nt < 4; ++nt)
        bfr[nt] = *(const bf16x8*)&lsB[(wc * 64 + nt * 16 + l16) * 64 + kk * 32 + quad * 8];
#pragma unroll
      for (int mt = 0; mt < 4; ++mt)
#pragma unroll
        for (int nt = 0; nt < 4; ++nt)
          acc[mt][nt] = __builtin_amdgcn_mfma_f32_16x16x32_bf16(af[mt], bfr[nt], acc[mt][nt], 0, 0, 0);
    }
    __syncthreads();
  }

  const int rb = row0 + wr * 64;
  const int cb = col0 + wc * 64;
#pragma unroll
  for (int mt = 0; mt < 4; ++mt) {
#pragma unroll
    for (int nt = 0; nt < 4; ++nt) {
      const int r = rb + mt * 16 + quad * 4;
      const int c = cb + nt * 16 + l16;
#pragma unroll
      for (int i = 0; i < 4; ++i) {
        const float v = acc[mt][nt][i];
        if (!isV) QKbuf[(size_t)(r + i) * 1024 + c] = f2b(v);
        else VT[(size_t)c * 4096 + (r + i)] = f2b(v);
      }
    }
  }
}

// ---------------------------------------------------------------------------
// LayerNorm over D=1024, one token per 256-thread block, bf16 out.
// ---------------------------------------------------------------------------
__global__ __launch_bounds__(256) void ln_kernel(
    const float* __restrict__ x, const float* __restrict__ g,
    const float* __restrict__ be, unsigned short* __restrict__ out) {
  __shared__ float sbuf[4];
  const int t = blockIdx.x, tid = threadIdx.x;
  const float* row = x + (size_t)t * 1024;
  float v[4], s = 0.f;
#pragma unroll
  for (int j = 0; j < 4; ++j) { v[j] = row[tid + j * 256]; s += v[j]; }
#pragma unroll
  for (int off = 32; off; off >>= 1) s += __shfl_xor(s, off);
  if ((tid & 63) == 0) sbuf[tid >> 6] = s;
  __syncthreads();
  const float mu = (sbuf[0] + sbuf[1] + sbuf[2] + sbuf[3]) * (1.f / 1024.f);
  __syncthreads();
  float ss = 0.f;
#pragma unroll
  for (int j = 0; j < 4; ++j) { const float d = v[j] - mu; ss += d * d; }
#pragma unroll
  for (int off = 32; off; off >>= 1) ss += __shfl_xor(ss, off);
  if ((tid & 63) == 0) sbuf[tid >> 6] = ss;
  __syncthreads();
  const float var = (sbuf[0] + sbuf[1] + sbuf[2] + sbuf[3]) * (1.f / 1024.f);
  const float rstd = rsqrtf(var + 1e-5f);
  unsigned short* orow = out + (size_t)t * 1024;
#pragma unroll
  for (int j = 0; j < 4; ++j) {
    const int c = tid + j * 256;
    orow[c] = f2b((v[j] - mu) * rstd * g[c] + be[c]);
  }
}

// ---------------------------------------------------------------------------
// Attention mixing: h_{q,k,v}[r] = sum_n w_f*[n]*all_h[t, (base)+n*64+r];
// t_*[t, n*64+r] = w_r*[n]*h_*[r].  all_h cols: [0,2048)=f_qk, [2048,4096)=f_v.
// ---------------------------------------------------------------------------
__global__ __launch_bounds__(256) void mix_attn(
    const unsigned short* __restrict__ all_h,
    const float* __restrict__ w_fq, const float* __restrict__ w_fk,
    const float* __restrict__ w_fv, const float* __restrict__ w_rq,
    const float* __restrict__ w_rk, const float* __restrict__ w_rv,
    unsigned short* __restrict__ t_qk, unsigned short* __restrict__ t_v) {
  __shared__ float hq[64], hk[64], hv[64];
  const int t = blockIdx.x, tid = threadIdx.x;
  const int wv = tid >> 6, lane = tid & 63;
  const unsigned short* row = all_h + (size_t)t * 4096;
  if (wv < 3) {
    const float* wf = (wv == 0 ? w_fq : wv == 1 ? w_fk : w_fv) + (size_t)t * 32;
    const int base = (wv == 2) ? 2048 : 0;
    float acc = 0.f;
#pragma unroll
    for (int n = 0; n < 32; ++n) acc += wf[n] * b2f(row[base + n * 64 + lane]);
    (wv == 0 ? hq : wv == 1 ? hk : hv)[lane] = acc;
  }
  __syncthreads();
  const float* wrq = w_rq + (size_t)t * 32;
  const float* wrk = w_rk + (size_t)t * 32;
  const float* wrv = w_rv + (size_t)t * 32;
  for (int idx = tid; idx < 2048; idx += 256) {
    const int n = idx >> 6, r = idx & 63;
    t_qk[(size_t)t * 2048 + idx] = f2b(wrq[n] * hq[r]);
    t_qk[(size_t)(4096 + t) * 2048 + idx] = f2b(wrk[n] * hk[r]);
    t_v[(size_t)t * 2048 + idx] = f2b(wrv[n] * hv[r]);
  }
}

// Knowledge mixing (RK=128): h[r]=sum_n w_f[n]*all_h[t,n*128+r]; t_know=w_r[n]*h[r]
__global__ __launch_bounds__(256) void mix_know(
    const unsigned short* __restrict__ all_h, const float* __restrict__ w_f,
    const float* __restrict__ w_r, unsigned short* __restrict__ t_know) {
  __shared__ float h[128];
  const int t = blockIdx.x, tid = threadIdx.x;
  const unsigned short* row = all_h + (size_t)t * 4096;
  if (tid < 128) {
    const float* wf = w_f + (size_t)t * 32;
    float acc = 0.f;
#pragma unroll
    for (int n = 0; n < 32; ++n) acc += wf[n] * b2f(row[n * 128 + tid]);
    h[tid] = acc;
  }
  __syncthreads();
  const float* wr = w_r + (size_t)t * 32;
  for (int idx = tid; idx < 4096; idx += 256) {
    const int n = idx >> 7, r = idx & 127;
    t_know[(size_t)t * 4096 + idx] = f2b(wr[n] * h[r]);
  }
}

// ---------------------------------------------------------------------------
// Batched transpose + fp32->bf16: in [batch][R][C] f32 -> out [batch][C][R] bf16
// ---------------------------------------------------------------------------
__global__ __launch_bounds__(256) void transpose_bf(
    const float* __restrict__ in, unsigned short* __restrict__ out, int R, int C) {
  __shared__ float tile[32][33];
  const int bb = blockIdx.z;
  const int c0 = blockIdx.x * 32, r0 = blockIdx.y * 32;
  const int tx = threadIdx.x, ty = threadIdx.y;
  const float* ip = in + (size_t)bb * R * C;
  unsigned short* op = out + (size_t)bb * R * C;
#pragma unroll
  for (int j = 0; j < 4; ++j)
    tile[ty + j * 8][tx] = ip[(size_t)(r0 + ty + j * 8) * C + c0 + tx];
  __syncthreads();
#pragma unroll
  for (int j = 0; j < 4; ++j)
    op[(size_t)(c0 + ty + j * 8) * R + r0 + tx] = f2b(tile[tx][ty + j * 8]);
}

__global__ __launch_bounds__(256) void convert_bf(
    const float* __restrict__ in, unsigned short* __restrict__ out, int n) {
  const int i = blockIdx.x * 256 + threadIdx.x;
  if (i < n) out[i] = f2b(in[i]);
}

// ---------------------------------------------------------------------------
// Causal flash attention v5: transposed algebra + 128 q-rows per block.
// Each wave owns TWO 16-q subtiles (q = w*32 + sub*16 + l16 within block).
// K/V staging, ds_reads, and barriers amortized over 2x q-rows; the two
// subtiles' MFMA/softmax chains are independent (ILP).
//   S^T = K·Q^T  (C/D col=l16 -> q-row; lane owns one q, 16 k in regs)
//   O^T = V^T·P^T; P^T C-layout -> B-frag via quad-pair ds_bpermute exchange
// LDS: double-buffered K/V (32 KB), XOR chunk swizzle, conflict-free.
// ---------------------------------------------------------------------------
__global__ __launch_bounds__(256) void flash_attn(
    const unsigned short* __restrict__ Q, const unsigned short* __restrict__ Kp,
    const unsigned short* __restrict__ VT, unsigned short* __restrict__ O) {
  __shared__ unsigned short Kls[2][64 * 64];
  __shared__ unsigned short Vls[2][64 * 64];
  const int qt = (gridDim.x - 1) - blockIdx.x;  // longest blocks first
  const int bh = blockIdx.y;
  const int b = bh >> 4, h = bh & 15;
  const int tid = threadIdx.x;
  const int w = tid >> 6, lane = tid & 63, quad = lane >> 4, l16 = lane & 15;
  const int tb = b * 2048;
  const float C = 0.18033688f;  // (1/sqrt(64)) * log2(e)

  const int srow = (lane >> 3);
  const int scol = ((lane & 7) ^ srow) * 8;  // XOR-swizzled chunk

  // per-wave q bases (local to the 2048-token b-column)
  const int qb0 = qt * 128 + w * 32;         // sub 0
  // Q fragments (B-operand): n = q-row = l16, k = kk*32 + quad*8 + j
  bf16x8 qf[2][2];
#pragma unroll
  for (int sub = 0; sub < 2; ++sub)
#pragma unroll
    for (int kk = 0; kk < 2; ++kk)
      qf[sub][kk] = *(const bf16x8*)&Q[(size_t)(tb + qb0 + sub * 16 + l16) * 1024 +
                                       h * 64 + kk * 32 + quad * 8];

  const f32x4 fz = {0.f, 0.f, 0.f, 0.f};
  float m_i[2] = {-1e30f, -1e30f}, l_i[2] = {0.f, 0.f};
  f32x4 o_acc[2][4];
#pragma unroll
  for (int sub = 0; sub < 2; ++sub)
#pragma unroll
    for (int nt = 0; nt < 4; ++nt) o_acc[sub][nt] = fz;

  auto stage = [&](int buf, int kt) {
#pragma unroll
    for (int j = 0; j < 2; ++j) {
      const int rg = (w * 2 + j) * 8 + srow;
      __builtin_amdgcn_global_load_lds(
          (const __attribute__((address_space(1))) unsigned int*)
              (Kp + (size_t)(tb + kt * 64 + rg) * 1024 + h * 64 + scol),
          (__attribute__((address_space(3))) unsigned int*)&Kls[buf][(w * 2 + j) * 8 * 64],
          16, 0, 0);
      __builtin_amdgcn_global_load_lds(
          (const __attribute__((address_space(1))) unsigned int*)
              (VT + (size_t)(h * 64 + rg) * 4096 + tb + kt * 64 + scol),
          (__attribute__((address_space(3))) unsigned int*)&Vls[buf][(w * 2 + j) * 8 * 64],
          16, 0, 0);
    }
  };

  // bpermute source byte-addrs for the P^T quad-pair exchange (constant)
  const int srcA = (((quad & 1) * 32 + l16) << 2);
  const int srcB = srcA + 64;
  const bool hiq = (quad >= 2);

  const int ktmax = 2 * qt + 1;
  stage(0, 0);
  __syncthreads();
  int buf = 0;
  for (int kt = 0; kt <= ktmax; ++kt) {
    bf16x8 kf[8], vf[8];
#pragma unroll
    for (int kk = 0; kk < 2; ++kk)
#pragma unroll
      for (int nt = 0; nt < 4; ++nt) {
        const int sl = (((kk * 4 + quad) ^ (l16 & 7)) * 8);
        kf[kk * 4 + nt] = *(const bf16x8*)&Kls[buf][(nt * 16 + l16) * 64 + sl];
        vf[kk * 4 + nt] = *(const bf16x8*)&Vls[buf][(nt * 16 + l16) * 64 + sl];
      }
    if (kt < ktmax) stage(buf ^ 1, kt + 1);

    const int k0 = kt * 64;
#pragma unroll
    for (int sub = 0; sub < 2; ++sub) {
      const int qbl = qb0 + sub * 16;       // wave-uniform
      if (k0 > qbl + 15) continue;          // fully masked subtile
      const bool partial = (k0 + 63 > qbl);

      f32x4 s[4];
#pragma unroll
      for (int nt = 0; nt < 4; ++nt) s[nt] = fz;
#pragma unroll
      for (int kk = 0; kk < 2; ++kk)
#pragma unroll
        for (int nt = 0; nt < 4; ++nt)
          if (!partial || (k0 + nt * 16 <= qbl + 15))  // skip fully-masked nt
            s[nt] = __builtin_amdgcn_mfma_f32_16x16x32_bf16(kf[kk * 4 + nt], qf[sub][kk], s[nt], 0, 0, 0);

      float mx = -1e30f;
#pragma unroll
      for (int nt = 0; nt < 4; ++nt)
#pragma unroll
        for (int i = 0; i < 4; ++i) {
          float v = s[nt][i];
          if (partial && (k0 + nt * 16 + quad * 4 + i) > (qbl + l16)) v = -1e30f;
          s[nt][i] = v;
          mx = fmaxf(mx, v);
        }
      mx = fmaxf(mx, __shfl_xor(mx, 16));
      mx = fmaxf(mx, __shfl_xor(mx, 32));
      const float mn = fmaxf(m_i[sub], mx);
      const float al = exp2f((m_i[sub] - mn) * C);
      m_i[sub] = mn;
      const float mC = mn * C;
      float rs = 0.f;
#pragma unroll
      for (int nt = 0; nt < 4; ++nt)
#pragma unroll
        for (int i = 0; i < 4; ++i) {
          const float p = exp2f(fmaf(s[nt][i], C, -mC));
          s[nt][i] = p;
          rs += p;
        }
      rs += __shfl_xor(rs, 16);
      rs += __shfl_xor(rs, 32);
      l_i[sub] = l_i[sub] * al + rs;
#pragma unroll
      for (int nt = 0; nt < 4; ++nt)
#pragma unroll
        for (int i = 0; i < 4; ++i) o_acc[sub][nt][i] *= al;

      unsigned pk[4][2];
#pragma unroll
      for (int nt = 0; nt < 4; ++nt) {
        pk[nt][0] = pk2(s[nt][0], s[nt][1]);
        pk[nt][1] = pk2(s[nt][2], s[nt][3]);
      }
#pragma unroll
      for (int kk = 0; kk < 2; ++kk) {
        const int ea = 2 * kk, eb = 2 * kk + 1;
        const unsigned u0 = __builtin_amdgcn_ds_bpermute(srcA, pk[ea][0]);
        const unsigned u1 = __builtin_amdgcn_ds_bpermute(srcA, pk[ea][1]);
        const unsigned u2 = __builtin_amdgcn_ds_bpermute(srcB, pk[ea][0]);
        const unsigned u3 = __builtin_amdgcn_ds_bpermute(srcB, pk[ea][1]);
        const unsigned w0 = __builtin_amdgcn_ds_bpermute(srcA, pk[eb][0]);
        const unsigned w1 = __builtin_amdgcn_ds_bpermute(srcA, pk[eb][1]);
        const unsigned w2 = __builtin_amdgcn_ds_bpermute(srcB, pk[eb][0]);
        const unsigned w3 = __builtin_amdgcn_ds_bpermute(srcB, pk[eb][1]);
        unsigned dw[4];
        dw[0] = hiq ? w0 : u0;
        dw[1] = hiq ? w1 : u1;
        dw[2] = hiq ? w2 : u2;
        dw[3] = hiq ? w3 : u3;
        const bf16x8 pf = *(const bf16x8*)dw;
#pragma unroll
        for (int nt = 0; nt < 4; ++nt)
          o_acc[sub][nt] = __builtin_amdgcn_mfma_f32_16x16x32_bf16(vf[kk * 4 + nt], pf, o_acc[sub][nt], 0, 0, 0);
      }
    }
    __syncthreads();  // drains prefetch vmcnt + guards LDS buffer swap
    buf ^= 1;
  }
  // epilogue: O^T regs -> O[token][d]; lane q = l16, d = nt*16 + quad*4 + i
#pragma unroll
  for (int sub = 0; sub < 2; ++sub) {
    const float inv = 1.0f / l_i[sub];
    unsigned short* orow = O + (size_t)(tb + qb0 + sub * 16 + l16) * 1024 + h * 64;
#pragma unroll
    for (int nt = 0; nt < 4; ++nt) {
      const unsigned d0 = pk2(o_acc[sub][nt][0] * inv, o_acc[sub][nt][1] * inv);
      const unsigned d1 = pk2(o_acc[sub][nt][2] * inv, o_acc[sub][nt][3] * inv);
      *(unsigned*)&orow[nt * 16 + quad * 4] = d0;
      *(unsigned*)&orow[nt * 16 + quad * 4 + 2] = d1;
    }
  }
}

// ---------------------------------------------------------------------------
extern "C" void kernel_launch(void* const* d_in, const int* in_sizes, int n_in,
                              void* d_out, int out_size, void* d_ws, size_t ws_size,
                              hipStream_t stream) {
  (void)in_sizes; (void)n_in; (void)out_size; (void)ws_size;
  const float* x      = (const float*)d_in[0];
  const float* f_qk   = (const float*)d_in[1];
  const float* f_v    = (const float*)d_in[2];
  const float* r_qk   = (const float*)d_in[3];
  const float* r_v    = (const float*)d_in[4];
  const float* f_know = (const float*)d_in[5];
  const float* r_know = (const float*)d_in[6];
  const float* W_O    = (const float*)d_in[7];
  const float* gamma1 = (const float*)d_in[8];
  const float* beta1  = (const float*)d_in[9];
  const float* gamma2 = (const float*)d_in[10];
  const float* beta2  = (const float*)d_in[11];
  const float* w_fq   = (const float*)d_in[12];
  const float* w_fk   = (const float*)d_in[13];
  const float* w_fv   = (const float*)d_in[14];
  const float* w_rq   = (const float*)d_in[15];
  const float* w_rk   = (const float*)d_in[16];
  const float* w_rv   = (const float*)d_in[17];
  const float* w_kf   = (const float*)d_in[18];
  const float* w_kr   = (const float*)d_in[19];

  char* base = (char*)d_ws;
  size_t off = 0;
  auto alloc = [&](size_t b) { char* p = base + off; off += (b + 255) & ~(size_t)255; return p; };
  unsigned short* fcomb   = (unsigned short*)alloc(8388608);   // [4096][1024]
  unsigned short* fknowT  = (unsigned short*)alloc(8388608);   // [4096][1024]
  unsigned short* r_qkT   = (unsigned short*)alloc(4194304);   // [1024][2048]
  unsigned short* r_vT    = (unsigned short*)alloc(4194304);   // [1024][2048]
  unsigned short* r_knowT = (unsigned short*)alloc(8388608);   // [1024][4096]
  unsigned short* WO_bf   = (unsigned short*)alloc(2097152);   // [1024][1024]
  unsigned short* nx_bf   = (unsigned short*)alloc(8388608);   // [4096][1024]
  unsigned short* all_h   = (unsigned short*)alloc(33554432);  // [4096][4096]
  unsigned short* t_qk    = (unsigned short*)alloc(33554432);  // [8192][2048]
  unsigned short* t_v     = (unsigned short*)alloc(16777216);  // [4096][2048]; reused as x1 fp32
  unsigned short* QKbuf   = (unsigned short*)alloc(16777216);  // [8192][1024]
  unsigned short* VT      = (unsigned short*)alloc(8388608);   // [1024][4096]
  unsigned short* attn    = (unsigned short*)alloc(8388608);   // [4096][1024]
  float* x1 = (float*)t_v;  // t_v dead before x1 written

  const dim3 blk256(256), blkT(32, 8);

  // weight preps
  transpose_bf<<<dim3(2, 32, 32), blkT, 0, stream>>>(f_qk, fcomb, 1024, 64);
  transpose_bf<<<dim3(2, 32, 32), blkT, 0, stream>>>(f_v, fcomb + (size_t)2048 * 1024, 1024, 64);
  transpose_bf<<<dim3(4, 32, 32), blkT, 0, stream>>>(f_know, fknowT, 1024, 128);
  transpose_bf<<<dim3(32, 64, 1), blkT, 0, stream>>>(r_qk, r_qkT, 2048, 1024);
  transpose_bf<<<dim3(32, 64, 1), blkT, 0, stream>>>(r_v, r_vT, 2048, 1024);
  transpose_bf<<<dim3(32, 128, 1), blkT, 0, stream>>>(r_know, r_knowT, 4096, 1024);
  convert_bf<<<4096, blk256, 0, stream>>>(W_O, WO_bf, 1048576);

  // attention circuit
  ln_kernel<<<4096, blk256, 0, stream>>>(x, gamma1, beta1, nx_bf);
  gemm_bt<<<dim3(32, 32), blk256, 0, stream>>>(nx_bf, fcomb, nullptr, all_h, 4096, 4096, 1024, 1);
  mix_attn<<<4096, blk256, 0, stream>>>(all_h, w_fq, w_fk, w_fv, w_rq, w_rk, w_rv, t_qk, t_v);
  gemm_qkv<<<dim3(8, 96), blk256, 0, stream>>>(t_qk, t_v, r_qkT, r_vT, QKbuf, VT);
  flash_attn<<<dim3(16, 32), blk256, 0, stream>>>(QKbuf, QKbuf + (size_t)4096 * 1024, VT, attn);
  gemm_bt<<<dim3(8, 32), blk256, 0, stream>>>(attn, WO_bf, x, x1, 4096, 1024, 1024, 2);

  // knowledge circuit
  ln_kernel<<<4096, blk256, 0, stream>>>(x1, gamma2, beta2, nx_bf);
  gemm_bt<<<dim3(32, 32), blk256, 0, stream>>>(nx_bf, fknowT, nullptr, all_h, 4096, 4096, 1024, 1);
  mix_know<<<4096, blk256, 0, stream>>>(all_h, w_kf, w_kr, t_qk);
  gemm_bt<<<dim3(8, 32), blk256, 0, stream>>>(t_qk, r_knowT, x1, (float*)d_out, 4096, 1024, 4096, 2);
}

// Round 6
// 649.348 us; speedup vs baseline: 1.0740x; 1.0740x over previous
//
#include <hip/hip_runtime.h>
#include <stdint.h>

// B=2,S=2048,D=1024,H=16,R=64,N=32,RK=128,DH=64. Tokens T=4096.

typedef __bf16 bf16x8 __attribute__((ext_vector_type(8)));
typedef float f32x4 __attribute__((ext_vector_type(4)));

__device__ __forceinline__ unsigned short f2b(float f) {
  union { float f; unsigned u; } v; v.f = f;
  unsigned u = v.u;
  unsigned r = (u + 0x7FFFu + ((u >> 16) & 1u)) >> 16;  // RNE
  return (unsigned short)r;
}
__device__ __forceinline__ float b2f(unsigned short h) {
  union { unsigned u; float f; } v; v.u = ((unsigned)h) << 16;
  return v.f;
}
__device__ __forceinline__ unsigned pk2(float lo, float hi) {
  return (unsigned)f2b(lo) | ((unsigned)f2b(hi) << 16);
}

// ---------------------------------------------------------------------------
// Generic bf16 GEMM: C[M,N] = A[M,K] @ Bt[N,K]^T.  128x128 tile, BK=64,
// 256 threads (4 waves, 2x2 of 64x64), 16x16x32 MFMA, global_load_lds x16.
// mode 0: fp32 out; 1: bf16 out; 2: fp32 out + res; 3: bf16 transposed out[N,M]
// ---------------------------------------------------------------------------
__global__ __launch_bounds__(256) void gemm_bt(
    const unsigned short* __restrict__ A, const unsigned short* __restrict__ Bt,
    const float* __restrict__ res, void* __restrict__ out,
    int M, int N, int K, int mode) {
  __shared__ unsigned short lsA[128 * 64];
  __shared__ unsigned short lsB[128 * 64];
  const int tid = threadIdx.x;
  const int w = tid >> 6, lane = tid & 63;
  const int quad = lane >> 4, l16 = lane & 15;
  const int wr = w >> 1, wc = w & 1;
  const int row0 = blockIdx.y * 128;
  const int col0 = blockIdx.x * 128;

  const int srow = w * 32 + (lane >> 3);
  const int scg = (lane & 7) * 8;
  const unsigned short* ap = A + (size_t)(row0 + srow) * K + scg;
  const unsigned short* bp = Bt + (size_t)(col0 + srow) * K + scg;

  const f32x4 fz = {0.f, 0.f, 0.f, 0.f};
  f32x4 acc[4][4];
#pragma unroll
  for (int i = 0; i < 4; ++i)
#pragma unroll
    for (int j = 0; j < 4; ++j) acc[i][j] = fz;

  for (int k0 = 0; k0 < K; k0 += 64) {
#pragma unroll
    for (int i = 0; i < 4; ++i) {
      __builtin_amdgcn_global_load_lds(
          (const __attribute__((address_space(1))) unsigned int*)(ap + (size_t)i * 8 * K + k0),
          (__attribute__((address_space(3))) unsigned int*)&lsA[(w * 32 + i * 8) * 64],
          16, 0, 0);
      __builtin_amdgcn_global_load_lds(
          (const __attribute__((address_space(1))) unsigned int*)(bp + (size_t)i * 8 * K + k0),
          (__attribute__((address_space(3))) unsigned int*)&lsB[(w * 32 + i * 8) * 64],
          16, 0, 0);
    }
    __syncthreads();
#pragma unroll
    for (int kk = 0; kk < 2; ++kk) {
      bf16x8 af[4], bfr[4];
#pragma unroll
      for (int mt = 0; mt < 4; ++mt)
        af[mt] = *(const bf16x8*)&lsA[(wr * 64 + mt * 16 + l16) * 64 + kk * 32 + quad * 8];
#pragma unroll
      for (int nt = 0; nt < 4; ++nt)
        bfr[nt] = *(const bf16x8*)&lsB[(wc * 64 + nt * 16 + l16) * 64 + kk * 32 + quad * 8];
#pragma unroll
      for (int mt = 0; mt < 4; ++mt)
#pragma unroll
        for (int nt = 0; nt < 4; ++nt)
          acc[mt][nt] = __builtin_amdgcn_mfma_f32_16x16x32_bf16(af[mt], bfr[nt], acc[mt][nt], 0, 0, 0);
    }
    __syncthreads();
  }

  const int rb = row0 + wr * 64;
  const int cb = col0 + wc * 64;
#pragma unroll
  for (int mt = 0; mt < 4; ++mt) {
#pragma unroll
    for (int nt = 0; nt < 4; ++nt) {
      const int r = rb + mt * 16 + quad * 4;
      const int c = cb + nt * 16 + l16;
#pragma unroll
      for (int i = 0; i < 4; ++i) {
        const float v = acc[mt][nt][i];
        const size_t idx = (size_t)(r + i) * N + c;
        if (mode == 0) ((float*)out)[idx] = v;
        else if (mode == 1) ((unsigned short*)out)[idx] = f2b(v);
        else if (mode == 2) ((float*)out)[idx] = v + res[idx];
        else ((unsigned short*)out)[(size_t)c * M + (r + i)] = f2b(v);
      }
    }
  }
}

// ---------------------------------------------------------------------------
// Fused Q/K + V restore GEMM (one dispatch, 768 blocks).
// by<64: QKbuf[row,col] (M=8192, A=t_qk);  by>=64: VT[col, row] (M=4096, A=t_v)
// ---------------------------------------------------------------------------
__global__ __launch_bounds__(256) void gemm_qkv(
    const unsigned short* __restrict__ t_qk, const unsigned short* __restrict__ t_v,
    const unsigned short* __restrict__ r_qkT, const unsigned short* __restrict__ r_vT,
    unsigned short* __restrict__ QKbuf, unsigned short* __restrict__ VT) {
  __shared__ unsigned short lsA[128 * 64];
  __shared__ unsigned short lsB[128 * 64];
  const int K = 2048;
  const bool isV = blockIdx.y >= 64;
  const unsigned short* A  = isV ? t_v : t_qk;
  const unsigned short* Bt = isV ? r_vT : r_qkT;
  const int row0 = (isV ? ((int)blockIdx.y - 64) : (int)blockIdx.y) * 128;
  const int col0 = blockIdx.x * 128;
  const int tid = threadIdx.x;
  const int w = tid >> 6, lane = tid & 63;
  const int quad = lane >> 4, l16 = lane & 15;
  const int wr = w >> 1, wc = w & 1;

  const int srow = w * 32 + (lane >> 3);
  const int scg = (lane & 7) * 8;
  const unsigned short* ap = A + (size_t)(row0 + srow) * K + scg;
  const unsigned short* bp = Bt + (size_t)(col0 + srow) * K + scg;

  const f32x4 fz = {0.f, 0.f, 0.f, 0.f};
  f32x4 acc[4][4];
#pragma unroll
  for (int i = 0; i < 4; ++i)
#pragma unroll
    for (int j = 0; j < 4; ++j) acc[i][j] = fz;

  for (int k0 = 0; k0 < K; k0 += 64) {
#pragma unroll
    for (int i = 0; i < 4; ++i) {
      __builtin_amdgcn_global_load_lds(
          (const __attribute__((address_space(1))) unsigned int*)(ap + (size_t)i * 8 * K + k0),
          (__attribute__((address_space(3))) unsigned int*)&lsA[(w * 32 + i * 8) * 64],
          16, 0, 0);
      __builtin_amdgcn_global_load_lds(
          (const __attribute__((address_space(1))) unsigned int*)(bp + (size_t)i * 8 * K + k0),
          (__attribute__((address_space(3))) unsigned int*)&lsB[(w * 32 + i * 8) * 64],
          16, 0, 0);
    }
    __syncthreads();
#pragma unroll
    for (int kk = 0; kk < 2; ++kk) {
      bf16x8 af[4], bfr[4];
#pragma unroll
      for (int mt = 0; mt < 4; ++mt)
        af[mt] = *(const bf16x8*)&lsA[(wr * 64 + mt * 16 + l16) * 64 + kk * 32 + quad * 8];
#pragma unroll
      for (int nt = 0; nt < 4; ++nt)
        bfr[nt] = *(const bf16x8*)&lsB[(wc * 64 + nt * 16 + l16) * 64 + kk * 32 + quad * 8];
#pragma unroll
      for (int mt = 0; mt < 4; ++mt)
#pragma unroll
        for (int nt = 0; nt < 4; ++nt)
          acc[mt][nt] = __builtin_amdgcn_mfma_f32_16x16x32_bf16(af[mt], bfr[nt], acc[mt][nt], 0, 0, 0);
    }
    __syncthreads();
  }

  const int rb = row0 + wr * 64;
  const int cb = col0 + wc * 64;
#pragma unroll
  for (int mt = 0; mt < 4; ++mt) {
#pragma unroll
    for (int nt = 0; nt < 4; ++nt) {
      const int r = rb + mt * 16 + quad * 4;
      const int c = cb + nt * 16 + l16;
#pragma unroll
      for (int i = 0; i < 4; ++i) {
        const float v = acc[mt][nt][i];
        if (!isV) QKbuf[(size_t)(r + i) * 1024 + c] = f2b(v);
        else VT[(size_t)c * 4096 + (r + i)] = f2b(v);
      }
    }
  }
}

// ---------------------------------------------------------------------------
// LayerNorm over D=1024, one token per 256-thread block, bf16 out.
// ---------------------------------------------------------------------------
__global__ __launch_bounds__(256) void ln_kernel(
    const float* __restrict__ x, const float* __restrict__ g,
    const float* __restrict__ be, unsigned short* __restrict__ out) {
  __shared__ float sbuf[4];
  const int t = blockIdx.x, tid = threadIdx.x;
  const float* row = x + (size_t)t * 1024;
  float v[4], s = 0.f;
#pragma unroll
  for (int j = 0; j < 4; ++j) { v[j] = row[tid + j * 256]; s += v[j]; }
#pragma unroll
  for (int off = 32; off; off >>= 1) s += __shfl_xor(s, off);
  if ((tid & 63) == 0) sbuf[tid >> 6] = s;
  __syncthreads();
  const float mu = (sbuf[0] + sbuf[1] + sbuf[2] + sbuf[3]) * (1.f / 1024.f);
  __syncthreads();
  float ss = 0.f;
#pragma unroll
  for (int j = 0; j < 4; ++j) { const float d = v[j] - mu; ss += d * d; }
#pragma unroll
  for (int off = 32; off; off >>= 1) ss += __shfl_xor(ss, off);
  if ((tid & 63) == 0) sbuf[tid >> 6] = ss;
  __syncthreads();
  const float var = (sbuf[0] + sbuf[1] + sbuf[2] + sbuf[3]) * (1.f / 1024.f);
  const float rstd = rsqrtf(var + 1e-5f);
  unsigned short* orow = out + (size_t)t * 1024;
#pragma unroll
  for (int j = 0; j < 4; ++j) {
    const int c = tid + j * 256;
    orow[c] = f2b((v[j] - mu) * rstd * g[c] + be[c]);
  }
}

// ---------------------------------------------------------------------------
// Attention mixing: h_{q,k,v}[r] = sum_n w_f*[n]*all_h[t, (base)+n*64+r];
// t_*[t, n*64+r] = w_r*[n]*h_*[r].  all_h cols: [0,2048)=f_qk, [2048,4096)=f_v.
// ---------------------------------------------------------------------------
__global__ __launch_bounds__(256) void mix_attn(
    const unsigned short* __restrict__ all_h,
    const float* __restrict__ w_fq, const float* __restrict__ w_fk,
    const float* __restrict__ w_fv, const float* __restrict__ w_rq,
    const float* __restrict__ w_rk, const float* __restrict__ w_rv,
    unsigned short* __restrict__ t_qk, unsigned short* __restrict__ t_v) {
  __shared__ float hq[64], hk[64], hv[64];
  const int t = blockIdx.x, tid = threadIdx.x;
  const int wv = tid >> 6, lane = tid & 63;
  const unsigned short* row = all_h + (size_t)t * 4096;
  if (wv < 3) {
    const float* wf = (wv == 0 ? w_fq : wv == 1 ? w_fk : w_fv) + (size_t)t * 32;
    const int base = (wv == 2) ? 2048 : 0;
    float acc = 0.f;
#pragma unroll
    for (int n = 0; n < 32; ++n) acc += wf[n] * b2f(row[base + n * 64 + lane]);
    (wv == 0 ? hq : wv == 1 ? hk : hv)[lane] = acc;
  }
  __syncthreads();
  const float* wrq = w_rq + (size_t)t * 32;
  const float* wrk = w_rk + (size_t)t * 32;
  const float* wrv = w_rv + (size_t)t * 32;
  for (int idx = tid; idx < 2048; idx += 256) {
    const int n = idx >> 6, r = idx & 63;
    t_qk[(size_t)t * 2048 + idx] = f2b(wrq[n] * hq[r]);
    t_qk[(size_t)(4096 + t) * 2048 + idx] = f2b(wrk[n] * hk[r]);
    t_v[(size_t)t * 2048 + idx] = f2b(wrv[n] * hv[r]);
  }
}

// Knowledge mixing (RK=128): h[r]=sum_n w_f[n]*all_h[t,n*128+r]; t_know=w_r[n]*h[r]
__global__ __launch_bounds__(256) void mix_know(
    const unsigned short* __restrict__ all_h, const float* __restrict__ w_f,
    const float* __restrict__ w_r, unsigned short* __restrict__ t_know) {
  __shared__ float h[128];
  const int t = blockIdx.x, tid = threadIdx.x;
  const unsigned short* row = all_h + (size_t)t * 4096;
  if (tid < 128) {
    const float* wf = w_f + (size_t)t * 32;
    float acc = 0.f;
#pragma unroll
    for (int n = 0; n < 32; ++n) acc += wf[n] * b2f(row[n * 128 + tid]);
    h[tid] = acc;
  }
  __syncthreads();
  const float* wr = w_r + (size_t)t * 32;
  for (int idx = tid; idx < 4096; idx += 256) {
    const int n = idx >> 7, r = idx & 127;
    t_know[(size_t)t * 4096 + idx] = f2b(wr[n] * h[r]);
  }
}

// ---------------------------------------------------------------------------
// Batched transpose + fp32->bf16: in [batch][R][C] f32 -> out [batch][C][R] bf16
// ---------------------------------------------------------------------------
__global__ __launch_bounds__(256) void transpose_bf(
    const float* __restrict__ in, unsigned short* __restrict__ out, int R, int C) {
  __shared__ float tile[32][33];
  const int bb = blockIdx.z;
  const int c0 = blockIdx.x * 32, r0 = blockIdx.y * 32;
  const int tx = threadIdx.x, ty = threadIdx.y;
  const float* ip = in + (size_t)bb * R * C;
  unsigned short* op = out + (size_t)bb * R * C;
#pragma unroll
  for (int j = 0; j < 4; ++j)
    tile[ty + j * 8][tx] = ip[(size_t)(r0 + ty + j * 8) * C + c0 + tx];
  __syncthreads();
#pragma unroll
  for (int j = 0; j < 4; ++j)
    op[(size_t)(c0 + ty + j * 8) * R + r0 + tx] = f2b(tile[tx][ty + j * 8]);
}

__global__ __launch_bounds__(256) void convert_bf(
    const float* __restrict__ in, unsigned short* __restrict__ out, int n) {
  const int i = blockIdx.x * 256 + threadIdx.x;
  if (i < n) out[i] = f2b(in[i]);
}

// ---------------------------------------------------------------------------
// Causal flash attention v6: SPLIT-K over history, uniform work units.
// Unit = one 64-q tile x <=8 k-tiles (512 tokens). 80 units per (b,h) column.
// qt<=7 (single chunk): write attn directly. Else write fp32 partial
// (O', m, l) for flash_reduce. v4 transposed-algebra core:
//   S^T = K*Q^T; per-lane softmax (2 shuffles); O^T = V^T*P^T via bpermute.
// ---------------------------------------------------------------------------
__global__ __launch_bounds__(256) void flash_split(
    const unsigned short* __restrict__ Q, const unsigned short* __restrict__ Kp,
    const unsigned short* __restrict__ VT, unsigned short* __restrict__ O,
    float* __restrict__ Opart, float* __restrict__ ml) {
  __shared__ unsigned short Kls[2][64 * 64];
  __shared__ unsigned short Vls[2][64 * 64];
  // unit decode (descending unit id -> longest chunks dispatch first)
  const int uidx = 79 - (int)blockIdx.x;
  int uu = uidx, qt = 0, ch = 0;
  for (int q = 0; q < 32; ++q) {
    const int n = (q >> 3) + 1;
    if (uu < n) { qt = q; ch = uu; break; }
    uu -= n;
  }
  const int bh = blockIdx.y;
  const int b = bh >> 4, h = bh & 15;
  const int tid = threadIdx.x;
  const int w = tid >> 6, lane = tid & 63, quad = lane >> 4, l16 = lane & 15;
  const int tb = b * 2048;
  const int qrow = qt * 64 + w * 16;
  const int ktlo = ch * 8;
  const int kthi = min(qt, ch * 8 + 7);
  const float C = 0.18033688f;  // (1/sqrt(64)) * log2(e)

  const int srow = (lane >> 3);
  const int scol = ((lane & 7) ^ srow) * 8;  // XOR-swizzled chunk

  bf16x8 qf[2];
#pragma unroll
  for (int kk = 0; kk < 2; ++kk)
    qf[kk] = *(const bf16x8*)&Q[(size_t)(tb + qrow + l16) * 1024 + h * 64 + kk * 32 + quad * 8];

  const f32x4 fz = {0.f, 0.f, 0.f, 0.f};
  float m_i = -1e30f, l_i = 0.f;
  f32x4 o_acc[4];
#pragma unroll
  for (int nt = 0; nt < 4; ++nt) o_acc[nt] = fz;

  auto stage = [&](int buf, int kt) {
#pragma unroll
    for (int j = 0; j < 2; ++j) {
      const int rg = (w * 2 + j) * 8 + srow;
      __builtin_amdgcn_global_load_lds(
          (const __attribute__((address_space(1))) unsigned int*)
              (Kp + (size_t)(tb + kt * 64 + rg) * 1024 + h * 64 + scol),
          (__attribute__((address_space(3))) unsigned int*)&Kls[buf][(w * 2 + j) * 8 * 64],
          16, 0, 0);
      __builtin_amdgcn_global_load_lds(
          (const __attribute__((address_space(1))) unsigned int*)
              (VT + (size_t)(h * 64 + rg) * 4096 + tb + kt * 64 + scol),
          (__attribute__((address_space(3))) unsigned int*)&Vls[buf][(w * 2 + j) * 8 * 64],
          16, 0, 0);
    }
  };

  const int srcA = (((quad & 1) * 32 + l16) << 2);
  const int srcB = srcA + 64;
  const bool hiq = (quad >= 2);

  stage(0, ktlo);
  __syncthreads();
  int buf = 0;
  for (int kt = ktlo; kt <= kthi; ++kt) {
    bf16x8 kf[8], vf[8];
#pragma unroll
    for (int kk = 0; kk < 2; ++kk)
#pragma unroll
      for (int nt = 0; nt < 4; ++nt) {
        const int sl = (((kk * 4 + quad) ^ (l16 & 7)) * 8);
        kf[kk * 4 + nt] = *(const bf16x8*)&Kls[buf][(nt * 16 + l16) * 64 + sl];
        vf[kk * 4 + nt] = *(const bf16x8*)&Vls[buf][(nt * 16 + l16) * 64 + sl];
      }
    if (kt < kthi) stage(buf ^ 1, kt + 1);

    const bool diag = (kt == qt);
    f32x4 s[4];
#pragma unroll
    for (int nt = 0; nt < 4; ++nt) s[nt] = fz;
#pragma unroll
    for (int kk = 0; kk < 2; ++kk)
#pragma unroll
      for (int nt = 0; nt < 4; ++nt)
        if (!diag || nt <= w)
          s[nt] = __builtin_amdgcn_mfma_f32_16x16x32_bf16(kf[kk * 4 + nt], qf[kk], s[nt], 0, 0, 0);

    const int qloc = w * 16 + l16;
    float mx = -1e30f;
#pragma unroll
    for (int nt = 0; nt < 4; ++nt)
#pragma unroll
      for (int i = 0; i < 4; ++i) {
        float v = s[nt][i];
        if (diag && (nt * 16 + quad * 4 + i) > qloc) v = -1e30f;
        s[nt][i] = v;
        mx = fmaxf(mx, v);
      }
    mx = fmaxf(mx, __shfl_xor(mx, 16));
    mx = fmaxf(mx, __shfl_xor(mx, 32));
    const float mn = fmaxf(m_i, mx);
    const float al = exp2f((m_i - mn) * C);
    m_i = mn;
    const float mC = mn * C;
    float rs = 0.f;
#pragma unroll
    for (int nt = 0; nt < 4; ++nt)
#pragma unroll
      for (int i = 0; i < 4; ++i) {
        const float p = exp2f(fmaf(s[nt][i], C, -mC));
        s[nt][i] = p;
        rs += p;
      }
    rs += __shfl_xor(rs, 16);
    rs += __shfl_xor(rs, 32);
    l_i = l_i * al + rs;
#pragma unroll
    for (int nt = 0; nt < 4; ++nt)
#pragma unroll
      for (int i = 0; i < 4; ++i) o_acc[nt][i] *= al;

    unsigned pk[4][2];
#pragma unroll
    for (int nt = 0; nt < 4; ++nt) {
      pk[nt][0] = pk2(s[nt][0], s[nt][1]);
      pk[nt][1] = pk2(s[nt][2], s[nt][3]);
    }
#pragma unroll
    for (int kk = 0; kk < 2; ++kk) {
      const int ea = 2 * kk, eb = 2 * kk + 1;
      const unsigned u0 = __builtin_amdgcn_ds_bpermute(srcA, pk[ea][0]);
      const unsigned u1 = __builtin_amdgcn_ds_bpermute(srcA, pk[ea][1]);
      const unsigned u2 = __builtin_amdgcn_ds_bpermute(srcB, pk[ea][0]);
      const unsigned u3 = __builtin_amdgcn_ds_bpermute(srcB, pk[ea][1]);
      const unsigned w0 = __builtin_amdgcn_ds_bpermute(srcA, pk[eb][0]);
      const unsigned w1 = __builtin_amdgcn_ds_bpermute(srcA, pk[eb][1]);
      const unsigned w2 = __builtin_amdgcn_ds_bpermute(srcB, pk[eb][0]);
      const unsigned w3 = __builtin_amdgcn_ds_bpermute(srcB, pk[eb][1]);
      unsigned dw[4];
      dw[0] = hiq ? w0 : u0;
      dw[1] = hiq ? w1 : u1;
      dw[2] = hiq ? w2 : u2;
      dw[3] = hiq ? w3 : u3;
      const bf16x8 pf = *(const bf16x8*)dw;
#pragma unroll
      for (int nt = 0; nt < 4; ++nt)
        o_acc[nt] = __builtin_amdgcn_mfma_f32_16x16x32_bf16(vf[kk * 4 + nt], pf, o_acc[nt], 0, 0, 0);
    }
    __syncthreads();
    buf ^= 1;
  }

  const int nch = (qt >> 3) + 1;
  if (nch == 1) {
    // single chunk: finalize directly
    const float inv = 1.0f / l_i;
    unsigned short* orow = O + (size_t)(tb + qrow + l16) * 1024 + h * 64;
#pragma unroll
    for (int nt = 0; nt < 4; ++nt) {
      const unsigned d0 = pk2(o_acc[nt][0] * inv, o_acc[nt][1] * inv);
      const unsigned d1 = pk2(o_acc[nt][2] * inv, o_acc[nt][3] * inv);
      *(unsigned*)&orow[nt * 16 + quad * 4] = d0;
      *(unsigned*)&orow[nt * 16 + quad * 4 + 2] = d1;
    }
  } else {
    // partial: O' fp32 [slot][lq][d], ml [slot][lq] = (m,l)
    const int slot = bh * 80 + uidx;
    const int lq = w * 16 + l16;
    float* op = Opart + ((size_t)slot * 64 + lq) * 64;
#pragma unroll
    for (int nt = 0; nt < 4; ++nt)
      *(f32x4*)&op[nt * 16 + quad * 4] = o_acc[nt];
    if (quad == 0) {
      ml[(size_t)slot * 128 + lq * 2] = m_i;
      ml[(size_t)slot * 128 + lq * 2 + 1] = l_i;
    }
  }
}

// ---------------------------------------------------------------------------
// Combine split-K partials for qt in [8,31]. Grid (24, 32), 256 threads.
// Thread: lq = tid>>2 (0..63), d-chunk = (tid&3)*16.
// ---------------------------------------------------------------------------
__global__ __launch_bounds__(256) void flash_reduce(
    const float* __restrict__ Opart, const float* __restrict__ ml,
    unsigned short* __restrict__ O) {
  const int qt = 8 + blockIdx.x;
  const int bh = blockIdx.y;
  const int b = bh >> 4, h = bh & 15;
  const int j = qt >> 3;                       // 1..3
  const int base = 8 * (j * (j + 1) / 2) + (qt - 8 * j) * (j + 1);
  const int nch = j + 1;
  const int tid = threadIdx.x;
  const int lq = tid >> 2, dq = (tid & 3) * 16;
  const float C = 0.18033688f;

  float mc[4], lc[4];
  float m = -1e30f;
#pragma unroll
  for (int c = 0; c < 4; ++c) {
    if (c < nch) {
      const size_t sl = (size_t)(bh * 80 + base + c) * 128 + lq * 2;
      mc[c] = ml[sl];
      lc[c] = ml[sl + 1];
    } else { mc[c] = -1e30f; lc[c] = 0.f; }
    m = fmaxf(m, mc[c]);
  }
  float fac[4], lt = 0.f;
#pragma unroll
  for (int c = 0; c < 4; ++c) {
    fac[c] = (c < nch) ? exp2f((mc[c] - m) * C) : 0.f;
    lt += fac[c] * lc[c];
  }
  const float inv = 1.0f / lt;
  float acc[16];
#pragma unroll
  for (int i = 0; i < 16; ++i) acc[i] = 0.f;
#pragma unroll
  for (int c = 0; c < 4; ++c) {
    if (c >= nch) continue;
    const float* op = Opart + ((size_t)(bh * 80 + base + c) * 64 + lq) * 64 + dq;
#pragma unroll
    for (int i = 0; i < 16; i += 4) {
      const f32x4 v = *(const f32x4*)&op[i];
#pragma unroll
      for (int k = 0; k < 4; ++k) acc[i + k] += fac[c] * v[k];
    }
  }
  unsigned short* orow = O + (size_t)(b * 2048 + qt * 64 + lq) * 1024 + h * 64 + dq;
#pragma unroll
  for (int i = 0; i < 16; i += 2)
    *(unsigned*)&orow[i] = pk2(acc[i] * inv, acc[i + 1] * inv);
}

// ---------------------------------------------------------------------------
extern "C" void kernel_launch(void* const* d_in, const int* in_sizes, int n_in,
                              void* d_out, int out_size, void* d_ws, size_t ws_size,
                              hipStream_t stream) {
  (void)in_sizes; (void)n_in; (void)out_size; (void)ws_size;
  const float* x      = (const float*)d_in[0];
  const float* f_qk   = (const float*)d_in[1];
  const float* f_v    = (const float*)d_in[2];
  const float* r_qk   = (const float*)d_in[3];
  const float* r_v    = (const float*)d_in[4];
  const float* f_know = (const float*)d_in[5];
  const float* r_know = (const float*)d_in[6];
  const float* W_O    = (const float*)d_in[7];
  const float* gamma1 = (const float*)d_in[8];
  const float* beta1  = (const float*)d_in[9];
  const float* gamma2 = (const float*)d_in[10];
  const float* beta2  = (const float*)d_in[11];
  const float* w_fq   = (const float*)d_in[12];
  const float* w_fk   = (const float*)d_in[13];
  const float* w_fv   = (const float*)d_in[14];
  const float* w_rq   = (const float*)d_in[15];
  const float* w_rk   = (const float*)d_in[16];
  const float* w_rv   = (const float*)d_in[17];
  const float* w_kf   = (const float*)d_in[18];
  const float* w_kr   = (const float*)d_in[19];

  char* base = (char*)d_ws;
  size_t off = 0;
  auto alloc = [&](size_t b) { char* p = base + off; off += (b + 255) & ~(size_t)255; return p; };
  unsigned short* fcomb   = (unsigned short*)alloc(8388608);   // [4096][1024]
  unsigned short* fknowT  = (unsigned short*)alloc(8388608);   // [4096][1024]
  unsigned short* r_qkT   = (unsigned short*)alloc(4194304);   // [1024][2048]
  unsigned short* r_vT    = (unsigned short*)alloc(4194304);   // [1024][2048]
  unsigned short* r_knowT = (unsigned short*)alloc(8388608);   // [1024][4096]
  unsigned short* WO_bf   = (unsigned short*)alloc(2097152);   // [1024][1024]
  unsigned short* nx_bf   = (unsigned short*)alloc(8388608);   // [4096][1024]
  unsigned short* all_h   = (unsigned short*)alloc(33554432);  // [4096][4096]
  unsigned short* t_qk    = (unsigned short*)alloc(33554432);  // [8192][2048]
  unsigned short* t_v     = (unsigned short*)alloc(16777216);  // [4096][2048]; reused as x1 fp32
  unsigned short* QKbuf   = (unsigned short*)alloc(16777216);  // [8192][1024]
  unsigned short* VT      = (unsigned short*)alloc(8388608);   // [1024][4096]
  unsigned short* attn    = (unsigned short*)alloc(8388608);   // [4096][1024]
  float* x1 = (float*)t_v;  // t_v dead before x1 written
  // split-K partials alias the dead all_h+t_qk region during attention:
  // Opart 2560*64*64*4 = 41.94 MB; ml 1.31 MB; region is 67.1 MB contiguous.
  float* Opart = (float*)all_h;
  float* mlbuf = (float*)(all_h + 20971520);  // byte offset 41943040

  const dim3 blk256(256), blkT(32, 8);

  // weight preps
  transpose_bf<<<dim3(2, 32, 32), blkT, 0, stream>>>(f_qk, fcomb, 1024, 64);
  transpose_bf<<<dim3(2, 32, 32), blkT, 0, stream>>>(f_v, fcomb + (size_t)2048 * 1024, 1024, 64);
  transpose_bf<<<dim3(4, 32, 32), blkT, 0, stream>>>(f_know, fknowT, 1024, 128);
  transpose_bf<<<dim3(32, 64, 1), blkT, 0, stream>>>(r_qk, r_qkT, 2048, 1024);
  transpose_bf<<<dim3(32, 64, 1), blkT, 0, stream>>>(r_v, r_vT, 2048, 1024);
  transpose_bf<<<dim3(32, 128, 1), blkT, 0, stream>>>(r_know, r_knowT, 4096, 1024);
  convert_bf<<<4096, blk256, 0, stream>>>(W_O, WO_bf, 1048576);

  // attention circuit
  ln_kernel<<<4096, blk256, 0, stream>>>(x, gamma1, beta1, nx_bf);
  gemm_bt<<<dim3(32, 32), blk256, 0, stream>>>(nx_bf, fcomb, nullptr, all_h, 4096, 4096, 1024, 1);
  mix_attn<<<4096, blk256, 0, stream>>>(all_h, w_fq, w_fk, w_fv, w_rq, w_rk, w_rv, t_qk, t_v);
  gemm_qkv<<<dim3(8, 96), blk256, 0, stream>>>(t_qk, t_v, r_qkT, r_vT, QKbuf, VT);
  flash_split<<<dim3(80, 32), blk256, 0, stream>>>(QKbuf, QKbuf + (size_t)4096 * 1024, VT, attn,
                                                   Opart, mlbuf);
  flash_reduce<<<dim3(24, 32), blk256, 0, stream>>>(Opart, mlbuf, attn);
  gemm_bt<<<dim3(8, 32), blk256, 0, stream>>>(attn, WO_bf, x, x1, 4096, 1024, 1024, 2);

  // knowledge circuit
  ln_kernel<<<4096, blk256, 0, stream>>>(x1, gamma2, beta2, nx_bf);
  gemm_bt<<<dim3(32, 32), blk256, 0, stream>>>(nx_bf, fknowT, nullptr, all_h, 4096, 4096, 1024, 1);
  mix_know<<<4096, blk256, 0, stream>>>(all_h, w_kf, w_kr, t_qk);
  gemm_bt<<<dim3(8, 32), blk256, 0, stream>>>(t_qk, r_knowT, x1, (float*)d_out, 4096, 1024, 4096, 2);
}

// Round 7
// 602.010 us; speedup vs baseline: 1.1584x; 1.0786x over previous
//
#include <hip/hip_runtime.h>
#include <stdint.h>

// B=2,S=2048,D=1024,H=16,R=64,N=32,RK=128,DH=64. Tokens T=4096.

typedef __bf16 bf16x8 __attribute__((ext_vector_type(8)));
typedef float f32x4 __attribute__((ext_vector_type(4)));

__device__ __forceinline__ unsigned short f2b(float f) {
  union { float f; unsigned u; } v; v.f = f;
  unsigned u = v.u;
  unsigned r = (u + 0x7FFFu + ((u >> 16) & 1u)) >> 16;  // RNE
  return (unsigned short)r;
}
__device__ __forceinline__ float b2f(unsigned short h) {
  union { unsigned u; float f; } v; v.u = ((unsigned)h) << 16;
  return v.f;
}
__device__ __forceinline__ unsigned pk2(float lo, float hi) {
  return (unsigned)f2b(lo) | ((unsigned)f2b(hi) << 16);
}

// ---------------------------------------------------------------------------
// Generic bf16 GEMM: C[M,N] = A[M,K] @ Bt[N,K]^T.  128x128 tile, BK=64,
// 256 threads, 16x16x32 MFMA, global_load_lds x16, XOR-swizzled LDS
// (conflict-free ds_read_b128). band>0: XCD row-banding remap (rows = 8*band).
// mode 0: fp32 out; 1: bf16 out; 2: fp32 out + res; 3: bf16 transposed out[N,M]
// ---------------------------------------------------------------------------
__global__ __launch_bounds__(256) void gemm_bt(
    const unsigned short* __restrict__ A, const unsigned short* __restrict__ Bt,
    const float* __restrict__ res, void* __restrict__ out,
    int M, int N, int K, int mode, int band) {
  __shared__ unsigned short lsA[128 * 64];
  __shared__ unsigned short lsB[128 * 64];
  const int tid = threadIdx.x;
  const int w = tid >> 6, lane = tid & 63;
  const int quad = lane >> 4, l16 = lane & 15;
  const int wr = w >> 1, wc = w & 1;
  int bx = blockIdx.x, by = blockIdx.y;
  if (band > 0) {  // XCD banding: xcd owns `band` contiguous rows, cols fastest
    const int bid = by * gridDim.x + bx;
    const int xcd = bid & 7, j = bid >> 3;
    by = xcd * band + j / gridDim.x;
    bx = j % gridDim.x;
  }
  const int row0 = by * 128;
  const int col0 = bx * 128;

  const int srow = w * 32 + (lane >> 3);
  const int scg = ((lane & 7) ^ (lane >> 3)) * 8;  // source-side XOR swizzle
  const unsigned short* ap = A + (size_t)(row0 + srow) * K + scg;
  const unsigned short* bp = Bt + (size_t)(col0 + srow) * K + scg;

  const f32x4 fz = {0.f, 0.f, 0.f, 0.f};
  f32x4 acc[4][4];
#pragma unroll
  for (int i = 0; i < 4; ++i)
#pragma unroll
    for (int j = 0; j < 4; ++j) acc[i][j] = fz;

  for (int k0 = 0; k0 < K; k0 += 64) {
#pragma unroll
    for (int i = 0; i < 4; ++i) {
      __builtin_amdgcn_global_load_lds(
          (const __attribute__((address_space(1))) unsigned int*)(ap + (size_t)i * 8 * K + k0),
          (__attribute__((address_space(3))) unsigned int*)&lsA[(w * 32 + i * 8) * 64],
          16, 0, 0);
      __builtin_amdgcn_global_load_lds(
          (const __attribute__((address_space(1))) unsigned int*)(bp + (size_t)i * 8 * K + k0),
          (__attribute__((address_space(3))) unsigned int*)&lsB[(w * 32 + i * 8) * 64],
          16, 0, 0);
    }
    __syncthreads();
#pragma unroll
    for (int kk = 0; kk < 2; ++kk) {
      bf16x8 af[4], bfr[4];
#pragma unroll
      for (int mt = 0; mt < 4; ++mt) {
        const int sl = (((kk * 4 + quad) ^ (l16 & 7)) * 8);
        af[mt] = *(const bf16x8*)&lsA[(wr * 64 + mt * 16 + l16) * 64 + sl];
      }
#pragma unroll
      for (int nt = 0; nt < 4; ++nt) {
        const int sl = (((kk * 4 + quad) ^ (l16 & 7)) * 8);
        bfr[nt] = *(const bf16x8*)&lsB[(wc * 64 + nt * 16 + l16) * 64 + sl];
      }
#pragma unroll
      for (int mt = 0; mt < 4; ++mt)
#pragma unroll
        for (int nt = 0; nt < 4; ++nt)
          acc[mt][nt] = __builtin_amdgcn_mfma_f32_16x16x32_bf16(af[mt], bfr[nt], acc[mt][nt], 0, 0, 0);
    }
    __syncthreads();
  }

  const int rb = row0 + wr * 64;
  const int cb = col0 + wc * 64;
#pragma unroll
  for (int mt = 0; mt < 4; ++mt) {
#pragma unroll
    for (int nt = 0; nt < 4; ++nt) {
      const int r = rb + mt * 16 + quad * 4;
      const int c = cb + nt * 16 + l16;
#pragma unroll
      for (int i = 0; i < 4; ++i) {
        const float v = acc[mt][nt][i];
        const size_t idx = (size_t)(r + i) * N + c;
        if (mode == 0) ((float*)out)[idx] = v;
        else if (mode == 1) ((unsigned short*)out)[idx] = f2b(v);
        else if (mode == 2) ((float*)out)[idx] = v + res[idx];
        else ((unsigned short*)out)[(size_t)c * M + (r + i)] = f2b(v);
      }
    }
  }
}

// ---------------------------------------------------------------------------
// Fused Q/K + V restore GEMM (768 blocks), XCD-banded (12 rows/XCD) + swizzle.
// row r<64: QKbuf[row,col] (A=t_qk);  r>=64: VT[col,row] (A=t_v)
// ---------------------------------------------------------------------------
__global__ __launch_bounds__(256) void gemm_qkv(
    const unsigned short* __restrict__ t_qk, const unsigned short* __restrict__ t_v,
    const unsigned short* __restrict__ r_qkT, const unsigned short* __restrict__ r_vT,
    unsigned short* __restrict__ QKbuf, unsigned short* __restrict__ VT) {
  __shared__ unsigned short lsA[128 * 64];
  __shared__ unsigned short lsB[128 * 64];
  const int K = 2048;
  const int bid = blockIdx.y * 8 + blockIdx.x;
  const int xcd = bid & 7, j = bid >> 3;
  const int r128 = xcd * 12 + (j >> 3);  // 0..95
  const bool isV = r128 >= 64;
  const unsigned short* A  = isV ? t_v : t_qk;
  const unsigned short* Bt = isV ? r_vT : r_qkT;
  const int row0 = (isV ? r128 - 64 : r128) * 128;
  const int col0 = (j & 7) * 128;
  const int tid = threadIdx.x;
  const int w = tid >> 6, lane = tid & 63;
  const int quad = lane >> 4, l16 = lane & 15;
  const int wr = w >> 1, wc = w & 1;

  const int srow = w * 32 + (lane >> 3);
  const int scg = ((lane & 7) ^ (lane >> 3)) * 8;
  const unsigned short* ap = A + (size_t)(row0 + srow) * K + scg;
  const unsigned short* bp = Bt + (size_t)(col0 + srow) * K + scg;

  const f32x4 fz = {0.f, 0.f, 0.f, 0.f};
  f32x4 acc[4][4];
#pragma unroll
  for (int i = 0; i < 4; ++i)
#pragma unroll
    for (int jj = 0; jj < 4; ++jj) acc[i][jj] = fz;

  for (int k0 = 0; k0 < K; k0 += 64) {
#pragma unroll
    for (int i = 0; i < 4; ++i) {
      __builtin_amdgcn_global_load_lds(
          (const __attribute__((address_space(1))) unsigned int*)(ap + (size_t)i * 8 * K + k0),
          (__attribute__((address_space(3))) unsigned int*)&lsA[(w * 32 + i * 8) * 64],
          16, 0, 0);
      __builtin_amdgcn_global_load_lds(
          (const __attribute__((address_space(1))) unsigned int*)(bp + (size_t)i * 8 * K + k0),
          (__attribute__((address_space(3))) unsigned int*)&lsB[(w * 32 + i * 8) * 64],
          16, 0, 0);
    }
    __syncthreads();
#pragma unroll
    for (int kk = 0; kk < 2; ++kk) {
      bf16x8 af[4], bfr[4];
#pragma unroll
      for (int mt = 0; mt < 4; ++mt) {
        const int sl = (((kk * 4 + quad) ^ (l16 & 7)) * 8);
        af[mt] = *(const bf16x8*)&lsA[(wr * 64 + mt * 16 + l16) * 64 + sl];
      }
#pragma unroll
      for (int nt = 0; nt < 4; ++nt) {
        const int sl = (((kk * 4 + quad) ^ (l16 & 7)) * 8);
        bfr[nt] = *(const bf16x8*)&lsB[(wc * 64 + nt * 16 + l16) * 64 + sl];
      }
#pragma unroll
      for (int mt = 0; mt < 4; ++mt)
#pragma unroll
        for (int nt = 0; nt < 4; ++nt)
          acc[mt][nt] = __builtin_amdgcn_mfma_f32_16x16x32_bf16(af[mt], bfr[nt], acc[mt][nt], 0, 0, 0);
    }
    __syncthreads();
  }

  const int rb = row0 + wr * 64;
  const int cb = col0 + wc * 64;
#pragma unroll
  for (int mt = 0; mt < 4; ++mt) {
#pragma unroll
    for (int nt = 0; nt < 4; ++nt) {
      const int r = rb + mt * 16 + quad * 4;
      const int c = cb + nt * 16 + l16;
#pragma unroll
      for (int i = 0; i < 4; ++i) {
        const float v = acc[mt][nt][i];
        if (!isV) QKbuf[(size_t)(r + i) * 1024 + c] = f2b(v);
        else VT[(size_t)c * 4096 + (r + i)] = f2b(v);
      }
    }
  }
}

// ---------------------------------------------------------------------------
// LayerNorm over D=1024, one token per 256-thread block, bf16 out.
// ---------------------------------------------------------------------------
__global__ __launch_bounds__(256) void ln_kernel(
    const float* __restrict__ x, const float* __restrict__ g,
    const float* __restrict__ be, unsigned short* __restrict__ out) {
  __shared__ float sbuf[4];
  const int t = blockIdx.x, tid = threadIdx.x;
  const float* row = x + (size_t)t * 1024;
  float v[4], s = 0.f;
#pragma unroll
  for (int j = 0; j < 4; ++j) { v[j] = row[tid + j * 256]; s += v[j]; }
#pragma unroll
  for (int off = 32; off; off >>= 1) s += __shfl_xor(s, off);
  if ((tid & 63) == 0) sbuf[tid >> 6] = s;
  __syncthreads();
  const float mu = (sbuf[0] + sbuf[1] + sbuf[2] + sbuf[3]) * (1.f / 1024.f);
  __syncthreads();
  float ss = 0.f;
#pragma unroll
  for (int j = 0; j < 4; ++j) { const float d = v[j] - mu; ss += d * d; }
#pragma unroll
  for (int off = 32; off; off >>= 1) ss += __shfl_xor(ss, off);
  if ((tid & 63) == 0) sbuf[tid >> 6] = ss;
  __syncthreads();
  const float var = (sbuf[0] + sbuf[1] + sbuf[2] + sbuf[3]) * (1.f / 1024.f);
  const float rstd = rsqrtf(var + 1e-5f);
  unsigned short* orow = out + (size_t)t * 1024;
#pragma unroll
  for (int j = 0; j < 4; ++j) {
    const int c = tid + j * 256;
    orow[c] = f2b((v[j] - mu) * rstd * g[c] + be[c]);
  }
}

// ---------------------------------------------------------------------------
// Attention mixing: h_{q,k,v}[r] = sum_n w_f*[n]*all_h[t, (base)+n*64+r];
// t_*[t, n*64+r] = w_r*[n]*h_*[r].  all_h cols: [0,2048)=f_qk, [2048,4096)=f_v.
// ---------------------------------------------------------------------------
__global__ __launch_bounds__(256) void mix_attn(
    const unsigned short* __restrict__ all_h,
    const float* __restrict__ w_fq, const float* __restrict__ w_fk,
    const float* __restrict__ w_fv, const float* __restrict__ w_rq,
    const float* __restrict__ w_rk, const float* __restrict__ w_rv,
    unsigned short* __restrict__ t_qk, unsigned short* __restrict__ t_v) {
  __shared__ float hq[64], hk[64], hv[64];
  const int t = blockIdx.x, tid = threadIdx.x;
  const int wv = tid >> 6, lane = tid & 63;
  const unsigned short* row = all_h + (size_t)t * 4096;
  if (wv < 3) {
    const float* wf = (wv == 0 ? w_fq : wv == 1 ? w_fk : w_fv) + (size_t)t * 32;
    const int base = (wv == 2) ? 2048 : 0;
    float acc = 0.f;
#pragma unroll
    for (int n = 0; n < 32; ++n) acc += wf[n] * b2f(row[base + n * 64 + lane]);
    (wv == 0 ? hq : wv == 1 ? hk : hv)[lane] = acc;
  }
  __syncthreads();
  const float* wrq = w_rq + (size_t)t * 32;
  const float* wrk = w_rk + (size_t)t * 32;
  const float* wrv = w_rv + (size_t)t * 32;
  for (int idx = tid; idx < 2048; idx += 256) {
    const int n = idx >> 6, r = idx & 63;
    t_qk[(size_t)t * 2048 + idx] = f2b(wrq[n] * hq[r]);
    t_qk[(size_t)(4096 + t) * 2048 + idx] = f2b(wrk[n] * hk[r]);
    t_v[(size_t)t * 2048 + idx] = f2b(wrv[n] * hv[r]);
  }
}

// Knowledge mixing (RK=128): h[r]=sum_n w_f[n]*all_h[t,n*128+r]; t_know=w_r[n]*h[r]
__global__ __launch_bounds__(256) void mix_know(
    const unsigned short* __restrict__ all_h, const float* __restrict__ w_f,
    const float* __restrict__ w_r, unsigned short* __restrict__ t_know) {
  __shared__ float h[128];
  const int t = blockIdx.x, tid = threadIdx.x;
  const unsigned short* row = all_h + (size_t)t * 4096;
  if (tid < 128) {
    const float* wf = w_f + (size_t)t * 32;
    float acc = 0.f;
#pragma unroll
    for (int n = 0; n < 32; ++n) acc += wf[n] * b2f(row[n * 128 + tid]);
    h[tid] = acc;
  }
  __syncthreads();
  const float* wr = w_r + (size_t)t * 32;
  for (int idx = tid; idx < 4096; idx += 256) {
    const int n = idx >> 7, r = idx & 127;
    t_know[(size_t)t * 4096 + idx] = f2b(wr[n] * h[r]);
  }
}

// ---------------------------------------------------------------------------
// Batched transpose + fp32->bf16: in [batch][R][C] f32 -> out [batch][C][R] bf16
// ---------------------------------------------------------------------------
__global__ __launch_bounds__(256) void transpose_bf(
    const float* __restrict__ in, unsigned short* __restrict__ out, int R, int C) {
  __shared__ float tile[32][33];
  const int bb = blockIdx.z;
  const int c0 = blockIdx.x * 32, r0 = blockIdx.y * 32;
  const int tx = threadIdx.x, ty = threadIdx.y;
  const float* ip = in + (size_t)bb * R * C;
  unsigned short* op = out + (size_t)bb * R * C;
#pragma unroll
  for (int j = 0; j < 4; ++j)
    tile[ty + j * 8][tx] = ip[(size_t)(r0 + ty + j * 8) * C + c0 + tx];
  __syncthreads();
#pragma unroll
  for (int j = 0; j < 4; ++j)
    op[(size_t)(c0 + ty + j * 8) * R + r0 + tx] = f2b(tile[tx][ty + j * 8]);
}

__global__ __launch_bounds__(256) void convert_bf(
    const float* __restrict__ in, unsigned short* __restrict__ out, int n) {
  const int i = blockIdx.x * 256 + threadIdx.x;
  if (i < n) out[i] = f2b(in[i]);
}

// ---------------------------------------------------------------------------
// Causal flash attention v6: SPLIT-K over history, uniform work units.
// Unit = one 64-q tile x <=8 k-tiles (512 tokens). 80 units per (b,h) column.
// ---------------------------------------------------------------------------
__global__ __launch_bounds__(256) void flash_split(
    const unsigned short* __restrict__ Q, const unsigned short* __restrict__ Kp,
    const unsigned short* __restrict__ VT, unsigned short* __restrict__ O,
    float* __restrict__ Opart, float* __restrict__ ml) {
  __shared__ unsigned short Kls[2][64 * 64];
  __shared__ unsigned short Vls[2][64 * 64];
  const int uidx = 79 - (int)blockIdx.x;
  int uu = uidx, qt = 0, ch = 0;
  for (int q = 0; q < 32; ++q) {
    const int n = (q >> 3) + 1;
    if (uu < n) { qt = q; ch = uu; break; }
    uu -= n;
  }
  const int bh = blockIdx.y;
  const int b = bh >> 4, h = bh & 15;
  const int tid = threadIdx.x;
  const int w = tid >> 6, lane = tid & 63, quad = lane >> 4, l16 = lane & 15;
  const int tb = b * 2048;
  const int qrow = qt * 64 + w * 16;
  const int ktlo = ch * 8;
  const int kthi = min(qt, ch * 8 + 7);
  const float C = 0.18033688f;  // (1/sqrt(64)) * log2(e)

  const int srow = (lane >> 3);
  const int scol = ((lane & 7) ^ srow) * 8;  // XOR-swizzled chunk

  bf16x8 qf[2];
#pragma unroll
  for (int kk = 0; kk < 2; ++kk)
    qf[kk] = *(const bf16x8*)&Q[(size_t)(tb + qrow + l16) * 1024 + h * 64 + kk * 32 + quad * 8];

  const f32x4 fz = {0.f, 0.f, 0.f, 0.f};
  float m_i = -1e30f, l_i = 0.f;
  f32x4 o_acc[4];
#pragma unroll
  for (int nt = 0; nt < 4; ++nt) o_acc[nt] = fz;

  auto stage = [&](int buf, int kt) {
#pragma unroll
    for (int j = 0; j < 2; ++j) {
      const int rg = (w * 2 + j) * 8 + srow;
      __builtin_amdgcn_global_load_lds(
          (const __attribute__((address_space(1))) unsigned int*)
              (Kp + (size_t)(tb + kt * 64 + rg) * 1024 + h * 64 + scol),
          (__attribute__((address_space(3))) unsigned int*)&Kls[buf][(w * 2 + j) * 8 * 64],
          16, 0, 0);
      __builtin_amdgcn_global_load_lds(
          (const __attribute__((address_space(1))) unsigned int*)
              (VT + (size_t)(h * 64 + rg) * 4096 + tb + kt * 64 + scol),
          (__attribute__((address_space(3))) unsigned int*)&Vls[buf][(w * 2 + j) * 8 * 64],
          16, 0, 0);
    }
  };

  const int srcA = (((quad & 1) * 32 + l16) << 2);
  const int srcB = srcA + 64;
  const bool hiq = (quad >= 2);

  stage(0, ktlo);
  __syncthreads();
  int buf = 0;
  for (int kt = ktlo; kt <= kthi; ++kt) {
    bf16x8 kf[8], vf[8];
#pragma unroll
    for (int kk = 0; kk < 2; ++kk)
#pragma unroll
      for (int nt = 0; nt < 4; ++nt) {
        const int sl = (((kk * 4 + quad) ^ (l16 & 7)) * 8);
        kf[kk * 4 + nt] = *(const bf16x8*)&Kls[buf][(nt * 16 + l16) * 64 + sl];
        vf[kk * 4 + nt] = *(const bf16x8*)&Vls[buf][(nt * 16 + l16) * 64 + sl];
      }
    if (kt < kthi) stage(buf ^ 1, kt + 1);

    const bool diag = (kt == qt);
    f32x4 s[4];
#pragma unroll
    for (int nt = 0; nt < 4; ++nt) s[nt] = fz;
#pragma unroll
    for (int kk = 0; kk < 2; ++kk)
#pragma unroll
      for (int nt = 0; nt < 4; ++nt)
        if (!diag || nt <= w)
          s[nt] = __builtin_amdgcn_mfma_f32_16x16x32_bf16(kf[kk * 4 + nt], qf[kk], s[nt], 0, 0, 0);

    const int qloc = w * 16 + l16;
    float mx = -1e30f;
#pragma unroll
    for (int nt = 0; nt < 4; ++nt)
#pragma unroll
      for (int i = 0; i < 4; ++i) {
        float v = s[nt][i];
        if (diag && (nt * 16 + quad * 4 + i) > qloc) v = -1e30f;
        s[nt][i] = v;
        mx = fmaxf(mx, v);
      }
    mx = fmaxf(mx, __shfl_xor(mx, 16));
    mx = fmaxf(mx, __shfl_xor(mx, 32));
    const float mn = fmaxf(m_i, mx);
    const float al = exp2f((m_i - mn) * C);
    m_i = mn;
    const float mC = mn * C;
    float rs = 0.f;
#pragma unroll
    for (int nt = 0; nt < 4; ++nt)
#pragma unroll
      for (int i = 0; i < 4; ++i) {
        const float p = exp2f(fmaf(s[nt][i], C, -mC));
        s[nt][i] = p;
        rs += p;
      }
    rs += __shfl_xor(rs, 16);
    rs += __shfl_xor(rs, 32);
    l_i = l_i * al + rs;
#pragma unroll
    for (int nt = 0; nt < 4; ++nt)
#pragma unroll
      for (int i = 0; i < 4; ++i) o_acc[nt][i] *= al;

    unsigned pk[4][2];
#pragma unroll
    for (int nt = 0; nt < 4; ++nt) {
      pk[nt][0] = pk2(s[nt][0], s[nt][1]);
      pk[nt][1] = pk2(s[nt][2], s[nt][3]);
    }
#pragma unroll
    for (int kk = 0; kk < 2; ++kk) {
      const int ea = 2 * kk, eb = 2 * kk + 1;
      const unsigned u0 = __builtin_amdgcn_ds_bpermute(srcA, pk[ea][0]);
      const unsigned u1 = __builtin_amdgcn_ds_bpermute(srcA, pk[ea][1]);
      const unsigned u2 = __builtin_amdgcn_ds_bpermute(srcB, pk[ea][0]);
      const unsigned u3 = __builtin_amdgcn_ds_bpermute(srcB, pk[ea][1]);
      const unsigned w0 = __builtin_amdgcn_ds_bpermute(srcA, pk[eb][0]);
      const unsigned w1 = __builtin_amdgcn_ds_bpermute(srcA, pk[eb][1]);
      const unsigned w2 = __builtin_amdgcn_ds_bpermute(srcB, pk[eb][0]);
      const unsigned w3 = __builtin_amdgcn_ds_bpermute(srcB, pk[eb][1]);
      unsigned dw[4];
      dw[0] = hiq ? w0 : u0;
      dw[1] = hiq ? w1 : u1;
      dw[2] = hiq ? w2 : u2;
      dw[3] = hiq ? w3 : u3;
      const bf16x8 pf = *(const bf16x8*)dw;
#pragma unroll
      for (int nt = 0; nt < 4; ++nt)
        o_acc[nt] = __builtin_amdgcn_mfma_f32_16x16x32_bf16(vf[kk * 4 + nt], pf, o_acc[nt], 0, 0, 0);
    }
    __syncthreads();
    buf ^= 1;
  }

  const int nch = (qt >> 3) + 1;
  if (nch == 1) {
    const float inv = 1.0f / l_i;
    unsigned short* orow = O + (size_t)(tb + qrow + l16) * 1024 + h * 64;
#pragma unroll
    for (int nt = 0; nt < 4; ++nt) {
      const unsigned d0 = pk2(o_acc[nt][0] * inv, o_acc[nt][1] * inv);
      const unsigned d1 = pk2(o_acc[nt][2] * inv, o_acc[nt][3] * inv);
      *(unsigned*)&orow[nt * 16 + quad * 4] = d0;
      *(unsigned*)&orow[nt * 16 + quad * 4 + 2] = d1;
    }
  } else {
    const int slot = bh * 80 + uidx;
    const int lq = w * 16 + l16;
    float* op = Opart + ((size_t)slot * 64 + lq) * 64;
#pragma unroll
    for (int nt = 0; nt < 4; ++nt)
      *(f32x4*)&op[nt * 16 + quad * 4] = o_acc[nt];
    if (quad == 0) {
      ml[(size_t)slot * 128 + lq * 2] = m_i;
      ml[(size_t)slot * 128 + lq * 2 + 1] = l_i;
    }
  }
}

// ---------------------------------------------------------------------------
// Combine split-K partials for qt in [8,31]. Grid (24, 32), 256 threads.
// ---------------------------------------------------------------------------
__global__ __launch_bounds__(256) void flash_reduce(
    const float* __restrict__ Opart, const float* __restrict__ ml,
    unsigned short* __restrict__ O) {
  const int qt = 8 + blockIdx.x;
  const int bh = blockIdx.y;
  const int b = bh >> 4, h = bh & 15;
  const int j = qt >> 3;                       // 1..3
  const int base = 8 * (j * (j + 1) / 2) + (qt - 8 * j) * (j + 1);
  const int nch = j + 1;
  const int tid = threadIdx.x;
  const int lq = tid >> 2, dq = (tid & 3) * 16;
  const float C = 0.18033688f;

  float mc[4], lc[4];
  float m = -1e30f;
#pragma unroll
  for (int c = 0; c < 4; ++c) {
    if (c < nch) {
      const size_t sl = (size_t)(bh * 80 + base + c) * 128 + lq * 2;
      mc[c] = ml[sl];
      lc[c] = ml[sl + 1];
    } else { mc[c] = -1e30f; lc[c] = 0.f; }
    m = fmaxf(m, mc[c]);
  }
  float fac[4], lt = 0.f;
#pragma unroll
  for (int c = 0; c < 4; ++c) {
    fac[c] = (c < nch) ? exp2f((mc[c] - m) * C) : 0.f;
    lt += fac[c] * lc[c];
  }
  const float inv = 1.0f / lt;
  float acc[16];
#pragma unroll
  for (int i = 0; i < 16; ++i) acc[i] = 0.f;
#pragma unroll
  for (int c = 0; c < 4; ++c) {
    if (c >= nch) continue;
    const float* op = Opart + ((size_t)(bh * 80 + base + c) * 64 + lq) * 64 + dq;
#pragma unroll
    for (int i = 0; i < 16; i += 4) {
      const f32x4 v = *(const f32x4*)&op[i];
#pragma unroll
      for (int k = 0; k < 4; ++k) acc[i + k] += fac[c] * v[k];
    }
  }
  unsigned short* orow = O + (size_t)(b * 2048 + qt * 64 + lq) * 1024 + h * 64 + dq;
#pragma unroll
  for (int i = 0; i < 16; i += 2)
    *(unsigned*)&orow[i] = pk2(acc[i] * inv, acc[i + 1] * inv);
}

// ---------------------------------------------------------------------------
extern "C" void kernel_launch(void* const* d_in, const int* in_sizes, int n_in,
                              void* d_out, int out_size, void* d_ws, size_t ws_size,
                              hipStream_t stream) {
  (void)in_sizes; (void)n_in; (void)out_size; (void)ws_size;
  const float* x      = (const float*)d_in[0];
  const float* f_qk   = (const float*)d_in[1];
  const float* f_v    = (const float*)d_in[2];
  const float* r_qk   = (const float*)d_in[3];
  const float* r_v    = (const float*)d_in[4];
  const float* f_know = (const float*)d_in[5];
  const float* r_know = (const float*)d_in[6];
  const float* W_O    = (const float*)d_in[7];
  const float* gamma1 = (const float*)d_in[8];
  const float* beta1  = (const float*)d_in[9];
  const float* gamma2 = (const float*)d_in[10];
  const float* beta2  = (const float*)d_in[11];
  const float* w_fq   = (const float*)d_in[12];
  const float* w_fk   = (const float*)d_in[13];
  const float* w_fv   = (const float*)d_in[14];
  const float* w_rq   = (const float*)d_in[15];
  const float* w_rk   = (const float*)d_in[16];
  const float* w_rv   = (const float*)d_in[17];
  const float* w_kf   = (const float*)d_in[18];
  const float* w_kr   = (const float*)d_in[19];

  char* base = (char*)d_ws;
  size_t off = 0;
  auto alloc = [&](size_t b) { char* p = base + off; off += (b + 255) & ~(size_t)255; return p; };
  unsigned short* fcomb   = (unsigned short*)alloc(8388608);   // [4096][1024]
  unsigned short* fknowT  = (unsigned short*)alloc(8388608);   // [4096][1024]
  unsigned short* r_qkT   = (unsigned short*)alloc(4194304);   // [1024][2048]
  unsigned short* r_vT    = (unsigned short*)alloc(4194304);   // [1024][2048]
  unsigned short* r_knowT = (unsigned short*)alloc(8388608);   // [1024][4096]
  unsigned short* WO_bf   = (unsigned short*)alloc(2097152);   // [1024][1024]
  unsigned short* nx_bf   = (unsigned short*)alloc(8388608);   // [4096][1024]
  unsigned short* all_h   = (unsigned short*)alloc(33554432);  // [4096][4096]
  unsigned short* t_qk    = (unsigned short*)alloc(33554432);  // [8192][2048]
  unsigned short* t_v     = (unsigned short*)alloc(16777216);  // [4096][2048]; reused as x1 fp32
  unsigned short* QKbuf   = (unsigned short*)alloc(16777216);  // [8192][1024]
  unsigned short* VT      = (unsigned short*)alloc(8388608);   // [1024][4096]
  unsigned short* attn    = (unsigned short*)alloc(8388608);   // [4096][1024]
  float* x1 = (float*)t_v;  // t_v dead before x1 written
  float* Opart = (float*)all_h;               // split-K partials (dead region)
  float* mlbuf = (float*)(all_h + 20971520);  // byte offset 41943040

  const dim3 blk256(256), blkT(32, 8);

  // weight preps
  transpose_bf<<<dim3(2, 32, 32), blkT, 0, stream>>>(f_qk, fcomb, 1024, 64);
  transpose_bf<<<dim3(2, 32, 32), blkT, 0, stream>>>(f_v, fcomb + (size_t)2048 * 1024, 1024, 64);
  transpose_bf<<<dim3(4, 32, 32), blkT, 0, stream>>>(f_know, fknowT, 1024, 128);
  transpose_bf<<<dim3(32, 64, 1), blkT, 0, stream>>>(r_qk, r_qkT, 2048, 1024);
  transpose_bf<<<dim3(32, 64, 1), blkT, 0, stream>>>(r_v, r_vT, 2048, 1024);
  transpose_bf<<<dim3(32, 128, 1), blkT, 0, stream>>>(r_know, r_knowT, 4096, 1024);
  convert_bf<<<4096, blk256, 0, stream>>>(W_O, WO_bf, 1048576);

  // attention circuit
  ln_kernel<<<4096, blk256, 0, stream>>>(x, gamma1, beta1, nx_bf);
  gemm_bt<<<dim3(32, 32), blk256, 0, stream>>>(nx_bf, fcomb, nullptr, all_h, 4096, 4096, 1024, 1, 0);
  mix_attn<<<4096, blk256, 0, stream>>>(all_h, w_fq, w_fk, w_fv, w_rq, w_rk, w_rv, t_qk, t_v);
  gemm_qkv<<<dim3(8, 96), blk256, 0, stream>>>(t_qk, t_v, r_qkT, r_vT, QKbuf, VT);
  flash_split<<<dim3(80, 32), blk256, 0, stream>>>(QKbuf, QKbuf + (size_t)4096 * 1024, VT, attn,
                                                   Opart, mlbuf);
  flash_reduce<<<dim3(24, 32), blk256, 0, stream>>>(Opart, mlbuf, attn);
  gemm_bt<<<dim3(8, 32), blk256, 0, stream>>>(attn, WO_bf, x, x1, 4096, 1024, 1024, 2, 0);

  // knowledge circuit
  ln_kernel<<<4096, blk256, 0, stream>>>(x1, gamma2, beta2, nx_bf);
  gemm_bt<<<dim3(32, 32), blk256, 0, stream>>>(nx_bf, fknowT, nullptr, all_h, 4096, 4096, 1024, 1, 0);
  mix_know<<<4096, blk256, 0, stream>>>(all_h, w_kf, w_kr, t_qk);
  gemm_bt<<<dim3(8, 32), blk256, 0, stream>>>(t_qk, r_knowT, x1, (float*)d_out, 4096, 1024, 4096, 2, 4);
}

// Round 8
// 570.181 us; speedup vs baseline: 1.2231x; 1.0558x over previous
//
#include <hip/hip_runtime.h>
#include <stdint.h>

// B=2,S=2048,D=1024,H=16,R=64,N=32,RK=128,DH=64. Tokens T=4096.

typedef __bf16 bf16x8 __attribute__((ext_vector_type(8)));
typedef float f32x4 __attribute__((ext_vector_type(4)));

__device__ __forceinline__ unsigned short f2b(float f) {
  union { float f; unsigned u; } v; v.f = f;
  unsigned u = v.u;
  unsigned r = (u + 0x7FFFu + ((u >> 16) & 1u)) >> 16;  // RNE
  return (unsigned short)r;
}
__device__ __forceinline__ float b2f(unsigned short h) {
  union { unsigned u; float f; } v; v.u = ((unsigned)h) << 16;
  return v.f;
}
__device__ __forceinline__ unsigned pk2(float lo, float hi) {
  return (unsigned)f2b(lo) | ((unsigned)f2b(hi) << 16);
}

// ---------------------------------------------------------------------------
// Generic bf16 GEMM: C[M,N] = A[M,K] @ Bt[N,K]^T.  128x128 tile, BK=64,
// 256 threads, 16x16x32 MFMA, global_load_lds x16, XOR-swizzled LDS.
// band>0: XCD row-banding remap. mode 0 fp32; 1 bf16; 2 fp32+res; 3 bf16 T.
// ---------------------------------------------------------------------------
__global__ __launch_bounds__(256) void gemm_bt(
    const unsigned short* __restrict__ A, const unsigned short* __restrict__ Bt,
    const float* __restrict__ res, void* __restrict__ out,
    int M, int N, int K, int mode, int band) {
  __shared__ unsigned short lsA[128 * 64];
  __shared__ unsigned short lsB[128 * 64];
  const int tid = threadIdx.x;
  const int w = tid >> 6, lane = tid & 63;
  const int quad = lane >> 4, l16 = lane & 15;
  const int wr = w >> 1, wc = w & 1;
  int bx = blockIdx.x, by = blockIdx.y;
  if (band > 0) {
    const int bid = by * gridDim.x + bx;
    const int xcd = bid & 7, j = bid >> 3;
    by = xcd * band + j / gridDim.x;
    bx = j % gridDim.x;
  }
  const int row0 = by * 128;
  const int col0 = bx * 128;

  const int srow = w * 32 + (lane >> 3);
  const int scg = ((lane & 7) ^ (lane >> 3)) * 8;  // source-side XOR swizzle
  const unsigned short* ap = A + (size_t)(row0 + srow) * K + scg;
  const unsigned short* bp = Bt + (size_t)(col0 + srow) * K + scg;

  const f32x4 fz = {0.f, 0.f, 0.f, 0.f};
  f32x4 acc[4][4];
#pragma unroll
  for (int i = 0; i < 4; ++i)
#pragma unroll
    for (int j = 0; j < 4; ++j) acc[i][j] = fz;

  for (int k0 = 0; k0 < K; k0 += 64) {
#pragma unroll
    for (int i = 0; i < 4; ++i) {
      __builtin_amdgcn_global_load_lds(
          (const __attribute__((address_space(1))) unsigned int*)(ap + (size_t)i * 8 * K + k0),
          (__attribute__((address_space(3))) unsigned int*)&lsA[(w * 32 + i * 8) * 64],
          16, 0, 0);
      __builtin_amdgcn_global_load_lds(
          (const __attribute__((address_space(1))) unsigned int*)(bp + (size_t)i * 8 * K + k0),
          (__attribute__((address_space(3))) unsigned int*)&lsB[(w * 32 + i * 8) * 64],
          16, 0, 0);
    }
    __syncthreads();
#pragma unroll
    for (int kk = 0; kk < 2; ++kk) {
      bf16x8 af[4], bfr[4];
      const int sl = (((kk * 4 + quad) ^ (l16 & 7)) * 8);
#pragma unroll
      for (int mt = 0; mt < 4; ++mt)
        af[mt] = *(const bf16x8*)&lsA[(wr * 64 + mt * 16 + l16) * 64 + sl];
#pragma unroll
      for (int nt = 0; nt < 4; ++nt)
        bfr[nt] = *(const bf16x8*)&lsB[(wc * 64 + nt * 16 + l16) * 64 + sl];
#pragma unroll
      for (int mt = 0; mt < 4; ++mt)
#pragma unroll
        for (int nt = 0; nt < 4; ++nt)
          acc[mt][nt] = __builtin_amdgcn_mfma_f32_16x16x32_bf16(af[mt], bfr[nt], acc[mt][nt], 0, 0, 0);
    }
    __syncthreads();
  }

  const int rb = row0 + wr * 64;
  const int cb = col0 + wc * 64;
#pragma unroll
  for (int mt = 0; mt < 4; ++mt) {
#pragma unroll
    for (int nt = 0; nt < 4; ++nt) {
      const int r = rb + mt * 16 + quad * 4;
      const int c = cb + nt * 16 + l16;
#pragma unroll
      for (int i = 0; i < 4; ++i) {
        const float v = acc[mt][nt][i];
        const size_t idx = (size_t)(r + i) * N + c;
        if (mode == 0) ((float*)out)[idx] = v;
        else if (mode == 1) ((unsigned short*)out)[idx] = f2b(v);
        else if (mode == 2) ((float*)out)[idx] = v + res[idx];
        else ((unsigned short*)out)[(size_t)c * M + (r + i)] = f2b(v);
      }
    }
  }
}

// ---------------------------------------------------------------------------
// Split-K x2 GEMM -> fp32 partials p0/p1. 128x128 tile; grid (N/128, M/64).
// XCD-banded: xcd owns (M/128/8) row-tiles x both k-halves x all cols.
// ---------------------------------------------------------------------------
__global__ __launch_bounds__(256) void gemm_ks2(
    const unsigned short* __restrict__ A, const unsigned short* __restrict__ Bt,
    float* __restrict__ p0, float* __restrict__ p1, int M, int N, int K) {
  __shared__ unsigned short lsA[128 * 64];
  __shared__ unsigned short lsB[128 * 64];
  const int tid = threadIdx.x;
  const int w = tid >> 6, lane = tid & 63;
  const int quad = lane >> 4, l16 = lane & 15;
  const int wr = w >> 1, wc = w & 1;
  const int nrow8 = (M / 128) >> 3;            // row-tiles per XCD
  const int bid = blockIdx.y * gridDim.x + blockIdx.x;
  const int xcd = bid & 7, j = bid >> 3;
  const int by = xcd * nrow8 + j / (2 * gridDim.x);
  const int rem = j % (2 * gridDim.x);
  const int ks = rem / gridDim.x;
  const int bx = rem % gridDim.x;
  const int row0 = by * 128;
  const int col0 = bx * 128;
  const int kbeg = ks * (K >> 1), kend = kbeg + (K >> 1);

  const int srow = w * 32 + (lane >> 3);
  const int scg = ((lane & 7) ^ (lane >> 3)) * 8;
  const unsigned short* ap = A + (size_t)(row0 + srow) * K + scg;
  const unsigned short* bp = Bt + (size_t)(col0 + srow) * K + scg;

  const f32x4 fz = {0.f, 0.f, 0.f, 0.f};
  f32x4 acc[4][4];
#pragma unroll
  for (int i = 0; i < 4; ++i)
#pragma unroll
    for (int jj = 0; jj < 4; ++jj) acc[i][jj] = fz;

  for (int k0 = kbeg; k0 < kend; k0 += 64) {
#pragma unroll
    for (int i = 0; i < 4; ++i) {
      __builtin_amdgcn_global_load_lds(
          (const __attribute__((address_space(1))) unsigned int*)(ap + (size_t)i * 8 * K + k0),
          (__attribute__((address_space(3))) unsigned int*)&lsA[(w * 32 + i * 8) * 64],
          16, 0, 0);
      __builtin_amdgcn_global_load_lds(
          (const __attribute__((address_space(1))) unsigned int*)(bp + (size_t)i * 8 * K + k0),
          (__attribute__((address_space(3))) unsigned int*)&lsB[(w * 32 + i * 8) * 64],
          16, 0, 0);
    }
    __syncthreads();
#pragma unroll
    for (int kk = 0; kk < 2; ++kk) {
      bf16x8 af[4], bfr[4];
      const int sl = (((kk * 4 + quad) ^ (l16 & 7)) * 8);
#pragma unroll
      for (int mt = 0; mt < 4; ++mt)
        af[mt] = *(const bf16x8*)&lsA[(wr * 64 + mt * 16 + l16) * 64 + sl];
#pragma unroll
      for (int nt = 0; nt < 4; ++nt)
        bfr[nt] = *(const bf16x8*)&lsB[(wc * 64 + nt * 16 + l16) * 64 + sl];
#pragma unroll
      for (int mt = 0; mt < 4; ++mt)
#pragma unroll
        for (int nt = 0; nt < 4; ++nt)
          acc[mt][nt] = __builtin_amdgcn_mfma_f32_16x16x32_bf16(af[mt], bfr[nt], acc[mt][nt], 0, 0, 0);
    }
    __syncthreads();
  }

  float* out = ks ? p1 : p0;
  const int rb = row0 + wr * 64;
  const int cb = col0 + wc * 64;
#pragma unroll
  for (int mt = 0; mt < 4; ++mt) {
#pragma unroll
    for (int nt = 0; nt < 4; ++nt) {
      const int r = rb + mt * 16 + quad * 4;
      const int c = cb + nt * 16 + l16;
#pragma unroll
      for (int i = 0; i < 4; ++i)
        out[(size_t)(r + i) * N + c] = acc[mt][nt][i];
    }
  }
}

// out = p0 + p1 + res (all fp32, n elements, f32x4-vectorized)
__global__ __launch_bounds__(256) void reduce_add3(
    const float* __restrict__ p0, const float* __restrict__ p1,
    const float* __restrict__ res, float* __restrict__ out, int n) {
  const int i = (blockIdx.x * 256 + threadIdx.x) * 4;
  if (i < n) {
    const f32x4 a = *(const f32x4*)&p0[i];
    const f32x4 b = *(const f32x4*)&p1[i];
    const f32x4 c = *(const f32x4*)&res[i];
    f32x4 o;
#pragma unroll
    for (int k = 0; k < 4; ++k) o[k] = a[k] + b[k] + c[k];
    *(f32x4*)&out[i] = o;
  }
}

// ---------------------------------------------------------------------------
// Fused Q/K + V restore GEMM (768 blocks), XCD-banded (12 rows/XCD) + swizzle.
// ---------------------------------------------------------------------------
__global__ __launch_bounds__(256) void gemm_qkv(
    const unsigned short* __restrict__ t_qk, const unsigned short* __restrict__ t_v,
    const unsigned short* __restrict__ r_qkT, const unsigned short* __restrict__ r_vT,
    unsigned short* __restrict__ QKbuf, unsigned short* __restrict__ VT) {
  __shared__ unsigned short lsA[128 * 64];
  __shared__ unsigned short lsB[128 * 64];
  const int K = 2048;
  const int bid = blockIdx.y * 8 + blockIdx.x;
  const int xcd = bid & 7, j = bid >> 3;
  const int r128 = xcd * 12 + (j >> 3);  // 0..95
  const bool isV = r128 >= 64;
  const unsigned short* A  = isV ? t_v : t_qk;
  const unsigned short* Bt = isV ? r_vT : r_qkT;
  const int row0 = (isV ? r128 - 64 : r128) * 128;
  const int col0 = (j & 7) * 128;
  const int tid = threadIdx.x;
  const int w = tid >> 6, lane = tid & 63;
  const int quad = lane >> 4, l16 = lane & 15;
  const int wr = w >> 1, wc = w & 1;

  const int srow = w * 32 + (lane >> 3);
  const int scg = ((lane & 7) ^ (lane >> 3)) * 8;
  const unsigned short* ap = A + (size_t)(row0 + srow) * K + scg;
  const unsigned short* bp = Bt + (size_t)(col0 + srow) * K + scg;

  const f32x4 fz = {0.f, 0.f, 0.f, 0.f};
  f32x4 acc[4][4];
#pragma unroll
  for (int i = 0; i < 4; ++i)
#pragma unroll
    for (int jj = 0; jj < 4; ++jj) acc[i][jj] = fz;

  for (int k0 = 0; k0 < K; k0 += 64) {
#pragma unroll
    for (int i = 0; i < 4; ++i) {
      __builtin_amdgcn_global_load_lds(
          (const __attribute__((address_space(1))) unsigned int*)(ap + (size_t)i * 8 * K + k0),
          (__attribute__((address_space(3))) unsigned int*)&lsA[(w * 32 + i * 8) * 64],
          16, 0, 0);
      __builtin_amdgcn_global_load_lds(
          (const __attribute__((address_space(1))) unsigned int*)(bp + (size_t)i * 8 * K + k0),
          (__attribute__((address_space(3))) unsigned int*)&lsB[(w * 32 + i * 8) * 64],
          16, 0, 0);
    }
    __syncthreads();
#pragma unroll
    for (int kk = 0; kk < 2; ++kk) {
      bf16x8 af[4], bfr[4];
      const int sl = (((kk * 4 + quad) ^ (l16 & 7)) * 8);
#pragma unroll
      for (int mt = 0; mt < 4; ++mt)
        af[mt] = *(const bf16x8*)&lsA[(wr * 64 + mt * 16 + l16) * 64 + sl];
#pragma unroll
      for (int nt = 0; nt < 4; ++nt)
        bfr[nt] = *(const bf16x8*)&lsB[(wc * 64 + nt * 16 + l16) * 64 + sl];
#pragma unroll
      for (int mt = 0; mt < 4; ++mt)
#pragma unroll
        for (int nt = 0; nt < 4; ++nt)
          acc[mt][nt] = __builtin_amdgcn_mfma_f32_16x16x32_bf16(af[mt], bfr[nt], acc[mt][nt], 0, 0, 0);
    }
    __syncthreads();
  }

  const int rb = row0 + wr * 64;
  const int cb = col0 + wc * 64;
#pragma unroll
  for (int mt = 0; mt < 4; ++mt) {
#pragma unroll
    for (int nt = 0; nt < 4; ++nt) {
      const int r = rb + mt * 16 + quad * 4;
      const int c = cb + nt * 16 + l16;
#pragma unroll
      for (int i = 0; i < 4; ++i) {
        const float v = acc[mt][nt][i];
        if (!isV) QKbuf[(size_t)(r + i) * 1024 + c] = f2b(v);
        else VT[(size_t)c * 4096 + (r + i)] = f2b(v);
      }
    }
  }
}

// ---------------------------------------------------------------------------
// LayerNorm over D=1024, one token per 256-thread block, bf16 out.
// ---------------------------------------------------------------------------
__global__ __launch_bounds__(256) void ln_kernel(
    const float* __restrict__ x, const float* __restrict__ g,
    const float* __restrict__ be, unsigned short* __restrict__ out) {
  __shared__ float sbuf[4];
  const int t = blockIdx.x, tid = threadIdx.x;
  const float* row = x + (size_t)t * 1024;
  float v[4], s = 0.f;
#pragma unroll
  for (int j = 0; j < 4; ++j) { v[j] = row[tid + j * 256]; s += v[j]; }
#pragma unroll
  for (int off = 32; off; off >>= 1) s += __shfl_xor(s, off);
  if ((tid & 63) == 0) sbuf[tid >> 6] = s;
  __syncthreads();
  const float mu = (sbuf[0] + sbuf[1] + sbuf[2] + sbuf[3]) * (1.f / 1024.f);
  __syncthreads();
  float ss = 0.f;
#pragma unroll
  for (int j = 0; j < 4; ++j) { const float d = v[j] - mu; ss += d * d; }
#pragma unroll
  for (int off = 32; off; off >>= 1) ss += __shfl_xor(ss, off);
  if ((tid & 63) == 0) sbuf[tid >> 6] = ss;
  __syncthreads();
  const float var = (sbuf[0] + sbuf[1] + sbuf[2] + sbuf[3]) * (1.f / 1024.f);
  const float rstd = rsqrtf(var + 1e-5f);
  unsigned short* orow = out + (size_t)t * 1024;
#pragma unroll
  for (int j = 0; j < 4; ++j) {
    const int c = tid + j * 256;
    orow[c] = f2b((v[j] - mu) * rstd * g[c] + be[c]);
  }
}

// ---------------------------------------------------------------------------
// Attention mixing.
// ---------------------------------------------------------------------------
__global__ __launch_bounds__(256) void mix_attn(
    const unsigned short* __restrict__ all_h,
    const float* __restrict__ w_fq, const float* __restrict__ w_fk,
    const float* __restrict__ w_fv, const float* __restrict__ w_rq,
    const float* __restrict__ w_rk, const float* __restrict__ w_rv,
    unsigned short* __restrict__ t_qk, unsigned short* __restrict__ t_v) {
  __shared__ float hq[64], hk[64], hv[64];
  const int t = blockIdx.x, tid = threadIdx.x;
  const int wv = tid >> 6, lane = tid & 63;
  const unsigned short* row = all_h + (size_t)t * 4096;
  if (wv < 3) {
    const float* wf = (wv == 0 ? w_fq : wv == 1 ? w_fk : w_fv) + (size_t)t * 32;
    const int base = (wv == 2) ? 2048 : 0;
    float acc = 0.f;
#pragma unroll
    for (int n = 0; n < 32; ++n) acc += wf[n] * b2f(row[base + n * 64 + lane]);
    (wv == 0 ? hq : wv == 1 ? hk : hv)[lane] = acc;
  }
  __syncthreads();
  const float* wrq = w_rq + (size_t)t * 32;
  const float* wrk = w_rk + (size_t)t * 32;
  const float* wrv = w_rv + (size_t)t * 32;
  for (int idx = tid; idx < 2048; idx += 256) {
    const int n = idx >> 6, r = idx & 63;
    t_qk[(size_t)t * 2048 + idx] = f2b(wrq[n] * hq[r]);
    t_qk[(size_t)(4096 + t) * 2048 + idx] = f2b(wrk[n] * hk[r]);
    t_v[(size_t)t * 2048 + idx] = f2b(wrv[n] * hv[r]);
  }
}

// Knowledge mixing (RK=128)
__global__ __launch_bounds__(256) void mix_know(
    const unsigned short* __restrict__ all_h, const float* __restrict__ w_f,
    const float* __restrict__ w_r, unsigned short* __restrict__ t_know) {
  __shared__ float h[128];
  const int t = blockIdx.x, tid = threadIdx.x;
  const unsigned short* row = all_h + (size_t)t * 4096;
  if (tid < 128) {
    const float* wf = w_f + (size_t)t * 32;
    float acc = 0.f;
#pragma unroll
    for (int n = 0; n < 32; ++n) acc += wf[n] * b2f(row[n * 128 + tid]);
    h[tid] = acc;
  }
  __syncthreads();
  const float* wr = w_r + (size_t)t * 32;
  for (int idx = tid; idx < 4096; idx += 256) {
    const int n = idx >> 7, r = idx & 127;
    t_know[(size_t)t * 4096 + idx] = f2b(wr[n] * h[r]);
  }
}

// ---------------------------------------------------------------------------
// Batched transpose + fp32->bf16
// ---------------------------------------------------------------------------
__global__ __launch_bounds__(256) void transpose_bf(
    const float* __restrict__ in, unsigned short* __restrict__ out, int R, int C) {
  __shared__ float tile[32][33];
  const int bb = blockIdx.z;
  const int c0 = blockIdx.x * 32, r0 = blockIdx.y * 32;
  const int tx = threadIdx.x, ty = threadIdx.y;
  const float* ip = in + (size_t)bb * R * C;
  unsigned short* op = out + (size_t)bb * R * C;
#pragma unroll
  for (int j = 0; j < 4; ++j)
    tile[ty + j * 8][tx] = ip[(size_t)(r0 + ty + j * 8) * C + c0 + tx];
  __syncthreads();
#pragma unroll
  for (int j = 0; j < 4; ++j)
    op[(size_t)(c0 + ty + j * 8) * R + r0 + tx] = f2b(tile[tx][ty + j * 8]);
}

__global__ __launch_bounds__(256) void convert_bf(
    const float* __restrict__ in, unsigned short* __restrict__ out, int n) {
  const int i = blockIdx.x * 256 + threadIdx.x;
  if (i < n) out[i] = f2b(in[i]);
}

// ---------------------------------------------------------------------------
// Causal flash attention: SPLIT-K over history, uniform work units.
// ---------------------------------------------------------------------------
__global__ __launch_bounds__(256) void flash_split(
    const unsigned short* __restrict__ Q, const unsigned short* __restrict__ Kp,
    const unsigned short* __restrict__ VT, unsigned short* __restrict__ O,
    float* __restrict__ Opart, float* __restrict__ ml) {
  __shared__ unsigned short Kls[2][64 * 64];
  __shared__ unsigned short Vls[2][64 * 64];
  const int uidx = 79 - (int)blockIdx.x;
  int uu = uidx, qt = 0, ch = 0;
  for (int q = 0; q < 32; ++q) {
    const int n = (q >> 3) + 1;
    if (uu < n) { qt = q; ch = uu; break; }
    uu -= n;
  }
  const int bh = blockIdx.y;
  const int b = bh >> 4, h = bh & 15;
  const int tid = threadIdx.x;
  const int w = tid >> 6, lane = tid & 63, quad = lane >> 4, l16 = lane & 15;
  const int tb = b * 2048;
  const int qrow = qt * 64 + w * 16;
  const int ktlo = ch * 8;
  const int kthi = min(qt, ch * 8 + 7);
  const float C = 0.18033688f;  // (1/sqrt(64)) * log2(e)

  const int srow = (lane >> 3);
  const int scol = ((lane & 7) ^ srow) * 8;

  bf16x8 qf[2];
#pragma unroll
  for (int kk = 0; kk < 2; ++kk)
    qf[kk] = *(const bf16x8*)&Q[(size_t)(tb + qrow + l16) * 1024 + h * 64 + kk * 32 + quad * 8];

  const f32x4 fz = {0.f, 0.f, 0.f, 0.f};
  float m_i = -1e30f, l_i = 0.f;
  f32x4 o_acc[4];
#pragma unroll
  for (int nt = 0; nt < 4; ++nt) o_acc[nt] = fz;

  auto stage = [&](int buf, int kt) {
#pragma unroll
    for (int j = 0; j < 2; ++j) {
      const int rg = (w * 2 + j) * 8 + srow;
      __builtin_amdgcn_global_load_lds(
          (const __attribute__((address_space(1))) unsigned int*)
              (Kp + (size_t)(tb + kt * 64 + rg) * 1024 + h * 64 + scol),
          (__attribute__((address_space(3))) unsigned int*)&Kls[buf][(w * 2 + j) * 8 * 64],
          16, 0, 0);
      __builtin_amdgcn_global_load_lds(
          (const __attribute__((address_space(1))) unsigned int*)
              (VT + (size_t)(h * 64 + rg) * 4096 + tb + kt * 64 + scol),
          (__attribute__((address_space(3))) unsigned int*)&Vls[buf][(w * 2 + j) * 8 * 64],
          16, 0, 0);
    }
  };

  const int srcA = (((quad & 1) * 32 + l16) << 2);
  const int srcB = srcA + 64;
  const bool hiq = (quad >= 2);

  stage(0, ktlo);
  __syncthreads();
  int buf = 0;
  for (int kt = ktlo; kt <= kthi; ++kt) {
    bf16x8 kf[8], vf[8];
#pragma unroll
    for (int kk = 0; kk < 2; ++kk)
#pragma unroll
      for (int nt = 0; nt < 4; ++nt) {
        const int sl = (((kk * 4 + quad) ^ (l16 & 7)) * 8);
        kf[kk * 4 + nt] = *(const bf16x8*)&Kls[buf][(nt * 16 + l16) * 64 + sl];
        vf[kk * 4 + nt] = *(const bf16x8*)&Vls[buf][(nt * 16 + l16) * 64 + sl];
      }
    if (kt < kthi) stage(buf ^ 1, kt + 1);

    const bool diag = (kt == qt);
    f32x4 s[4];
#pragma unroll
    for (int nt = 0; nt < 4; ++nt) s[nt] = fz;
#pragma unroll
    for (int kk = 0; kk < 2; ++kk)
#pragma unroll
      for (int nt = 0; nt < 4; ++nt)
        if (!diag || nt <= w)
          s[nt] = __builtin_amdgcn_mfma_f32_16x16x32_bf16(kf[kk * 4 + nt], qf[kk], s[nt], 0, 0, 0);

    const int qloc = w * 16 + l16;
    float mx = -1e30f;
#pragma unroll
    for (int nt = 0; nt < 4; ++nt)
#pragma unroll
      for (int i = 0; i < 4; ++i) {
        float v = s[nt][i];
        if (diag && (nt * 16 + quad * 4 + i) > qloc) v = -1e30f;
        s[nt][i] = v;
        mx = fmaxf(mx, v);
      }
    mx = fmaxf(mx, __shfl_xor(mx, 16));
    mx = fmaxf(mx, __shfl_xor(mx, 32));
    const float mn = fmaxf(m_i, mx);
    const float al = exp2f((m_i - mn) * C);
    m_i = mn;
    const float mC = mn * C;
    float rs = 0.f;
#pragma unroll
    for (int nt = 0; nt < 4; ++nt)
#pragma unroll
      for (int i = 0; i < 4; ++i) {
        const float p = exp2f(fmaf(s[nt][i], C, -mC));
        s[nt][i] = p;
        rs += p;
      }
    rs += __shfl_xor(rs, 16);
    rs += __shfl_xor(rs, 32);
    l_i = l_i * al + rs;
#pragma unroll
    for (int nt = 0; nt < 4; ++nt)
#pragma unroll
      for (int i = 0; i < 4; ++i) o_acc[nt][i] *= al;

    unsigned pk[4][2];
#pragma unroll
    for (int nt = 0; nt < 4; ++nt) {
      pk[nt][0] = pk2(s[nt][0], s[nt][1]);
      pk[nt][1] = pk2(s[nt][2], s[nt][3]);
    }
#pragma unroll
    for (int kk = 0; kk < 2; ++kk) {
      const int ea = 2 * kk, eb = 2 * kk + 1;
      const unsigned u0 = __builtin_amdgcn_ds_bpermute(srcA, pk[ea][0]);
      const unsigned u1 = __builtin_amdgcn_ds_bpermute(srcA, pk[ea][1]);
      const unsigned u2 = __builtin_amdgcn_ds_bpermute(srcB, pk[ea][0]);
      const unsigned u3 = __builtin_amdgcn_ds_bpermute(srcB, pk[ea][1]);
      const unsigned w0 = __builtin_amdgcn_ds_bpermute(srcA, pk[eb][0]);
      const unsigned w1 = __builtin_amdgcn_ds_bpermute(srcA, pk[eb][1]);
      const unsigned w2 = __builtin_amdgcn_ds_bpermute(srcB, pk[eb][0]);
      const unsigned w3 = __builtin_amdgcn_ds_bpermute(srcB, pk[eb][1]);
      unsigned dw[4];
      dw[0] = hiq ? w0 : u0;
      dw[1] = hiq ? w1 : u1;
      dw[2] = hiq ? w2 : u2;
      dw[3] = hiq ? w3 : u3;
      const bf16x8 pf = *(const bf16x8*)dw;
#pragma unroll
      for (int nt = 0; nt < 4; ++nt)
        o_acc[nt] = __builtin_amdgcn_mfma_f32_16x16x32_bf16(vf[kk * 4 + nt], pf, o_acc[nt], 0, 0, 0);
    }
    __syncthreads();
    buf ^= 1;
  }

  const int nch = (qt >> 3) + 1;
  if (nch == 1) {
    const float inv = 1.0f / l_i;
    unsigned short* orow = O + (size_t)(tb + qrow + l16) * 1024 + h * 64;
#pragma unroll
    for (int nt = 0; nt < 4; ++nt) {
      const unsigned d0 = pk2(o_acc[nt][0] * inv, o_acc[nt][1] * inv);
      const unsigned d1 = pk2(o_acc[nt][2] * inv, o_acc[nt][3] * inv);
      *(unsigned*)&orow[nt * 16 + quad * 4] = d0;
      *(unsigned*)&orow[nt * 16 + quad * 4 + 2] = d1;
    }
  } else {
    const int slot = bh * 80 + uidx;
    const int lq = w * 16 + l16;
    float* op = Opart + ((size_t)slot * 64 + lq) * 64;
#pragma unroll
    for (int nt = 0; nt < 4; ++nt)
      *(f32x4*)&op[nt * 16 + quad * 4] = o_acc[nt];
    if (quad == 0) {
      ml[(size_t)slot * 128 + lq * 2] = m_i;
      ml[(size_t)slot * 128 + lq * 2 + 1] = l_i;
    }
  }
}

// ---------------------------------------------------------------------------
// Combine split-K partials for qt in [8,31]. Grid (24, 32), 256 threads.
// ---------------------------------------------------------------------------
__global__ __launch_bounds__(256) void flash_reduce(
    const float* __restrict__ Opart, const float* __restrict__ ml,
    unsigned short* __restrict__ O) {
  const int qt = 8 + blockIdx.x;
  const int bh = blockIdx.y;
  const int b = bh >> 4, h = bh & 15;
  const int j = qt >> 3;                       // 1..3
  const int base = 8 * (j * (j + 1) / 2) + (qt - 8 * j) * (j + 1);
  const int nch = j + 1;
  const int tid = threadIdx.x;
  const int lq = tid >> 2, dq = (tid & 3) * 16;
  const float C = 0.18033688f;

  float mc[4], lc[4];
  float m = -1e30f;
#pragma unroll
  for (int c = 0; c < 4; ++c) {
    if (c < nch) {
      const size_t sl = (size_t)(bh * 80 + base + c) * 128 + lq * 2;
      mc[c] = ml[sl];
      lc[c] = ml[sl + 1];
    } else { mc[c] = -1e30f; lc[c] = 0.f; }
    m = fmaxf(m, mc[c]);
  }
  float fac[4], lt = 0.f;
#pragma unroll
  for (int c = 0; c < 4; ++c) {
    fac[c] = (c < nch) ? exp2f((mc[c] - m) * C) : 0.f;
    lt += fac[c] * lc[c];
  }
  const float inv = 1.0f / lt;
  float acc[16];
#pragma unroll
  for (int i = 0; i < 16; ++i) acc[i] = 0.f;
#pragma unroll
  for (int c = 0; c < 4; ++c) {
    if (c >= nch) continue;
    const float* op = Opart + ((size_t)(bh * 80 + base + c) * 64 + lq) * 64 + dq;
#pragma unroll
    for (int i = 0; i < 16; i += 4) {
      const f32x4 v = *(const f32x4*)&op[i];
#pragma unroll
      for (int k = 0; k < 4; ++k) acc[i + k] += fac[c] * v[k];
    }
  }
  unsigned short* orow = O + (size_t)(b * 2048 + qt * 64 + lq) * 1024 + h * 64 + dq;
#pragma unroll
  for (int i = 0; i < 16; i += 2)
    *(unsigned*)&orow[i] = pk2(acc[i] * inv, acc[i + 1] * inv);
}

// ---------------------------------------------------------------------------
extern "C" void kernel_launch(void* const* d_in, const int* in_sizes, int n_in,
                              void* d_out, int out_size, void* d_ws, size_t ws_size,
                              hipStream_t stream) {
  (void)in_sizes; (void)n_in; (void)out_size; (void)ws_size;
  const float* x      = (const float*)d_in[0];
  const float* f_qk   = (const float*)d_in[1];
  const float* f_v    = (const float*)d_in[2];
  const float* r_qk   = (const float*)d_in[3];
  const float* r_v    = (const float*)d_in[4];
  const float* f_know = (const float*)d_in[5];
  const float* r_know = (const float*)d_in[6];
  const float* W_O    = (const float*)d_in[7];
  const float* gamma1 = (const float*)d_in[8];
  const float* beta1  = (const float*)d_in[9];
  const float* gamma2 = (const float*)d_in[10];
  const float* beta2  = (const float*)d_in[11];
  const float* w_fq   = (const float*)d_in[12];
  const float* w_fk   = (const float*)d_in[13];
  const float* w_fv   = (const float*)d_in[14];
  const float* w_rq   = (const float*)d_in[15];
  const float* w_rk   = (const float*)d_in[16];
  const float* w_rv   = (const float*)d_in[17];
  const float* w_kf   = (const float*)d_in[18];
  const float* w_kr   = (const float*)d_in[19];

  char* base = (char*)d_ws;
  size_t off = 0;
  auto alloc = [&](size_t b) { char* p = base + off; off += (b + 255) & ~(size_t)255; return p; };
  unsigned short* fcomb   = (unsigned short*)alloc(8388608);   // [4096][1024]
  unsigned short* fknowT  = (unsigned short*)alloc(8388608);   // [4096][1024]
  unsigned short* r_qkT   = (unsigned short*)alloc(4194304);   // [1024][2048]
  unsigned short* r_vT    = (unsigned short*)alloc(4194304);   // [1024][2048]
  unsigned short* r_knowT = (unsigned short*)alloc(8388608);   // [1024][4096]
  unsigned short* WO_bf   = (unsigned short*)alloc(2097152);   // [1024][1024]
  unsigned short* nx_bf   = (unsigned short*)alloc(8388608);   // [4096][1024]
  unsigned short* all_h   = (unsigned short*)alloc(33554432);  // [4096][4096]
  unsigned short* t_qk    = (unsigned short*)alloc(33554432);  // [8192][2048]
  unsigned short* t_v     = (unsigned short*)alloc(16777216);  // [4096][2048]; reused as x1 fp32
  unsigned short* QKbuf   = (unsigned short*)alloc(16777216);  // [8192][1024]
  unsigned short* VT      = (unsigned short*)alloc(8388608);   // [1024][4096]
  unsigned short* attn    = (unsigned short*)alloc(8388608);   // [4096][1024]
  float* x1 = (float*)t_v;  // t_v dead before x1 written
  float* Opart = (float*)all_h;               // flash split-K partials (dead region)
  float* mlbuf = (float*)(all_h + 20971520);  // byte offset 41943040
  // GEMM split-K partials also live in the (dead-by-then) all_h region:
  float* pA = (float*)all_h;                  // 16 MB
  float* pB = (float*)(all_h + 8388608);      // +16 MB (region is 33.55 MB)

  const dim3 blk256(256), blkT(32, 8);

  // weight preps
  transpose_bf<<<dim3(2, 32, 32), blkT, 0, stream>>>(f_qk, fcomb, 1024, 64);
  transpose_bf<<<dim3(2, 32, 32), blkT, 0, stream>>>(f_v, fcomb + (size_t)2048 * 1024, 1024, 64);
  transpose_bf<<<dim3(4, 32, 32), blkT, 0, stream>>>(f_know, fknowT, 1024, 128);
  transpose_bf<<<dim3(32, 64, 1), blkT, 0, stream>>>(r_qk, r_qkT, 2048, 1024);
  transpose_bf<<<dim3(32, 64, 1), blkT, 0, stream>>>(r_v, r_vT, 2048, 1024);
  transpose_bf<<<dim3(32, 128, 1), blkT, 0, stream>>>(r_know, r_knowT, 4096, 1024);
  convert_bf<<<4096, blk256, 0, stream>>>(W_O, WO_bf, 1048576);

  // attention circuit
  ln_kernel<<<4096, blk256, 0, stream>>>(x, gamma1, beta1, nx_bf);
  gemm_bt<<<dim3(32, 32), blk256, 0, stream>>>(nx_bf, fcomb, nullptr, all_h, 4096, 4096, 1024, 1, 0);
  mix_attn<<<4096, blk256, 0, stream>>>(all_h, w_fq, w_fk, w_fv, w_rq, w_rk, w_rv, t_qk, t_v);
  gemm_qkv<<<dim3(8, 96), blk256, 0, stream>>>(t_qk, t_v, r_qkT, r_vT, QKbuf, VT);
  flash_split<<<dim3(80, 32), blk256, 0, stream>>>(QKbuf, QKbuf + (size_t)4096 * 1024, VT, attn,
                                                   Opart, mlbuf);
  flash_reduce<<<dim3(24, 32), blk256, 0, stream>>>(Opart, mlbuf, attn);
  // W_O GEMM, split-K x2 (512 blocks) -> fp32 partials -> +x residual
  gemm_ks2<<<dim3(8, 64), blk256, 0, stream>>>(attn, WO_bf, pA, pB, 4096, 1024, 1024);
  reduce_add3<<<4096, blk256, 0, stream>>>(pA, pB, x, x1, 4194304);

  // knowledge circuit
  ln_kernel<<<4096, blk256, 0, stream>>>(x1, gamma2, beta2, nx_bf);
  gemm_bt<<<dim3(32, 32), blk256, 0, stream>>>(nx_bf, fknowT, nullptr, all_h, 4096, 4096, 1024, 1, 0);
  mix_know<<<4096, blk256, 0, stream>>>(all_h, w_kf, w_kr, t_qk);
  // knowledge restore GEMM, split-K x2 (512 blocks) -> +x1 residual -> d_out
  gemm_ks2<<<dim3(8, 64), blk256, 0, stream>>>(t_qk, r_knowT, pA, pB, 4096, 1024, 4096);
  reduce_add3<<<4096, blk256, 0, stream>>>(pA, pB, x1, (float*)d_out, 4194304);
}

// Round 9
// 552.584 us; speedup vs baseline: 1.2621x; 1.0318x over previous
//
#include <hip/hip_runtime.h>
#include <stdint.h>

// B=2,S=2048,D=1024,H=16,R=64,N=32,RK=128,DH=64. Tokens T=4096.

typedef __bf16 bf16x8 __attribute__((ext_vector_type(8)));
typedef float f32x4 __attribute__((ext_vector_type(4)));

__device__ __forceinline__ unsigned short f2b(float f) {
  union { float f; unsigned u; } v; v.f = f;
  unsigned u = v.u;
  unsigned r = (u + 0x7FFFu + ((u >> 16) & 1u)) >> 16;  // RNE
  return (unsigned short)r;
}
__device__ __forceinline__ float b2f(unsigned short h) {
  union { unsigned u; float f; } v; v.u = ((unsigned)h) << 16;
  return v.f;
}
__device__ __forceinline__ unsigned pk2(float lo, float hi) {
  return (unsigned)f2b(lo) | ((unsigned)f2b(hi) << 16);
}

// ---------------------------------------------------------------------------
// Generic bf16 GEMM: C[M,N] = A[M,K] @ Bt[N,K]^T.  128x128 tile, BK=64,
// XOR-swizzled LDS (conflict-free). mode 1 = bf16 out (only user now).
// ---------------------------------------------------------------------------
__global__ __launch_bounds__(256) void gemm_bt(
    const unsigned short* __restrict__ A, const unsigned short* __restrict__ Bt,
    void* __restrict__ out, int M, int N, int K) {
  __shared__ unsigned short lsA[128 * 64];
  __shared__ unsigned short lsB[128 * 64];
  const int tid = threadIdx.x;
  const int w = tid >> 6, lane = tid & 63;
  const int quad = lane >> 4, l16 = lane & 15;
  const int wr = w >> 1, wc = w & 1;
  const int row0 = blockIdx.y * 128;
  const int col0 = blockIdx.x * 128;

  const int srow = w * 32 + (lane >> 3);
  const int scg = ((lane & 7) ^ (lane >> 3)) * 8;
  const unsigned short* ap = A + (size_t)(row0 + srow) * K + scg;
  const unsigned short* bp = Bt + (size_t)(col0 + srow) * K + scg;

  const f32x4 fz = {0.f, 0.f, 0.f, 0.f};
  f32x4 acc[4][4];
#pragma unroll
  for (int i = 0; i < 4; ++i)
#pragma unroll
    for (int j = 0; j < 4; ++j) acc[i][j] = fz;

  for (int k0 = 0; k0 < K; k0 += 64) {
#pragma unroll
    for (int i = 0; i < 4; ++i) {
      __builtin_amdgcn_global_load_lds(
          (const __attribute__((address_space(1))) unsigned int*)(ap + (size_t)i * 8 * K + k0),
          (__attribute__((address_space(3))) unsigned int*)&lsA[(w * 32 + i * 8) * 64],
          16, 0, 0);
      __builtin_amdgcn_global_load_lds(
          (const __attribute__((address_space(1))) unsigned int*)(bp + (size_t)i * 8 * K + k0),
          (__attribute__((address_space(3))) unsigned int*)&lsB[(w * 32 + i * 8) * 64],
          16, 0, 0);
    }
    __syncthreads();
#pragma unroll
    for (int kk = 0; kk < 2; ++kk) {
      bf16x8 af[4], bfr[4];
      const int sl = (((kk * 4 + quad) ^ (l16 & 7)) * 8);
#pragma unroll
      for (int mt = 0; mt < 4; ++mt)
        af[mt] = *(const bf16x8*)&lsA[(wr * 64 + mt * 16 + l16) * 64 + sl];
#pragma unroll
      for (int nt = 0; nt < 4; ++nt)
        bfr[nt] = *(const bf16x8*)&lsB[(wc * 64 + nt * 16 + l16) * 64 + sl];
#pragma unroll
      for (int mt = 0; mt < 4; ++mt)
#pragma unroll
        for (int nt = 0; nt < 4; ++nt)
          acc[mt][nt] = __builtin_amdgcn_mfma_f32_16x16x32_bf16(af[mt], bfr[nt], acc[mt][nt], 0, 0, 0);
    }
    __syncthreads();
  }

  const int rb = row0 + wr * 64;
  const int cb = col0 + wc * 64;
#pragma unroll
  for (int mt = 0; mt < 4; ++mt) {
#pragma unroll
    for (int nt = 0; nt < 4; ++nt) {
      const int r = rb + mt * 16 + quad * 4;
      const int c = cb + nt * 16 + l16;
#pragma unroll
      for (int i = 0; i < 4; ++i)
        ((unsigned short*)out)[(size_t)(r + i) * N + c] = f2b(acc[mt][nt][i]);
    }
  }
}

// ---------------------------------------------------------------------------
// Fused Q/K(split-K x2) + V restore GEMM. 1280 blocks (V first: longer).
//  bid<256: V unit (full K=2048) -> VT transposed bf16
//  else: QK unit (K-half) -> bf16 partial pQK[ks]
// XCD-banded rows; XOR swizzle.
// ---------------------------------------------------------------------------
__global__ __launch_bounds__(256) void gemm_qkv2(
    const unsigned short* __restrict__ t_qk, const unsigned short* __restrict__ t_v,
    const unsigned short* __restrict__ r_qkT, const unsigned short* __restrict__ r_vT,
    unsigned short* __restrict__ pQK0, unsigned short* __restrict__ pQK1,
    unsigned short* __restrict__ VT) {
  __shared__ unsigned short lsA[128 * 64];
  __shared__ unsigned short lsB[128 * 64];
  const int K = 2048;
  const int bid = blockIdx.x;
  const unsigned short* A;
  const unsigned short* Bt;
  int row0, col0, kbeg, kend, kind;  // kind: 0=V, 1=QK ks0, 2=QK ks1
  if (bid < 256) {
    const int xcd = bid & 7, j = bid >> 3;           // 32 per xcd
    row0 = (xcd * 4 + (j >> 3)) * 128;
    col0 = (j & 7) * 128;
    A = t_v; Bt = r_vT; kbeg = 0; kend = K; kind = 0;
  } else {
    const int u = bid - 256;
    const int xcd = u & 7, j = u >> 3;               // 128 per xcd
    const int row_l = j >> 4, rem = j & 15;
    const int ks = rem >> 3, col = rem & 7;
    row0 = (xcd * 8 + row_l) * 128;
    col0 = col * 128;
    A = t_qk; Bt = r_qkT; kbeg = ks * 1024; kend = kbeg + 1024; kind = 1 + ks;
  }
  const int tid = threadIdx.x;
  const int w = tid >> 6, lane = tid & 63;
  const int quad = lane >> 4, l16 = lane & 15;
  const int wr = w >> 1, wc = w & 1;

  const int srow = w * 32 + (lane >> 3);
  const int scg = ((lane & 7) ^ (lane >> 3)) * 8;
  const unsigned short* ap = A + (size_t)(row0 + srow) * K + scg;
  const unsigned short* bp = Bt + (size_t)(col0 + srow) * K + scg;

  const f32x4 fz = {0.f, 0.f, 0.f, 0.f};
  f32x4 acc[4][4];
#pragma unroll
  for (int i = 0; i < 4; ++i)
#pragma unroll
    for (int jj = 0; jj < 4; ++jj) acc[i][jj] = fz;

  for (int k0 = kbeg; k0 < kend; k0 += 64) {
#pragma unroll
    for (int i = 0; i < 4; ++i) {
      __builtin_amdgcn_global_load_lds(
          (const __attribute__((address_space(1))) unsigned int*)(ap + (size_t)i * 8 * K + k0),
          (__attribute__((address_space(3))) unsigned int*)&lsA[(w * 32 + i * 8) * 64],
          16, 0, 0);
      __builtin_amdgcn_global_load_lds(
          (const __attribute__((address_space(1))) unsigned int*)(bp + (size_t)i * 8 * K + k0),
          (__attribute__((address_space(3))) unsigned int*)&lsB[(w * 32 + i * 8) * 64],
          16, 0, 0);
    }
    __syncthreads();
#pragma unroll
    for (int kk = 0; kk < 2; ++kk) {
      bf16x8 af[4], bfr[4];
      const int sl = (((kk * 4 + quad) ^ (l16 & 7)) * 8);
#pragma unroll
      for (int mt = 0; mt < 4; ++mt)
        af[mt] = *(const bf16x8*)&lsA[(wr * 64 + mt * 16 + l16) * 64 + sl];
#pragma unroll
      for (int nt = 0; nt < 4; ++nt)
        bfr[nt] = *(const bf16x8*)&lsB[(wc * 64 + nt * 16 + l16) * 64 + sl];
#pragma unroll
      for (int mt = 0; mt < 4; ++mt)
#pragma unroll
        for (int nt = 0; nt < 4; ++nt)
          acc[mt][nt] = __builtin_amdgcn_mfma_f32_16x16x32_bf16(af[mt], bfr[nt], acc[mt][nt], 0, 0, 0);
    }
    __syncthreads();
  }

  const int rb = row0 + wr * 64;
  const int cb = col0 + wc * 64;
  unsigned short* pout = (kind == 1) ? pQK0 : pQK1;
#pragma unroll
  for (int mt = 0; mt < 4; ++mt) {
#pragma unroll
    for (int nt = 0; nt < 4; ++nt) {
      const int r = rb + mt * 16 + quad * 4;
      const int c = cb + nt * 16 + l16;
#pragma unroll
      for (int i = 0; i < 4; ++i) {
        const float v = acc[mt][nt][i];
        if (kind == 0) VT[(size_t)c * 4096 + (r + i)] = f2b(v);
        else pout[(size_t)(r + i) * 1024 + c] = f2b(v);
      }
    }
  }
}

// QKbuf = bf16( b2f(p0) + b2f(p1) ), n = 8388608, 8 elems/thread
__global__ __launch_bounds__(256) void reduce_qk(
    const unsigned short* __restrict__ p0, const unsigned short* __restrict__ p1,
    unsigned short* __restrict__ out) {
  const int i = (blockIdx.x * 256 + threadIdx.x) * 8;
  uint4 a = *(const uint4*)&p0[i];
  uint4 b = *(const uint4*)&p1[i];
  unsigned r[4];
  const unsigned* aa = (const unsigned*)&a;
  const unsigned* bb = (const unsigned*)&b;
#pragma unroll
  for (int k = 0; k < 4; ++k) {
    const float lo = b2f((unsigned short)(aa[k] & 0xFFFF)) + b2f((unsigned short)(bb[k] & 0xFFFF));
    const float hi = b2f((unsigned short)(aa[k] >> 16)) + b2f((unsigned short)(bb[k] >> 16));
    r[k] = pk2(lo, hi);
  }
  *(uint4*)&out[i] = *(uint4*)r;
}

// ---------------------------------------------------------------------------
// Split-K x4 GEMM -> fp32 partials p0..p3. M=4096 fixed (32 row-tiles).
// 1024 blocks; XCD-banded (4 row-tiles/XCD x 4 ks x 8 cols).
// ---------------------------------------------------------------------------
__global__ __launch_bounds__(256) void gemm_ks4(
    const unsigned short* __restrict__ A, const unsigned short* __restrict__ Bt,
    float* __restrict__ p0, float* __restrict__ p1,
    float* __restrict__ p2, float* __restrict__ p3, int K) {
  __shared__ unsigned short lsA[128 * 64];
  __shared__ unsigned short lsB[128 * 64];
  const int N = 1024;
  const int bid = blockIdx.x;
  const int xcd = bid & 7, j = bid >> 3;        // 128 per xcd
  const int row_l = j >> 5, rem = j & 31;
  const int ks = rem >> 3, col = rem & 7;
  const int row0 = (xcd * 4 + row_l) * 128;
  const int col0 = col * 128;
  const int kq = K >> 2;
  const int kbeg = ks * kq, kend = kbeg + kq;
  const int tid = threadIdx.x;
  const int w = tid >> 6, lane = tid & 63;
  const int quad = lane >> 4, l16 = lane & 15;
  const int wr = w >> 1, wc = w & 1;

  const int srow = w * 32 + (lane >> 3);
  const int scg = ((lane & 7) ^ (lane >> 3)) * 8;
  const unsigned short* ap = A + (size_t)(row0 + srow) * K + scg;
  const unsigned short* bp = Bt + (size_t)(col0 + srow) * K + scg;

  const f32x4 fz = {0.f, 0.f, 0.f, 0.f};
  f32x4 acc[4][4];
#pragma unroll
  for (int i = 0; i < 4; ++i)
#pragma unroll
    for (int jj = 0; jj < 4; ++jj) acc[i][jj] = fz;

  for (int k0 = kbeg; k0 < kend; k0 += 64) {
#pragma unroll
    for (int i = 0; i < 4; ++i) {
      __builtin_amdgcn_global_load_lds(
          (const __attribute__((address_space(1))) unsigned int*)(ap + (size_t)i * 8 * K + k0),
          (__attribute__((address_space(3))) unsigned int*)&lsA[(w * 32 + i * 8) * 64],
          16, 0, 0);
      __builtin_amdgcn_global_load_lds(
          (const __attribute__((address_space(1))) unsigned int*)(bp + (size_t)i * 8 * K + k0),
          (__attribute__((address_space(3))) unsigned int*)&lsB[(w * 32 + i * 8) * 64],
          16, 0, 0);
    }
    __syncthreads();
#pragma unroll
    for (int kk = 0; kk < 2; ++kk) {
      bf16x8 af[4], bfr[4];
      const int sl = (((kk * 4 + quad) ^ (l16 & 7)) * 8);
#pragma unroll
      for (int mt = 0; mt < 4; ++mt)
        af[mt] = *(const bf16x8*)&lsA[(wr * 64 + mt * 16 + l16) * 64 + sl];
#pragma unroll
      for (int nt = 0; nt < 4; ++nt)
        bfr[nt] = *(const bf16x8*)&lsB[(wc * 64 + nt * 16 + l16) * 64 + sl];
#pragma unroll
      for (int mt = 0; mt < 4; ++mt)
#pragma unroll
        for (int nt = 0; nt < 4; ++nt)
          acc[mt][nt] = __builtin_amdgcn_mfma_f32_16x16x32_bf16(af[mt], bfr[nt], acc[mt][nt], 0, 0, 0);
    }
    __syncthreads();
  }

  float* out = (ks == 0) ? p0 : (ks == 1) ? p1 : (ks == 2) ? p2 : p3;
  const int rb = row0 + wr * 64;
  const int cb = col0 + wc * 64;
#pragma unroll
  for (int mt = 0; mt < 4; ++mt) {
#pragma unroll
    for (int nt = 0; nt < 4; ++nt) {
      const int r = rb + mt * 16 + quad * 4;
      const int c = cb + nt * 16 + l16;
#pragma unroll
      for (int i = 0; i < 4; ++i)
        out[(size_t)(r + i) * N + c] = acc[mt][nt][i];
    }
  }
}

// out = p0+p1+p2+p3+res (fp32, f32x4-vectorized), n = 4194304
__global__ __launch_bounds__(256) void reduce_add5(
    const float* __restrict__ p0, const float* __restrict__ p1,
    const float* __restrict__ p2, const float* __restrict__ p3,
    const float* __restrict__ res, float* __restrict__ out) {
  const int i = (blockIdx.x * 256 + threadIdx.x) * 4;
  const f32x4 a = *(const f32x4*)&p0[i];
  const f32x4 b = *(const f32x4*)&p1[i];
  const f32x4 c = *(const f32x4*)&p2[i];
  const f32x4 d = *(const f32x4*)&p3[i];
  const f32x4 e = *(const f32x4*)&res[i];
  f32x4 o;
#pragma unroll
  for (int k = 0; k < 4; ++k) o[k] = ((a[k] + b[k]) + (c[k] + d[k])) + e[k];
  *(f32x4*)&out[i] = o;
}

// ---------------------------------------------------------------------------
// LayerNorm over D=1024, one token per 256-thread block, bf16 out.
// ---------------------------------------------------------------------------
__global__ __launch_bounds__(256) void ln_kernel(
    const float* __restrict__ x, const float* __restrict__ g,
    const float* __restrict__ be, unsigned short* __restrict__ out) {
  __shared__ float sbuf[4];
  const int t = blockIdx.x, tid = threadIdx.x;
  const float* row = x + (size_t)t * 1024;
  float v[4], s = 0.f;
#pragma unroll
  for (int j = 0; j < 4; ++j) { v[j] = row[tid + j * 256]; s += v[j]; }
#pragma unroll
  for (int off = 32; off; off >>= 1) s += __shfl_xor(s, off);
  if ((tid & 63) == 0) sbuf[tid >> 6] = s;
  __syncthreads();
  const float mu = (sbuf[0] + sbuf[1] + sbuf[2] + sbuf[3]) * (1.f / 1024.f);
  __syncthreads();
  float ss = 0.f;
#pragma unroll
  for (int j = 0; j < 4; ++j) { const float d = v[j] - mu; ss += d * d; }
#pragma unroll
  for (int off = 32; off; off >>= 1) ss += __shfl_xor(ss, off);
  if ((tid & 63) == 0) sbuf[tid >> 6] = ss;
  __syncthreads();
  const float var = (sbuf[0] + sbuf[1] + sbuf[2] + sbuf[3]) * (1.f / 1024.f);
  const float rstd = rsqrtf(var + 1e-5f);
  unsigned short* orow = out + (size_t)t * 1024;
#pragma unroll
  for (int j = 0; j < 4; ++j) {
    const int c = tid + j * 256;
    orow[c] = f2b((v[j] - mu) * rstd * g[c] + be[c]);
  }
}

// ---------------------------------------------------------------------------
// Attention mixing.
// ---------------------------------------------------------------------------
__global__ __launch_bounds__(256) void mix_attn(
    const unsigned short* __restrict__ all_h,
    const float* __restrict__ w_fq, const float* __restrict__ w_fk,
    const float* __restrict__ w_fv, const float* __restrict__ w_rq,
    const float* __restrict__ w_rk, const float* __restrict__ w_rv,
    unsigned short* __restrict__ t_qk, unsigned short* __restrict__ t_v) {
  __shared__ float hq[64], hk[64], hv[64];
  const int t = blockIdx.x, tid = threadIdx.x;
  const int wv = tid >> 6, lane = tid & 63;
  const unsigned short* row = all_h + (size_t)t * 4096;
  if (wv < 3) {
    const float* wf = (wv == 0 ? w_fq : wv == 1 ? w_fk : w_fv) + (size_t)t * 32;
    const int base = (wv == 2) ? 2048 : 0;
    float acc = 0.f;
#pragma unroll
    for (int n = 0; n < 32; ++n) acc += wf[n] * b2f(row[base + n * 64 + lane]);
    (wv == 0 ? hq : wv == 1 ? hk : hv)[lane] = acc;
  }
  __syncthreads();
  const float* wrq = w_rq + (size_t)t * 32;
  const float* wrk = w_rk + (size_t)t * 32;
  const float* wrv = w_rv + (size_t)t * 32;
  for (int idx = tid; idx < 2048; idx += 256) {
    const int n = idx >> 6, r = idx & 63;
    t_qk[(size_t)t * 2048 + idx] = f2b(wrq[n] * hq[r]);
    t_qk[(size_t)(4096 + t) * 2048 + idx] = f2b(wrk[n] * hk[r]);
    t_v[(size_t)t * 2048 + idx] = f2b(wrv[n] * hv[r]);
  }
}

// Knowledge mixing (RK=128)
__global__ __launch_bounds__(256) void mix_know(
    const unsigned short* __restrict__ all_h, const float* __restrict__ w_f,
    const float* __restrict__ w_r, unsigned short* __restrict__ t_know) {
  __shared__ float h[128];
  const int t = blockIdx.x, tid = threadIdx.x;
  const unsigned short* row = all_h + (size_t)t * 4096;
  if (tid < 128) {
    const float* wf = w_f + (size_t)t * 32;
    float acc = 0.f;
#pragma unroll
    for (int n = 0; n < 32; ++n) acc += wf[n] * b2f(row[n * 128 + tid]);
    h[tid] = acc;
  }
  __syncthreads();
  const float* wr = w_r + (size_t)t * 32;
  for (int idx = tid; idx < 4096; idx += 256) {
    const int n = idx >> 7, r = idx & 127;
    t_know[(size_t)t * 4096 + idx] = f2b(wr[n] * h[r]);
  }
}

// ---------------------------------------------------------------------------
// Merged weight prep: 6 transposes + W_O convert in ONE dispatch.
// Block (32,8). Segments by blockIdx.x; transposes use 32x32 tiles.
// ---------------------------------------------------------------------------
__global__ __launch_bounds__(256) void prep_all(
    const float* __restrict__ f_qk, const float* __restrict__ f_v,
    const float* __restrict__ f_know, const float* __restrict__ r_qk,
    const float* __restrict__ r_v, const float* __restrict__ r_know,
    const float* __restrict__ W_O,
    unsigned short* __restrict__ fcomb, unsigned short* __restrict__ fknowT,
    unsigned short* __restrict__ r_qkT, unsigned short* __restrict__ r_vT,
    unsigned short* __restrict__ r_knowT, unsigned short* __restrict__ WO_bf) {
  __shared__ float tile[32][33];
  const int bid = blockIdx.x;
  const int tx = threadIdx.x, ty = threadIdx.y;
  const float* in;
  unsigned short* out;
  int R, C, gx, loc;
  if (bid < 2048)       { in = f_qk;   out = fcomb;                         R = 1024; C = 64;   gx = 2;  loc = bid; }
  else if (bid < 4096)  { in = f_v;    out = fcomb + (size_t)2048 * 1024;   R = 1024; C = 64;   gx = 2;  loc = bid - 2048; }
  else if (bid < 8192)  { in = f_know; out = fknowT;                        R = 1024; C = 128;  gx = 4;  loc = bid - 4096; }
  else if (bid < 10240) { in = r_qk;   out = r_qkT;                         R = 2048; C = 1024; gx = 32; loc = bid - 8192; }
  else if (bid < 12288) { in = r_v;    out = r_vT;                          R = 2048; C = 1024; gx = 32; loc = bid - 10240; }
  else if (bid < 16384) { in = r_know; out = r_knowT;                       R = 4096; C = 1024; gx = 32; loc = bid - 12288; }
  else {  // W_O convert: 1024 blocks x 256 threads x 4 floats
    const int i = ((bid - 16384) * 256 + ty * 32 + tx) * 4;
    const f32x4 v = *(const f32x4*)&W_O[i];
    *(unsigned*)&WO_bf[i] = pk2(v[0], v[1]);
    *(unsigned*)&WO_bf[i + 2] = pk2(v[2], v[3]);
    return;
  }
  const int tiles = gx * (R >> 5);
  const int bb = loc / tiles, rem = loc % tiles;
  const int r0 = (rem / gx) * 32, c0 = (rem % gx) * 32;
  const float* ip = in + (size_t)bb * R * C;
  unsigned short* op = out + (size_t)bb * R * C;
#pragma unroll
  for (int j = 0; j < 4; ++j)
    tile[ty + j * 8][tx] = ip[(size_t)(r0 + ty + j * 8) * C + c0 + tx];
  __syncthreads();
#pragma unroll
  for (int j = 0; j < 4; ++j)
    op[(size_t)(c0 + ty + j * 8) * R + r0 + tx] = f2b(tile[tx][ty + j * 8]);
}

// ---------------------------------------------------------------------------
// Causal flash attention: SPLIT-K over history, uniform work units.
// ---------------------------------------------------------------------------
__global__ __launch_bounds__(256) void flash_split(
    const unsigned short* __restrict__ Q, const unsigned short* __restrict__ Kp,
    const unsigned short* __restrict__ VT, unsigned short* __restrict__ O,
    float* __restrict__ Opart, float* __restrict__ ml) {
  __shared__ unsigned short Kls[2][64 * 64];
  __shared__ unsigned short Vls[2][64 * 64];
  const int uidx = 79 - (int)blockIdx.x;
  int uu = uidx, qt = 0, ch = 0;
  for (int q = 0; q < 32; ++q) {
    const int n = (q >> 3) + 1;
    if (uu < n) { qt = q; ch = uu; break; }
    uu -= n;
  }
  const int bh = blockIdx.y;
  const int b = bh >> 4, h = bh & 15;
  const int tid = threadIdx.x;
  const int w = tid >> 6, lane = tid & 63, quad = lane >> 4, l16 = lane & 15;
  const int tb = b * 2048;
  const int qrow = qt * 64 + w * 16;
  const int ktlo = ch * 8;
  const int kthi = min(qt, ch * 8 + 7);
  const float C = 0.18033688f;  // (1/sqrt(64)) * log2(e)

  const int srow = (lane >> 3);
  const int scol = ((lane & 7) ^ srow) * 8;

  bf16x8 qf[2];
#pragma unroll
  for (int kk = 0; kk < 2; ++kk)
    qf[kk] = *(const bf16x8*)&Q[(size_t)(tb + qrow + l16) * 1024 + h * 64 + kk * 32 + quad * 8];

  const f32x4 fz = {0.f, 0.f, 0.f, 0.f};
  float m_i = -1e30f, l_i = 0.f;
  f32x4 o_acc[4];
#pragma unroll
  for (int nt = 0; nt < 4; ++nt) o_acc[nt] = fz;

  auto stage = [&](int buf, int kt) {
#pragma unroll
    for (int j = 0; j < 2; ++j) {
      const int rg = (w * 2 + j) * 8 + srow;
      __builtin_amdgcn_global_load_lds(
          (const __attribute__((address_space(1))) unsigned int*)
              (Kp + (size_t)(tb + kt * 64 + rg) * 1024 + h * 64 + scol),
          (__attribute__((address_space(3))) unsigned int*)&Kls[buf][(w * 2 + j) * 8 * 64],
          16, 0, 0);
      __builtin_amdgcn_global_load_lds(
          (const __attribute__((address_space(1))) unsigned int*)
              (VT + (size_t)(h * 64 + rg) * 4096 + tb + kt * 64 + scol),
          (__attribute__((address_space(3))) unsigned int*)&Vls[buf][(w * 2 + j) * 8 * 64],
          16, 0, 0);
    }
  };

  const int srcA = (((quad & 1) * 32 + l16) << 2);
  const int srcB = srcA + 64;
  const bool hiq = (quad >= 2);

  stage(0, ktlo);
  __syncthreads();
  int buf = 0;
  for (int kt = ktlo; kt <= kthi; ++kt) {
    bf16x8 kf[8], vf[8];
#pragma unroll
    for (int kk = 0; kk < 2; ++kk)
#pragma unroll
      for (int nt = 0; nt < 4; ++nt) {
        const int sl = (((kk * 4 + quad) ^ (l16 & 7)) * 8);
        kf[kk * 4 + nt] = *(const bf16x8*)&Kls[buf][(nt * 16 + l16) * 64 + sl];
        vf[kk * 4 + nt] = *(const bf16x8*)&Vls[buf][(nt * 16 + l16) * 64 + sl];
      }
    if (kt < kthi) stage(buf ^ 1, kt + 1);

    const bool diag = (kt == qt);
    f32x4 s[4];
#pragma unroll
    for (int nt = 0; nt < 4; ++nt) s[nt] = fz;
#pragma unroll
    for (int kk = 0; kk < 2; ++kk)
#pragma unroll
      for (int nt = 0; nt < 4; ++nt)
        if (!diag || nt <= w)
          s[nt] = __builtin_amdgcn_mfma_f32_16x16x32_bf16(kf[kk * 4 + nt], qf[kk], s[nt], 0, 0, 0);

    const int qloc = w * 16 + l16;
    float mx = -1e30f;
#pragma unroll
    for (int nt = 0; nt < 4; ++nt)
#pragma unroll
      for (int i = 0; i < 4; ++i) {
        float v = s[nt][i];
        if (diag && (nt * 16 + quad * 4 + i) > qloc) v = -1e30f;
        s[nt][i] = v;
        mx = fmaxf(mx, v);
      }
    mx = fmaxf(mx, __shfl_xor(mx, 16));
    mx = fmaxf(mx, __shfl_xor(mx, 32));
    const float mn = fmaxf(m_i, mx);
    const float al = exp2f((m_i - mn) * C);
    m_i = mn;
    const float mC = mn * C;
    float rs = 0.f;
#pragma unroll
    for (int nt = 0; nt < 4; ++nt)
#pragma unroll
      for (int i = 0; i < 4; ++i) {
        const float p = exp2f(fmaf(s[nt][i], C, -mC));
        s[nt][i] = p;
        rs += p;
      }
    rs += __shfl_xor(rs, 16);
    rs += __shfl_xor(rs, 32);
    l_i = l_i * al + rs;
#pragma unroll
    for (int nt = 0; nt < 4; ++nt)
#pragma unroll
      for (int i = 0; i < 4; ++i) o_acc[nt][i] *= al;

    unsigned pk[4][2];
#pragma unroll
    for (int nt = 0; nt < 4; ++nt) {
      pk[nt][0] = pk2(s[nt][0], s[nt][1]);
      pk[nt][1] = pk2(s[nt][2], s[nt][3]);
    }
#pragma unroll
    for (int kk = 0; kk < 2; ++kk) {
      const int ea = 2 * kk, eb = 2 * kk + 1;
      const unsigned u0 = __builtin_amdgcn_ds_bpermute(srcA, pk[ea][0]);
      const unsigned u1 = __builtin_amdgcn_ds_bpermute(srcA, pk[ea][1]);
      const unsigned u2 = __builtin_amdgcn_ds_bpermute(srcB, pk[ea][0]);
      const unsigned u3 = __builtin_amdgcn_ds_bpermute(srcB, pk[ea][1]);
      const unsigned w0 = __builtin_amdgcn_ds_bpermute(srcA, pk[eb][0]);
      const unsigned w1 = __builtin_amdgcn_ds_bpermute(srcA, pk[eb][1]);
      const unsigned w2 = __builtin_amdgcn_ds_bpermute(srcB, pk[eb][0]);
      const unsigned w3 = __builtin_amdgcn_ds_bpermute(srcB, pk[eb][1]);
      unsigned dw[4];
      dw[0] = hiq ? w0 : u0;
      dw[1] = hiq ? w1 : u1;
      dw[2] = hiq ? w2 : u2;
      dw[3] = hiq ? w3 : u3;
      const bf16x8 pf = *(const bf16x8*)dw;
#pragma unroll
      for (int nt = 0; nt < 4; ++nt)
        o_acc[nt] = __builtin_amdgcn_mfma_f32_16x16x32_bf16(vf[kk * 4 + nt], pf, o_acc[nt], 0, 0, 0);
    }
    __syncthreads();
    buf ^= 1;
  }

  const int nch = (qt >> 3) + 1;
  if (nch == 1) {
    const float inv = 1.0f / l_i;
    unsigned short* orow = O + (size_t)(tb + qrow + l16) * 1024 + h * 64;
#pragma unroll
    for (int nt = 0; nt < 4; ++nt) {
      const unsigned d0 = pk2(o_acc[nt][0] * inv, o_acc[nt][1] * inv);
      const unsigned d1 = pk2(o_acc[nt][2] * inv, o_acc[nt][3] * inv);
      *(unsigned*)&orow[nt * 16 + quad * 4] = d0;
      *(unsigned*)&orow[nt * 16 + quad * 4 + 2] = d1;
    }
  } else {
    const int slot = bh * 80 + uidx;
    const int lq = w * 16 + l16;
    float* op = Opart + ((size_t)slot * 64 + lq) * 64;
#pragma unroll
    for (int nt = 0; nt < 4; ++nt)
      *(f32x4*)&op[nt * 16 + quad * 4] = o_acc[nt];
    if (quad == 0) {
      ml[(size_t)slot * 128 + lq * 2] = m_i;
      ml[(size_t)slot * 128 + lq * 2 + 1] = l_i;
    }
  }
}

// ---------------------------------------------------------------------------
// Combine flash split-K partials for qt in [8,31]. Grid (24, 32).
// ---------------------------------------------------------------------------
__global__ __launch_bounds__(256) void flash_reduce(
    const float* __restrict__ Opart, const float* __restrict__ ml,
    unsigned short* __restrict__ O) {
  const int qt = 8 + blockIdx.x;
  const int bh = blockIdx.y;
  const int b = bh >> 4, h = bh & 15;
  const int j = qt >> 3;
  const int base = 8 * (j * (j + 1) / 2) + (qt - 8 * j) * (j + 1);
  const int nch = j + 1;
  const int tid = threadIdx.x;
  const int lq = tid >> 2, dq = (tid & 3) * 16;
  const float C = 0.18033688f;

  float mc[4], lc[4];
  float m = -1e30f;
#pragma unroll
  for (int c = 0; c < 4; ++c) {
    if (c < nch) {
      const size_t sl = (size_t)(bh * 80 + base + c) * 128 + lq * 2;
      mc[c] = ml[sl];
      lc[c] = ml[sl + 1];
    } else { mc[c] = -1e30f; lc[c] = 0.f; }
    m = fmaxf(m, mc[c]);
  }
  float fac[4], lt = 0.f;
#pragma unroll
  for (int c = 0; c < 4; ++c) {
    fac[c] = (c < nch) ? exp2f((mc[c] - m) * C) : 0.f;
    lt += fac[c] * lc[c];
  }
  const float inv = 1.0f / lt;
  float acc[16];
#pragma unroll
  for (int i = 0; i < 16; ++i) acc[i] = 0.f;
#pragma unroll
  for (int c = 0; c < 4; ++c) {
    if (c >= nch) continue;
    const float* op = Opart + ((size_t)(bh * 80 + base + c) * 64 + lq) * 64 + dq;
#pragma unroll
    for (int i = 0; i < 16; i += 4) {
      const f32x4 v = *(const f32x4*)&op[i];
#pragma unroll
      for (int k = 0; k < 4; ++k) acc[i + k] += fac[c] * v[k];
    }
  }
  unsigned short* orow = O + (size_t)(b * 2048 + qt * 64 + lq) * 1024 + h * 64 + dq;
#pragma unroll
  for (int i = 0; i < 16; i += 2)
    *(unsigned*)&orow[i] = pk2(acc[i] * inv, acc[i + 1] * inv);
}

// ---------------------------------------------------------------------------
extern "C" void kernel_launch(void* const* d_in, const int* in_sizes, int n_in,
                              void* d_out, int out_size, void* d_ws, size_t ws_size,
                              hipStream_t stream) {
  (void)in_sizes; (void)n_in; (void)out_size; (void)ws_size;
  const float* x      = (const float*)d_in[0];
  const float* f_qk   = (const float*)d_in[1];
  const float* f_v    = (const float*)d_in[2];
  const float* r_qk   = (const float*)d_in[3];
  const float* r_v    = (const float*)d_in[4];
  const float* f_know = (const float*)d_in[5];
  const float* r_know = (const float*)d_in[6];
  const float* W_O    = (const float*)d_in[7];
  const float* gamma1 = (const float*)d_in[8];
  const float* beta1  = (const float*)d_in[9];
  const float* gamma2 = (const float*)d_in[10];
  const float* beta2  = (const float*)d_in[11];
  const float* w_fq   = (const float*)d_in[12];
  const float* w_fk   = (const float*)d_in[13];
  const float* w_fv   = (const float*)d_in[14];
  const float* w_rq   = (const float*)d_in[15];
  const float* w_rk   = (const float*)d_in[16];
  const float* w_rv   = (const float*)d_in[17];
  const float* w_kf   = (const float*)d_in[18];
  const float* w_kr   = (const float*)d_in[19];

  char* base = (char*)d_ws;
  size_t off = 0;
  auto alloc = [&](size_t b) { char* p = base + off; off += (b + 255) & ~(size_t)255; return p; };
  unsigned short* fcomb   = (unsigned short*)alloc(8388608);   // [4096][1024]
  unsigned short* fknowT  = (unsigned short*)alloc(8388608);   // [4096][1024]
  unsigned short* r_qkT   = (unsigned short*)alloc(4194304);   // [1024][2048]
  unsigned short* r_vT    = (unsigned short*)alloc(4194304);   // [1024][2048]
  unsigned short* r_knowT = (unsigned short*)alloc(8388608);   // [1024][4096]
  unsigned short* WO_bf   = (unsigned short*)alloc(2097152);   // [1024][1024]
  unsigned short* nx_bf   = (unsigned short*)alloc(8388608);   // [4096][1024]
  unsigned short* all_h   = (unsigned short*)alloc(33554432);  // [4096][4096]
  unsigned short* t_qk    = (unsigned short*)alloc(33554432);  // [8192][2048]
  unsigned short* t_v     = (unsigned short*)alloc(16777216);  // [4096][2048]; reused as x1 fp32
  unsigned short* QKbuf   = (unsigned short*)alloc(16777216);  // [8192][1024]
  unsigned short* VT      = (unsigned short*)alloc(8388608);   // [1024][4096]
  unsigned short* attn    = (unsigned short*)alloc(8388608);   // [4096][1024]
  float* x1 = (float*)t_v;                    // t_v dead before x1 written
  // dead-region aliases (sequential reuse, no overlap in time):
  unsigned short* pQK0 = all_h;               // bf16 QK partial ks=0 (16 MB)
  unsigned short* pQK1 = all_h + 8388608;     // bf16 QK partial ks=1 (16 MB)
  float* Opart = (float*)all_h;               // flash partials (42 MB, spills into dead t_qk)
  float* mlbuf = (float*)((char*)all_h + 41943040);
  float* pW0 = (float*)all_h;                 // ks4 fp32 partials (4 x 16 MB)
  float* pW1 = (float*)((char*)all_h + 16777216);
  float* pW2 = (float*)QKbuf;
  float* pW3 = (float*)VT;                    // VT(8MB)+attn(8MB) contiguous — but attn
                                              // is ALIVE for WO gemm; use only for knowledge?
  // VT is 8 MB; pW3 needs 16 MB -> VT+attn contiguous region. attn alive during WO.
  // For WO use nx_bf(8MB)+? -> instead: pW3 = t_qk region end (dead during WO; during
  // knowledge gemm t_qk is ALIVE). So pass per-call pointers below.
  float* pW3_wo   = (float*)t_qk;             // t_qk dead during WO gemm (16 MB ok)
  float* pW3_know = (float*)VT;               // VT+attn dead during knowledge gemm

  const dim3 blk256(256), blkT(32, 8);

  // merged weight prep (1 dispatch)
  prep_all<<<17408, blkT, 0, stream>>>(f_qk, f_v, f_know, r_qk, r_v, r_know, W_O,
                                       fcomb, fknowT, r_qkT, r_vT, r_knowT, WO_bf);

  // attention circuit
  ln_kernel<<<4096, blk256, 0, stream>>>(x, gamma1, beta1, nx_bf);
  gemm_bt<<<dim3(32, 32), blk256, 0, stream>>>(nx_bf, fcomb, all_h, 4096, 4096, 1024);
  mix_attn<<<4096, blk256, 0, stream>>>(all_h, w_fq, w_fk, w_fv, w_rq, w_rk, w_rv, t_qk, t_v);
  gemm_qkv2<<<1280, blk256, 0, stream>>>(t_qk, t_v, r_qkT, r_vT, pQK0, pQK1, VT);
  reduce_qk<<<4096, blk256, 0, stream>>>(pQK0, pQK1, QKbuf);
  flash_split<<<dim3(80, 32), blk256, 0, stream>>>(QKbuf, QKbuf + (size_t)4096 * 1024, VT, attn,
                                                   Opart, mlbuf);
  flash_reduce<<<dim3(24, 32), blk256, 0, stream>>>(Opart, mlbuf, attn);
  // W_O GEMM split-K x4 (1024 blocks): partials in all_h(2) + QKbuf + t_qk (all dead)
  gemm_ks4<<<1024, blk256, 0, stream>>>(attn, WO_bf, pW0, pW1, pW2, pW3_wo, 1024);
  reduce_add5<<<4096, blk256, 0, stream>>>(pW0, pW1, pW2, pW3_wo, x, x1);

  // knowledge circuit
  ln_kernel<<<4096, blk256, 0, stream>>>(x1, gamma2, beta2, nx_bf);
  gemm_bt<<<dim3(32, 32), blk256, 0, stream>>>(nx_bf, fknowT, all_h, 4096, 4096, 1024);
  mix_know<<<4096, blk256, 0, stream>>>(all_h, w_kf, w_kr, t_qk);
  // knowledge GEMM split-K x4: partials in all_h(2) + QKbuf + VT/attn (all dead)
  gemm_ks4<<<1024, blk256, 0, stream>>>(t_qk, r_knowT, pW0, pW1, pW2, pW3_know, 4096);
  reduce_add5<<<4096, blk256, 0, stream>>>(pW0, pW1, pW2, pW3_know, x1, (float*)d_out);
}

// Round 10
// 543.627 us; speedup vs baseline: 1.2829x; 1.0165x over previous
//
#include <hip/hip_runtime.h>
#include <stdint.h>

// B=2,S=2048,D=1024,H=16,R=64,N=32,RK=128,DH=64. Tokens T=4096.

typedef __bf16 bf16x8 __attribute__((ext_vector_type(8)));
typedef float f32x4 __attribute__((ext_vector_type(4)));

__device__ __forceinline__ unsigned short f2b(float f) {
  union { float f; unsigned u; } v; v.f = f;
  unsigned u = v.u;
  unsigned r = (u + 0x7FFFu + ((u >> 16) & 1u)) >> 16;  // RNE
  return (unsigned short)r;
}
__device__ __forceinline__ float b2f(unsigned short h) {
  union { unsigned u; float f; } v; v.u = ((unsigned)h) << 16;
  return v.f;
}
__device__ __forceinline__ unsigned pk2(float lo, float hi) {
  return (unsigned)f2b(lo) | ((unsigned)f2b(hi) << 16);
}
// truncation pack: one v_perm_b32 (bytes: [hi.b3, hi.b2, lo.b3, lo.b2])
__device__ __forceinline__ unsigned pkt(float lo, float hi) {
  union { float f; unsigned u; } a, b; a.f = lo; b.f = hi;
  return __builtin_amdgcn_perm(b.u, a.u, 0x07060302u);
}

// ---------------------------------------------------------------------------
// Generic bf16 GEMM: C[M,N] = A[M,K] @ Bt[N,K]^T.  128x128 tile, BK=64,
// XOR-swizzled LDS (conflict-free). bf16 out.
// ---------------------------------------------------------------------------
__global__ __launch_bounds__(256) void gemm_bt(
    const unsigned short* __restrict__ A, const unsigned short* __restrict__ Bt,
    void* __restrict__ out, int M, int N, int K) {
  __shared__ unsigned short lsA[128 * 64];
  __shared__ unsigned short lsB[128 * 64];
  const int tid = threadIdx.x;
  const int w = tid >> 6, lane = tid & 63;
  const int quad = lane >> 4, l16 = lane & 15;
  const int wr = w >> 1, wc = w & 1;
  const int row0 = blockIdx.y * 128;
  const int col0 = blockIdx.x * 128;

  const int srow = w * 32 + (lane >> 3);
  const int scg = ((lane & 7) ^ (lane >> 3)) * 8;
  const unsigned short* ap = A + (size_t)(row0 + srow) * K + scg;
  const unsigned short* bp = Bt + (size_t)(col0 + srow) * K + scg;

  const f32x4 fz = {0.f, 0.f, 0.f, 0.f};
  f32x4 acc[4][4];
#pragma unroll
  for (int i = 0; i < 4; ++i)
#pragma unroll
    for (int j = 0; j < 4; ++j) acc[i][j] = fz;

  for (int k0 = 0; k0 < K; k0 += 64) {
#pragma unroll
    for (int i = 0; i < 4; ++i) {
      __builtin_amdgcn_global_load_lds(
          (const __attribute__((address_space(1))) unsigned int*)(ap + (size_t)i * 8 * K + k0),
          (__attribute__((address_space(3))) unsigned int*)&lsA[(w * 32 + i * 8) * 64],
          16, 0, 0);
      __builtin_amdgcn_global_load_lds(
          (const __attribute__((address_space(1))) unsigned int*)(bp + (size_t)i * 8 * K + k0),
          (__attribute__((address_space(3))) unsigned int*)&lsB[(w * 32 + i * 8) * 64],
          16, 0, 0);
    }
    __syncthreads();
#pragma unroll
    for (int kk = 0; kk < 2; ++kk) {
      bf16x8 af[4], bfr[4];
      const int sl = (((kk * 4 + quad) ^ (l16 & 7)) * 8);
#pragma unroll
      for (int mt = 0; mt < 4; ++mt)
        af[mt] = *(const bf16x8*)&lsA[(wr * 64 + mt * 16 + l16) * 64 + sl];
#pragma unroll
      for (int nt = 0; nt < 4; ++nt)
        bfr[nt] = *(const bf16x8*)&lsB[(wc * 64 + nt * 16 + l16) * 64 + sl];
#pragma unroll
      for (int mt = 0; mt < 4; ++mt)
#pragma unroll
        for (int nt = 0; nt < 4; ++nt)
          acc[mt][nt] = __builtin_amdgcn_mfma_f32_16x16x32_bf16(af[mt], bfr[nt], acc[mt][nt], 0, 0, 0);
    }
    __syncthreads();
  }

  const int rb = row0 + wr * 64;
  const int cb = col0 + wc * 64;
#pragma unroll
  for (int mt = 0; mt < 4; ++mt) {
#pragma unroll
    for (int nt = 0; nt < 4; ++nt) {
      const int r = rb + mt * 16 + quad * 4;
      const int c = cb + nt * 16 + l16;
#pragma unroll
      for (int i = 0; i < 4; ++i)
        ((unsigned short*)out)[(size_t)(r + i) * N + c] = f2b(acc[mt][nt][i]);
    }
  }
}

// ---------------------------------------------------------------------------
// Fused Q/K(split-K x2) + V restore GEMM. 1280 blocks (V first: longer).
// ---------------------------------------------------------------------------
__global__ __launch_bounds__(256) void gemm_qkv2(
    const unsigned short* __restrict__ t_qk, const unsigned short* __restrict__ t_v,
    const unsigned short* __restrict__ r_qkT, const unsigned short* __restrict__ r_vT,
    unsigned short* __restrict__ pQK0, unsigned short* __restrict__ pQK1,
    unsigned short* __restrict__ VT) {
  __shared__ unsigned short lsA[128 * 64];
  __shared__ unsigned short lsB[128 * 64];
  const int K = 2048;
  const int bid = blockIdx.x;
  const unsigned short* A;
  const unsigned short* Bt;
  int row0, col0, kbeg, kend, kind;  // kind: 0=V, 1=QK ks0, 2=QK ks1
  if (bid < 256) {
    const int xcd = bid & 7, j = bid >> 3;
    row0 = (xcd * 4 + (j >> 3)) * 128;
    col0 = (j & 7) * 128;
    A = t_v; Bt = r_vT; kbeg = 0; kend = K; kind = 0;
  } else {
    const int u = bid - 256;
    const int xcd = u & 7, j = u >> 3;
    const int row_l = j >> 4, rem = j & 15;
    const int ks = rem >> 3, col = rem & 7;
    row0 = (xcd * 8 + row_l) * 128;
    col0 = col * 128;
    A = t_qk; Bt = r_qkT; kbeg = ks * 1024; kend = kbeg + 1024; kind = 1 + ks;
  }
  const int tid = threadIdx.x;
  const int w = tid >> 6, lane = tid & 63;
  const int quad = lane >> 4, l16 = lane & 15;
  const int wr = w >> 1, wc = w & 1;

  const int srow = w * 32 + (lane >> 3);
  const int scg = ((lane & 7) ^ (lane >> 3)) * 8;
  const unsigned short* ap = A + (size_t)(row0 + srow) * K + scg;
  const unsigned short* bp = Bt + (size_t)(col0 + srow) * K + scg;

  const f32x4 fz = {0.f, 0.f, 0.f, 0.f};
  f32x4 acc[4][4];
#pragma unroll
  for (int i = 0; i < 4; ++i)
#pragma unroll
    for (int jj = 0; jj < 4; ++jj) acc[i][jj] = fz;

  for (int k0 = kbeg; k0 < kend; k0 += 64) {
#pragma unroll
    for (int i = 0; i < 4; ++i) {
      __builtin_amdgcn_global_load_lds(
          (const __attribute__((address_space(1))) unsigned int*)(ap + (size_t)i * 8 * K + k0),
          (__attribute__((address_space(3))) unsigned int*)&lsA[(w * 32 + i * 8) * 64],
          16, 0, 0);
      __builtin_amdgcn_global_load_lds(
          (const __attribute__((address_space(1))) unsigned int*)(bp + (size_t)i * 8 * K + k0),
          (__attribute__((address_space(3))) unsigned int*)&lsB[(w * 32 + i * 8) * 64],
          16, 0, 0);
    }
    __syncthreads();
#pragma unroll
    for (int kk = 0; kk < 2; ++kk) {
      bf16x8 af[4], bfr[4];
      const int sl = (((kk * 4 + quad) ^ (l16 & 7)) * 8);
#pragma unroll
      for (int mt = 0; mt < 4; ++mt)
        af[mt] = *(const bf16x8*)&lsA[(wr * 64 + mt * 16 + l16) * 64 + sl];
#pragma unroll
      for (int nt = 0; nt < 4; ++nt)
        bfr[nt] = *(const bf16x8*)&lsB[(wc * 64 + nt * 16 + l16) * 64 + sl];
#pragma unroll
      for (int mt = 0; mt < 4; ++mt)
#pragma unroll
        for (int nt = 0; nt < 4; ++nt)
          acc[mt][nt] = __builtin_amdgcn_mfma_f32_16x16x32_bf16(af[mt], bfr[nt], acc[mt][nt], 0, 0, 0);
    }
    __syncthreads();
  }

  const int rb = row0 + wr * 64;
  const int cb = col0 + wc * 64;
  unsigned short* pout = (kind == 1) ? pQK0 : pQK1;
#pragma unroll
  for (int mt = 0; mt < 4; ++mt) {
#pragma unroll
    for (int nt = 0; nt < 4; ++nt) {
      const int r = rb + mt * 16 + quad * 4;
      const int c = cb + nt * 16 + l16;
#pragma unroll
      for (int i = 0; i < 4; ++i) {
        const float v = acc[mt][nt][i];
        if (kind == 0) VT[(size_t)c * 4096 + (r + i)] = f2b(v);
        else pout[(size_t)(r + i) * 1024 + c] = f2b(v);
      }
    }
  }
}

// QKbuf = bf16( b2f(p0) + b2f(p1) ), 8 elems/thread
__global__ __launch_bounds__(256) void reduce_qk(
    const unsigned short* __restrict__ p0, const unsigned short* __restrict__ p1,
    unsigned short* __restrict__ out) {
  const int i = (blockIdx.x * 256 + threadIdx.x) * 8;
  uint4 a = *(const uint4*)&p0[i];
  uint4 b = *(const uint4*)&p1[i];
  unsigned r[4];
  const unsigned* aa = (const unsigned*)&a;
  const unsigned* bb = (const unsigned*)&b;
#pragma unroll
  for (int k = 0; k < 4; ++k) {
    const float lo = b2f((unsigned short)(aa[k] & 0xFFFF)) + b2f((unsigned short)(bb[k] & 0xFFFF));
    const float hi = b2f((unsigned short)(aa[k] >> 16)) + b2f((unsigned short)(bb[k] >> 16));
    r[k] = pk2(lo, hi);
  }
  *(uint4*)&out[i] = *(uint4*)r;
}

// ---------------------------------------------------------------------------
// Split-K x4 GEMM -> fp32 partials. M=4096 fixed; 1024 blocks, XCD-banded.
// ---------------------------------------------------------------------------
__global__ __launch_bounds__(256) void gemm_ks4(
    const unsigned short* __restrict__ A, const unsigned short* __restrict__ Bt,
    float* __restrict__ p0, float* __restrict__ p1,
    float* __restrict__ p2, float* __restrict__ p3, int K) {
  __shared__ unsigned short lsA[128 * 64];
  __shared__ unsigned short lsB[128 * 64];
  const int N = 1024;
  const int bid = blockIdx.x;
  const int xcd = bid & 7, j = bid >> 3;
  const int row_l = j >> 5, rem = j & 31;
  const int ks = rem >> 3, col = rem & 7;
  const int row0 = (xcd * 4 + row_l) * 128;
  const int col0 = col * 128;
  const int kq = K >> 2;
  const int kbeg = ks * kq, kend = kbeg + kq;
  const int tid = threadIdx.x;
  const int w = tid >> 6, lane = tid & 63;
  const int quad = lane >> 4, l16 = lane & 15;
  const int wr = w >> 1, wc = w & 1;

  const int srow = w * 32 + (lane >> 3);
  const int scg = ((lane & 7) ^ (lane >> 3)) * 8;
  const unsigned short* ap = A + (size_t)(row0 + srow) * K + scg;
  const unsigned short* bp = Bt + (size_t)(col0 + srow) * K + scg;

  const f32x4 fz = {0.f, 0.f, 0.f, 0.f};
  f32x4 acc[4][4];
#pragma unroll
  for (int i = 0; i < 4; ++i)
#pragma unroll
    for (int jj = 0; jj < 4; ++jj) acc[i][jj] = fz;

  for (int k0 = kbeg; k0 < kend; k0 += 64) {
#pragma unroll
    for (int i = 0; i < 4; ++i) {
      __builtin_amdgcn_global_load_lds(
          (const __attribute__((address_space(1))) unsigned int*)(ap + (size_t)i * 8 * K + k0),
          (__attribute__((address_space(3))) unsigned int*)&lsA[(w * 32 + i * 8) * 64],
          16, 0, 0);
      __builtin_amdgcn_global_load_lds(
          (const __attribute__((address_space(1))) unsigned int*)(bp + (size_t)i * 8 * K + k0),
          (__attribute__((address_space(3))) unsigned int*)&lsB[(w * 32 + i * 8) * 64],
          16, 0, 0);
    }
    __syncthreads();
#pragma unroll
    for (int kk = 0; kk < 2; ++kk) {
      bf16x8 af[4], bfr[4];
      const int sl = (((kk * 4 + quad) ^ (l16 & 7)) * 8);
#pragma unroll
      for (int mt = 0; mt < 4; ++mt)
        af[mt] = *(const bf16x8*)&lsA[(wr * 64 + mt * 16 + l16) * 64 + sl];
#pragma unroll
      for (int nt = 0; nt < 4; ++nt)
        bfr[nt] = *(const bf16x8*)&lsB[(wc * 64 + nt * 16 + l16) * 64 + sl];
#pragma unroll
      for (int mt = 0; mt < 4; ++mt)
#pragma unroll
        for (int nt = 0; nt < 4; ++nt)
          acc[mt][nt] = __builtin_amdgcn_mfma_f32_16x16x32_bf16(af[mt], bfr[nt], acc[mt][nt], 0, 0, 0);
    }
    __syncthreads();
  }

  float* out = (ks == 0) ? p0 : (ks == 1) ? p1 : (ks == 2) ? p2 : p3;
  const int rb = row0 + wr * 64;
  const int cb = col0 + wc * 64;
#pragma unroll
  for (int mt = 0; mt < 4; ++mt) {
#pragma unroll
    for (int nt = 0; nt < 4; ++nt) {
      const int r = rb + mt * 16 + quad * 4;
      const int c = cb + nt * 16 + l16;
#pragma unroll
      for (int i = 0; i < 4; ++i)
        out[(size_t)(r + i) * N + c] = acc[mt][nt][i];
    }
  }
}

// out = p0+p1+p2+p3+res (fp32)
__global__ __launch_bounds__(256) void reduce_add5(
    const float* __restrict__ p0, const float* __restrict__ p1,
    const float* __restrict__ p2, const float* __restrict__ p3,
    const float* __restrict__ res, float* __restrict__ out) {
  const int i = (blockIdx.x * 256 + threadIdx.x) * 4;
  const f32x4 a = *(const f32x4*)&p0[i];
  const f32x4 b = *(const f32x4*)&p1[i];
  const f32x4 c = *(const f32x4*)&p2[i];
  const f32x4 d = *(const f32x4*)&p3[i];
  const f32x4 e = *(const f32x4*)&res[i];
  f32x4 o;
#pragma unroll
  for (int k = 0; k < 4; ++k) o[k] = ((a[k] + b[k]) + (c[k] + d[k])) + e[k];
  *(f32x4*)&out[i] = o;
}

// ---------------------------------------------------------------------------
// LayerNorm over D=1024, one token per 256-thread block, bf16 out.
// ---------------------------------------------------------------------------
__global__ __launch_bounds__(256) void ln_kernel(
    const float* __restrict__ x, const float* __restrict__ g,
    const float* __restrict__ be, unsigned short* __restrict__ out) {
  __shared__ float sbuf[4];
  const int t = blockIdx.x, tid = threadIdx.x;
  const float* row = x + (size_t)t * 1024;
  float v[4], s = 0.f;
#pragma unroll
  for (int j = 0; j < 4; ++j) { v[j] = row[tid + j * 256]; s += v[j]; }
#pragma unroll
  for (int off = 32; off; off >>= 1) s += __shfl_xor(s, off);
  if ((tid & 63) == 0) sbuf[tid >> 6] = s;
  __syncthreads();
  const float mu = (sbuf[0] + sbuf[1] + sbuf[2] + sbuf[3]) * (1.f / 1024.f);
  __syncthreads();
  float ss = 0.f;
#pragma unroll
  for (int j = 0; j < 4; ++j) { const float d = v[j] - mu; ss += d * d; }
#pragma unroll
  for (int off = 32; off; off >>= 1) ss += __shfl_xor(ss, off);
  if ((tid & 63) == 0) sbuf[tid >> 6] = ss;
  __syncthreads();
  const float var = (sbuf[0] + sbuf[1] + sbuf[2] + sbuf[3]) * (1.f / 1024.f);
  const float rstd = rsqrtf(var + 1e-5f);
  unsigned short* orow = out + (size_t)t * 1024;
#pragma unroll
  for (int j = 0; j < 4; ++j) {
    const int c = tid + j * 256;
    orow[c] = f2b((v[j] - mu) * rstd * g[c] + be[c]);
  }
}

// ---------------------------------------------------------------------------
// Attention mixing.
// ---------------------------------------------------------------------------
__global__ __launch_bounds__(256) void mix_attn(
    const unsigned short* __restrict__ all_h,
    const float* __restrict__ w_fq, const float* __restrict__ w_fk,
    const float* __restrict__ w_fv, const float* __restrict__ w_rq,
    const float* __restrict__ w_rk, const float* __restrict__ w_rv,
    unsigned short* __restrict__ t_qk, unsigned short* __restrict__ t_v) {
  __shared__ float hq[64], hk[64], hv[64];
  const int t = blockIdx.x, tid = threadIdx.x;
  const int wv = tid >> 6, lane = tid & 63;
  const unsigned short* row = all_h + (size_t)t * 4096;
  if (wv < 3) {
    const float* wf = (wv == 0 ? w_fq : wv == 1 ? w_fk : w_fv) + (size_t)t * 32;
    const int base = (wv == 2) ? 2048 : 0;
    float acc = 0.f;
#pragma unroll
    for (int n = 0; n < 32; ++n) acc += wf[n] * b2f(row[base + n * 64 + lane]);
    (wv == 0 ? hq : wv == 1 ? hk : hv)[lane] = acc;
  }
  __syncthreads();
  const float* wrq = w_rq + (size_t)t * 32;
  const float* wrk = w_rk + (size_t)t * 32;
  const float* wrv = w_rv + (size_t)t * 32;
  for (int idx = tid; idx < 2048; idx += 256) {
    const int n = idx >> 6, r = idx & 63;
    t_qk[(size_t)t * 2048 + idx] = f2b(wrq[n] * hq[r]);
    t_qk[(size_t)(4096 + t) * 2048 + idx] = f2b(wrk[n] * hk[r]);
    t_v[(size_t)t * 2048 + idx] = f2b(wrv[n] * hv[r]);
  }
}

// Knowledge mixing (RK=128)
__global__ __launch_bounds__(256) void mix_know(
    const unsigned short* __restrict__ all_h, const float* __restrict__ w_f,
    const float* __restrict__ w_r, unsigned short* __restrict__ t_know) {
  __shared__ float h[128];
  const int t = blockIdx.x, tid = threadIdx.x;
  const unsigned short* row = all_h + (size_t)t * 4096;
  if (tid < 128) {
    const float* wf = w_f + (size_t)t * 32;
    float acc = 0.f;
#pragma unroll
    for (int n = 0; n < 32; ++n) acc += wf[n] * b2f(row[n * 128 + tid]);
    h[tid] = acc;
  }
  __syncthreads();
  const float* wr = w_r + (size_t)t * 32;
  for (int idx = tid; idx < 4096; idx += 256) {
    const int n = idx >> 7, r = idx & 127;
    t_know[(size_t)t * 4096 + idx] = f2b(wr[n] * h[r]);
  }
}

// ---------------------------------------------------------------------------
// Merged weight prep: 6 transposes + W_O convert in ONE dispatch.
// ---------------------------------------------------------------------------
__global__ __launch_bounds__(256) void prep_all(
    const float* __restrict__ f_qk, const float* __restrict__ f_v,
    const float* __restrict__ f_know, const float* __restrict__ r_qk,
    const float* __restrict__ r_v, const float* __restrict__ r_know,
    const float* __restrict__ W_O,
    unsigned short* __restrict__ fcomb, unsigned short* __restrict__ fknowT,
    unsigned short* __restrict__ r_qkT, unsigned short* __restrict__ r_vT,
    unsigned short* __restrict__ r_knowT, unsigned short* __restrict__ WO_bf) {
  __shared__ float tile[32][33];
  const int bid = blockIdx.x;
  const int tx = threadIdx.x, ty = threadIdx.y;
  const float* in;
  unsigned short* out;
  int R, C, gx, loc;
  if (bid < 2048)       { in = f_qk;   out = fcomb;                         R = 1024; C = 64;   gx = 2;  loc = bid; }
  else if (bid < 4096)  { in = f_v;    out = fcomb + (size_t)2048 * 1024;   R = 1024; C = 64;   gx = 2;  loc = bid - 2048; }
  else if (bid < 8192)  { in = f_know; out = fknowT;                        R = 1024; C = 128;  gx = 4;  loc = bid - 4096; }
  else if (bid < 10240) { in = r_qk;   out = r_qkT;                         R = 2048; C = 1024; gx = 32; loc = bid - 8192; }
  else if (bid < 12288) { in = r_v;    out = r_vT;                          R = 2048; C = 1024; gx = 32; loc = bid - 10240; }
  else if (bid < 16384) { in = r_know; out = r_knowT;                       R = 4096; C = 1024; gx = 32; loc = bid - 12288; }
  else {
    const int i = ((bid - 16384) * 256 + ty * 32 + tx) * 4;
    const f32x4 v = *(const f32x4*)&W_O[i];
    *(unsigned*)&WO_bf[i] = pk2(v[0], v[1]);
    *(unsigned*)&WO_bf[i + 2] = pk2(v[2], v[3]);
    return;
  }
  const int tiles = gx * (R >> 5);
  const int bb = loc / tiles, rem = loc % tiles;
  const int r0 = (rem / gx) * 32, c0 = (rem % gx) * 32;
  const float* ip = in + (size_t)bb * R * C;
  unsigned short* op = out + (size_t)bb * R * C;
#pragma unroll
  for (int j = 0; j < 4; ++j)
    tile[ty + j * 8][tx] = ip[(size_t)(r0 + ty + j * 8) * C + c0 + tx];
  __syncthreads();
#pragma unroll
  for (int j = 0; j < 4; ++j)
    op[(size_t)(c0 + ty + j * 8) * R + r0 + tx] = f2b(tile[tx][ty + j * 8]);
}

// ---------------------------------------------------------------------------
// Causal flash attention: SPLIT-K over history, uniform work units.
// v7: P-fragment repack via single v_perm_b32 truncation packs (VALU cut),
// wave-uniform softmax skip for fully-masked nt groups on diagonal tiles.
// ---------------------------------------------------------------------------
__global__ __launch_bounds__(256) void flash_split(
    const unsigned short* __restrict__ Q, const unsigned short* __restrict__ Kp,
    const unsigned short* __restrict__ VT, unsigned short* __restrict__ O,
    float* __restrict__ Opart, float* __restrict__ ml) {
  __shared__ unsigned short Kls[2][64 * 64];
  __shared__ unsigned short Vls[2][64 * 64];
  const int uidx = 79 - (int)blockIdx.x;
  int uu = uidx, qt = 0, ch = 0;
  for (int q = 0; q < 32; ++q) {
    const int n = (q >> 3) + 1;
    if (uu < n) { qt = q; ch = uu; break; }
    uu -= n;
  }
  const int bh = blockIdx.y;
  const int b = bh >> 4, h = bh & 15;
  const int tid = threadIdx.x;
  const int w = tid >> 6, lane = tid & 63, quad = lane >> 4, l16 = lane & 15;
  const int tb = b * 2048;
  const int qrow = qt * 64 + w * 16;
  const int ktlo = ch * 8;
  const int kthi = min(qt, ch * 8 + 7);
  const float C = 0.18033688f;  // (1/sqrt(64)) * log2(e)

  const int srow = (lane >> 3);
  const int scol = ((lane & 7) ^ srow) * 8;

  bf16x8 qf[2];
#pragma unroll
  for (int kk = 0; kk < 2; ++kk)
    qf[kk] = *(const bf16x8*)&Q[(size_t)(tb + qrow + l16) * 1024 + h * 64 + kk * 32 + quad * 8];

  const f32x4 fz = {0.f, 0.f, 0.f, 0.f};
  float m_i = -1e30f, l_i = 0.f;
  f32x4 o_acc[4];
#pragma unroll
  for (int nt = 0; nt < 4; ++nt) o_acc[nt] = fz;

  auto stage = [&](int buf, int kt) {
#pragma unroll
    for (int j = 0; j < 2; ++j) {
      const int rg = (w * 2 + j) * 8 + srow;
      __builtin_amdgcn_global_load_lds(
          (const __attribute__((address_space(1))) unsigned int*)
              (Kp + (size_t)(tb + kt * 64 + rg) * 1024 + h * 64 + scol),
          (__attribute__((address_space(3))) unsigned int*)&Kls[buf][(w * 2 + j) * 8 * 64],
          16, 0, 0);
      __builtin_amdgcn_global_load_lds(
          (const __attribute__((address_space(1))) unsigned int*)
              (VT + (size_t)(h * 64 + rg) * 4096 + tb + kt * 64 + scol),
          (__attribute__((address_space(3))) unsigned int*)&Vls[buf][(w * 2 + j) * 8 * 64],
          16, 0, 0);
    }
  };

  const int srcA = (((quad & 1) * 32 + l16) << 2);
  const int srcB = srcA + 64;
  const bool hiq = (quad >= 2);

  stage(0, ktlo);
  __syncthreads();
  int buf = 0;
  for (int kt = ktlo; kt <= kthi; ++kt) {
    bf16x8 kf[8], vf[8];
#pragma unroll
    for (int kk = 0; kk < 2; ++kk)
#pragma unroll
      for (int nt = 0; nt < 4; ++nt) {
        const int sl = (((kk * 4 + quad) ^ (l16 & 7)) * 8);
        kf[kk * 4 + nt] = *(const bf16x8*)&Kls[buf][(nt * 16 + l16) * 64 + sl];
        vf[kk * 4 + nt] = *(const bf16x8*)&Vls[buf][(nt * 16 + l16) * 64 + sl];
      }
    if (kt < kthi) stage(buf ^ 1, kt + 1);

    const bool diag = (kt == qt);
    const int ntmax = diag ? (w + 1) : 4;  // wave-uniform live nt count
    f32x4 s[4];
#pragma unroll
    for (int nt = 0; nt < 4; ++nt) s[nt] = fz;
#pragma unroll
    for (int kk = 0; kk < 2; ++kk)
#pragma unroll
      for (int nt = 0; nt < 4; ++nt)
        if (nt < ntmax)
          s[nt] = __builtin_amdgcn_mfma_f32_16x16x32_bf16(kf[kk * 4 + nt], qf[kk], s[nt], 0, 0, 0);

    const int qloc = w * 16 + l16;
    float mx = -1e30f;
#pragma unroll
    for (int nt = 0; nt < 4; ++nt) {
      if (nt >= ntmax) continue;
#pragma unroll
      for (int i = 0; i < 4; ++i) {
        float v = s[nt][i];
        if (diag && (nt * 16 + quad * 4 + i) > qloc) v = -1e30f;
        s[nt][i] = v;
        mx = fmaxf(mx, v);
      }
    }
    mx = fmaxf(mx, __shfl_xor(mx, 16));
    mx = fmaxf(mx, __shfl_xor(mx, 32));
    const float mn = fmaxf(m_i, mx);
    const float al = exp2f((m_i - mn) * C);
    m_i = mn;
    const float mC = mn * C;
    float rs = 0.f;
#pragma unroll
    for (int nt = 0; nt < 4; ++nt) {
      if (nt >= ntmax) {
#pragma unroll
        for (int i = 0; i < 4; ++i) s[nt][i] = 0.f;
        continue;
      }
#pragma unroll
      for (int i = 0; i < 4; ++i) {
        const float p = exp2f(fmaf(s[nt][i], C, -mC));
        s[nt][i] = p;
        rs += p;
      }
    }
    rs += __shfl_xor(rs, 16);
    rs += __shfl_xor(rs, 32);
    l_i = l_i * al + rs;
#pragma unroll
    for (int nt = 0; nt < 4; ++nt)
#pragma unroll
      for (int i = 0; i < 4; ++i) o_acc[nt][i] *= al;

    // P pack: truncation, 1 v_perm each (intermediate only; <=1 ULP bf16)
    unsigned pk[4][2];
#pragma unroll
    for (int nt = 0; nt < 4; ++nt) {
      pk[nt][0] = pkt(s[nt][0], s[nt][1]);
      pk[nt][1] = pkt(s[nt][2], s[nt][3]);
    }
#pragma unroll
    for (int kk = 0; kk < 2; ++kk) {
      const int ea = 2 * kk, eb = 2 * kk + 1;
      const unsigned u0 = __builtin_amdgcn_ds_bpermute(srcA, pk[ea][0]);
      const unsigned u1 = __builtin_amdgcn_ds_bpermute(srcA, pk[ea][1]);
      const unsigned u2 = __builtin_amdgcn_ds_bpermute(srcB, pk[ea][0]);
      const unsigned u3 = __builtin_amdgcn_ds_bpermute(srcB, pk[ea][1]);
      const unsigned w0 = __builtin_amdgcn_ds_bpermute(srcA, pk[eb][0]);
      const unsigned w1 = __builtin_amdgcn_ds_bpermute(srcA, pk[eb][1]);
      const unsigned w2 = __builtin_amdgcn_ds_bpermute(srcB, pk[eb][0]);
      const unsigned w3 = __builtin_amdgcn_ds_bpermute(srcB, pk[eb][1]);
      unsigned dw[4];
      dw[0] = hiq ? w0 : u0;
      dw[1] = hiq ? w1 : u1;
      dw[2] = hiq ? w2 : u2;
      dw[3] = hiq ? w3 : u3;
      const bf16x8 pf = *(const bf16x8*)dw;
#pragma unroll
      for (int nt = 0; nt < 4; ++nt)
        o_acc[nt] = __builtin_amdgcn_mfma_f32_16x16x32_bf16(vf[kk * 4 + nt], pf, o_acc[nt], 0, 0, 0);
    }
    __syncthreads();
    buf ^= 1;
  }

  const int nch = (qt >> 3) + 1;
  if (nch == 1) {
    const float inv = 1.0f / l_i;
    unsigned short* orow = O + (size_t)(tb + qrow + l16) * 1024 + h * 64;
#pragma unroll
    for (int nt = 0; nt < 4; ++nt) {
      const unsigned d0 = pk2(o_acc[nt][0] * inv, o_acc[nt][1] * inv);
      const unsigned d1 = pk2(o_acc[nt][2] * inv, o_acc[nt][3] * inv);
      *(unsigned*)&orow[nt * 16 + quad * 4] = d0;
      *(unsigned*)&orow[nt * 16 + quad * 4 + 2] = d1;
    }
  } else {
    const int slot = bh * 80 + uidx;
    const int lq = w * 16 + l16;
    float* op = Opart + ((size_t)slot * 64 + lq) * 64;
#pragma unroll
    for (int nt = 0; nt < 4; ++nt)
      *(f32x4*)&op[nt * 16 + quad * 4] = o_acc[nt];
    if (quad == 0) {
      ml[(size_t)slot * 128 + lq * 2] = m_i;
      ml[(size_t)slot * 128 + lq * 2 + 1] = l_i;
    }
  }
}

// ---------------------------------------------------------------------------
// Combine flash split-K partials for qt in [8,31]. Grid (24, 32).
// ---------------------------------------------------------------------------
__global__ __launch_bounds__(256) void flash_reduce(
    const float* __restrict__ Opart, const float* __restrict__ ml,
    unsigned short* __restrict__ O) {
  const int qt = 8 + blockIdx.x;
  const int bh = blockIdx.y;
  const int b = bh >> 4, h = bh & 15;
  const int j = qt >> 3;
  const int base = 8 * (j * (j + 1) / 2) + (qt - 8 * j) * (j + 1);
  const int nch = j + 1;
  const int tid = threadIdx.x;
  const int lq = tid >> 2, dq = (tid & 3) * 16;
  const float C = 0.18033688f;

  float mc[4], lc[4];
  float m = -1e30f;
#pragma unroll
  for (int c = 0; c < 4; ++c) {
    if (c < nch) {
      const size_t sl = (size_t)(bh * 80 + base + c) * 128 + lq * 2;
      mc[c] = ml[sl];
      lc[c] = ml[sl + 1];
    } else { mc[c] = -1e30f; lc[c] = 0.f; }
    m = fmaxf(m, mc[c]);
  }
  float fac[4], lt = 0.f;
#pragma unroll
  for (int c = 0; c < 4; ++c) {
    fac[c] = (c < nch) ? exp2f((mc[c] - m) * C) : 0.f;
    lt += fac[c] * lc[c];
  }
  const float inv = 1.0f / lt;
  float acc[16];
#pragma unroll
  for (int i = 0; i < 16; ++i) acc[i] = 0.f;
#pragma unroll
  for (int c = 0; c < 4; ++c) {
    if (c >= nch) continue;
    const float* op = Opart + ((size_t)(bh * 80 + base + c) * 64 + lq) * 64 + dq;
#pragma unroll
    for (int i = 0; i < 16; i += 4) {
      const f32x4 v = *(const f32x4*)&op[i];
#pragma unroll
      for (int k = 0; k < 4; ++k) acc[i + k] += fac[c] * v[k];
    }
  }
  unsigned short* orow = O + (size_t)(b * 2048 + qt * 64 + lq) * 1024 + h * 64 + dq;
#pragma unroll
  for (int i = 0; i < 16; i += 2)
    *(unsigned*)&orow[i] = pk2(acc[i] * inv, acc[i + 1] * inv);
}

// ---------------------------------------------------------------------------
extern "C" void kernel_launch(void* const* d_in, const int* in_sizes, int n_in,
                              void* d_out, int out_size, void* d_ws, size_t ws_size,
                              hipStream_t stream) {
  (void)in_sizes; (void)n_in; (void)out_size; (void)ws_size;
  const float* x      = (const float*)d_in[0];
  const float* f_qk   = (const float*)d_in[1];
  const float* f_v    = (const float*)d_in[2];
  const float* r_qk   = (const float*)d_in[3];
  const float* r_v    = (const float*)d_in[4];
  const float* f_know = (const float*)d_in[5];
  const float* r_know = (const float*)d_in[6];
  const float* W_O    = (const float*)d_in[7];
  const float* gamma1 = (const float*)d_in[8];
  const float* beta1  = (const float*)d_in[9];
  const float* gamma2 = (const float*)d_in[10];
  const float* beta2  = (const float*)d_in[11];
  const float* w_fq   = (const float*)d_in[12];
  const float* w_fk   = (const float*)d_in[13];
  const float* w_fv   = (const float*)d_in[14];
  const float* w_rq   = (const float*)d_in[15];
  const float* w_rk   = (const float*)d_in[16];
  const float* w_rv   = (const float*)d_in[17];
  const float* w_kf   = (const float*)d_in[18];
  const float* w_kr   = (const float*)d_in[19];

  char* base = (char*)d_ws;
  size_t off = 0;
  auto alloc = [&](size_t b) { char* p = base + off; off += (b + 255) & ~(size_t)255; return p; };
  unsigned short* fcomb   = (unsigned short*)alloc(8388608);   // [4096][1024]
  unsigned short* fknowT  = (unsigned short*)alloc(8388608);   // [4096][1024]
  unsigned short* r_qkT   = (unsigned short*)alloc(4194304);   // [1024][2048]
  unsigned short* r_vT    = (unsigned short*)alloc(4194304);   // [1024][2048]
  unsigned short* r_knowT = (unsigned short*)alloc(8388608);   // [1024][4096]
  unsigned short* WO_bf   = (unsigned short*)alloc(2097152);   // [1024][1024]
  unsigned short* nx_bf   = (unsigned short*)alloc(8388608);   // [4096][1024]
  unsigned short* all_h   = (unsigned short*)alloc(33554432);  // [4096][4096]
  unsigned short* t_qk    = (unsigned short*)alloc(33554432);  // [8192][2048]
  unsigned short* t_v     = (unsigned short*)alloc(16777216);  // [4096][2048]; reused as x1 fp32
  unsigned short* QKbuf   = (unsigned short*)alloc(16777216);  // [8192][1024]
  unsigned short* VT      = (unsigned short*)alloc(8388608);   // [1024][4096]
  unsigned short* attn    = (unsigned short*)alloc(8388608);   // [4096][1024]
  float* x1 = (float*)t_v;                    // t_v dead before x1 written
  unsigned short* pQK0 = all_h;               // bf16 QK partial ks=0
  unsigned short* pQK1 = all_h + 8388608;     // bf16 QK partial ks=1
  float* Opart = (float*)all_h;               // flash partials
  float* mlbuf = (float*)((char*)all_h + 41943040);
  float* pW0 = (float*)all_h;                 // ks4 fp32 partials
  float* pW1 = (float*)((char*)all_h + 16777216);
  float* pW2 = (float*)QKbuf;
  float* pW3_wo   = (float*)t_qk;             // dead during WO gemm
  float* pW3_know = (float*)VT;               // VT+attn dead during knowledge gemm

  const dim3 blk256(256), blkT(32, 8);

  prep_all<<<17408, blkT, 0, stream>>>(f_qk, f_v, f_know, r_qk, r_v, r_know, W_O,
                                       fcomb, fknowT, r_qkT, r_vT, r_knowT, WO_bf);

  // attention circuit
  ln_kernel<<<4096, blk256, 0, stream>>>(x, gamma1, beta1, nx_bf);
  gemm_bt<<<dim3(32, 32), blk256, 0, stream>>>(nx_bf, fcomb, all_h, 4096, 4096, 1024);
  mix_attn<<<4096, blk256, 0, stream>>>(all_h, w_fq, w_fk, w_fv, w_rq, w_rk, w_rv, t_qk, t_v);
  gemm_qkv2<<<1280, blk256, 0, stream>>>(t_qk, t_v, r_qkT, r_vT, pQK0, pQK1, VT);
  reduce_qk<<<4096, blk256, 0, stream>>>(pQK0, pQK1, QKbuf);
  flash_split<<<dim3(80, 32), blk256, 0, stream>>>(QKbuf, QKbuf + (size_t)4096 * 1024, VT, attn,
                                                   Opart, mlbuf);
  flash_reduce<<<dim3(24, 32), blk256, 0, stream>>>(Opart, mlbuf, attn);
  gemm_ks4<<<1024, blk256, 0, stream>>>(attn, WO_bf, pW0, pW1, pW2, pW3_wo, 1024);
  reduce_add5<<<4096, blk256, 0, stream>>>(pW0, pW1, pW2, pW3_wo, x, x1);

  // knowledge circuit
  ln_kernel<<<4096, blk256, 0, stream>>>(x1, gamma2, beta2, nx_bf);
  gemm_bt<<<dim3(32, 32), blk256, 0, stream>>>(nx_bf, fknowT, all_h, 4096, 4096, 1024);
  mix_know<<<4096, blk256, 0, stream>>>(all_h, w_kf, w_kr, t_qk);
  gemm_ks4<<<1024, blk256, 0, stream>>>(t_qk, r_knowT, pW0, pW1, pW2, pW3_know, 4096);
  reduce_add5<<<4096, blk256, 0, stream>>>(pW0, pW1, pW2, pW3_know, x1, (float*)d_out);
}